// Round 6
// baseline (3114.745 us; speedup 1.0000x reference)
//
#include <hip/hip_runtime.h>
#include <hip/hip_bf16.h>

typedef __hip_bfloat16 bf16;

#define KN 8384
#define KE 50000

__constant__ int c_sn[5] = {1, 137, 4321, 8200, 8321};

__device__ __forceinline__ float toF(float v){ return v; }
__device__ __forceinline__ float toF(bf16 v){ return __bfloat162float(v); }
__device__ __forceinline__ void stor(float* p, float v){ *p = v; }
__device__ __forceinline__ void stor(bf16* p, float v){ *p = __float2bfloat16(v); }

// ---------------- generic tiled GEMM: C[M,N] = A[M,K] @ B[K,N] (+bias) ----------------
template<typename TA, typename TB, typename TC>
__global__ __launch_bounds__(256)
void gemm_k(const TA* __restrict__ A, const TB* __restrict__ B,
            const float* __restrict__ bias, TC* __restrict__ C,
            int M, int N, int K)
{
  __shared__ float As[16][65];
  __shared__ float Bs[16][65];
  const int bm = blockIdx.y * 64, bn = blockIdx.x * 64;
  const int tid = threadIdx.x;
  const int tm = (tid >> 4) << 2, tn = (tid & 15) << 2;
  float acc00=0,acc01=0,acc02=0,acc03=0,
        acc10=0,acc11=0,acc12=0,acc13=0,
        acc20=0,acc21=0,acc22=0,acc23=0,
        acc30=0,acc31=0,acc32=0,acc33=0;
  for (int k0 = 0; k0 < K; k0 += 16) {
    #pragma unroll
    for (int i = 0; i < 4; i++) {
      int idx = tid + i * 256;
      { int am = idx >> 4, ak = idx & 15;
        int gr = bm + am, gk = k0 + ak;
        As[ak][am] = (gr < M && gk < K) ? toF(A[(size_t)gr * K + gk]) : 0.f; }
      { int bk = idx >> 6, bn2 = idx & 63;
        int gk = k0 + bk, gn = bn + bn2;
        Bs[bk][bn2] = (gk < K && gn < N) ? toF(B[(size_t)gk * N + gn]) : 0.f; }
    }
    __syncthreads();
    #pragma unroll
    for (int kk = 0; kk < 16; kk++) {
      float a0=As[kk][tm+0], a1=As[kk][tm+1], a2=As[kk][tm+2], a3=As[kk][tm+3];
      float b0=Bs[kk][tn+0], b1=Bs[kk][tn+1], b2=Bs[kk][tn+2], b3=Bs[kk][tn+3];
      acc00+=a0*b0; acc01+=a0*b1; acc02+=a0*b2; acc03+=a0*b3;
      acc10+=a1*b0; acc11+=a1*b1; acc12+=a1*b2; acc13+=a1*b3;
      acc20+=a2*b0; acc21+=a2*b1; acc22+=a2*b2; acc23+=a2*b3;
      acc30+=a3*b0; acc31+=a3*b1; acc32+=a3*b2; acc33+=a3*b3;
    }
    __syncthreads();
  }
  float accs[4][4] = {{acc00,acc01,acc02,acc03},{acc10,acc11,acc12,acc13},
                      {acc20,acc21,acc22,acc23},{acc30,acc31,acc32,acc33}};
  #pragma unroll
  for (int r = 0; r < 4; r++) {
    int gr = bm + tm + r;
    if (gr >= M) continue;
    #pragma unroll
    for (int c = 0; c < 4; c++) {
      int gn = bn + tn + c;
      if (gn >= N) continue;
      float v = accs[r][c];
      if (bias) v += bias[gn];
      stor(&C[(size_t)gr * N + gn], v);
    }
  }
}

// ---------------- small utility kernels ----------------
__global__ void k_mean(const float* cv, float* m){
  int o = threadIdx.x;  // 128
  float s = 0.f;
  for (int c = 0; c < 64; c++) s += cv[c * 128 + o];
  m[o] = s * (1.f / 64.f);
}
__global__ void k_dfeat(const float* x, const float* duc, float* df){
  int n = blockIdx.x, o = threadIdx.x; // 256
  float v;
  if (n < 8192)      v = x[(n & 127) * 256 + o];
  else if (n < 8256) v = duc[(n - 8192) * 256 + o];
  else               v = x[(n - 8256) * 256 + o];
  df[n * 256 + o] = v;
}
__global__ void k_cfin(const float* cv, const float* cm, float* cf){
  int n = blockIdx.x, o = threadIdx.x; // 128
  float v;
  if (n < 8192)      v = cv[(n >> 7) * 128 + o];
  else if (n < 8256) v = cv[(n - 8192) * 128 + o];
  else               v = cm[o];
  cf[n * 128 + o] = v;
}
__global__ void k_inf(const float* df, const float* cfin, float* inf){
  int n = blockIdx.x, c = threadIdx.x; // 384
  inf[n * 384 + c] = (c < 256) ? df[n * 256 + c] : cfin[n * 128 + (c - 256)];
}
__global__ void k_zeroi(int* p, int n){
  int i = blockIdx.x * blockDim.x + threadIdx.x; if (i < n) p[i] = 0;
}
__global__ void k_copyi(const int* a, int* b, int n){
  int i = blockIdx.x * blockDim.x + threadIdx.x; if (i < n) b[i] = a[i];
}
__global__ void k_count(const int* dst, int* cnt, int e){
  int i = blockIdx.x * blockDim.x + threadIdx.x;
  if (i < e) atomicAdd(&cnt[dst[i]], 1);
}
__global__ void k_scan(const int* __restrict__ cnt, int* __restrict__ ptr, int n){
  __shared__ int part[1024];
  int tid = threadIdx.x;
  const int CH = (n + 1023) >> 10;
  int base = tid * CH;
  int s = 0;
  for (int i = 0; i < CH; i++){ int idx = base + i; if (idx < n) s += cnt[idx]; }
  part[tid] = s; __syncthreads();
  for (int off = 1; off < 1024; off <<= 1){
    int v = (tid >= off) ? part[tid - off] : 0;
    __syncthreads();
    part[tid] += v;
    __syncthreads();
  }
  int run = part[tid] - s;  // exclusive base
  for (int i = 0; i < CH; i++){
    int idx = base + i;
    if (idx < n){ ptr[idx] = run; run += cnt[idx]; }
  }
  if (tid == 1023) ptr[n] = part[1023];
}
__global__ void k_fill(const int* src, const int* dst, int* cur, int* csrc, int e){
  int i = blockIdx.x * blockDim.x + threadIdx.x;
  if (i < e){ int p = atomicAdd(&cur[dst[i]], 1); csrc[p] = src[i]; }
}
__global__ void k_edgechk(const int* e, int n, int* diag){
  int i = blockIdx.x * blockDim.x + threadIdx.x;
  if (i < n && (unsigned)e[i] >= (unsigned)KN) atomicOr(diag, 32);
}
__global__ void k_elr(const float* __restrict__ feat, const float* __restrict__ al,
                      const float* __restrict__ ar, float* el, float* er){
  int n = blockIdx.x, tid = threadIdx.x; // 256
  int h = tid >> 6, lane = tid & 63;
  const float* f = feat + (size_t)n * 1024 + h * 256;
  float a = 0.f, b = 0.f;
  for (int i = lane; i < 256; i += 64){
    float fv = f[i];
    a += fv * al[h * 256 + i];
    b += fv * ar[h * 256 + i];
  }
  for (int off = 32; off; off >>= 1){ a += __shfl_down(a, off); b += __shfl_down(b, off); }
  if (lane == 0){ el[n * 4 + h] = a; er[n * 4 + h] = b; }
}

// ------------- per-dst GAT aggregation + fused score (rst . qk) -------------
__global__ __launch_bounds__(256)
void k_agg(const int* __restrict__ ptr, const int* __restrict__ srcs,
           const float* __restrict__ el, const float* __restrict__ er,
           const float* __restrict__ feat, const float* __restrict__ gb,
           const float* __restrict__ qk,
           bf16* __restrict__ rst, float* __restrict__ score, int t)
{
  const int n = blockIdx.x, tid = threadIdx.x;
  const int beg = ptr[n], deg = ptr[n + 1] - beg;
  const int h4 = tid & 3, j0 = tid >> 2;
  __shared__ float red[256];
  __shared__ float sm[4], sinv[4];
  __shared__ float sa[64][4];
  __shared__ int ssrc[64];
  float ern = er[n * 4 + h4];
  float mx = -1e30f;
  for (int j = j0; j < deg; j += 64){
    int s = srcs[beg + j];
    float e = el[s * 4 + h4] + ern;
    e = e > 0.f ? e : 0.2f * e;
    mx = fmaxf(mx, e);
  }
  red[tid] = mx; __syncthreads();
  for (int off = 128; off >= 4; off >>= 1){
    if (tid < off) red[tid] = fmaxf(red[tid], red[tid + off]);
    __syncthreads();
  }
  if (tid < 4) sm[tid] = red[tid];
  __syncthreads();
  float m = sm[h4];
  float sum = 0.f;
  for (int j = j0; j < deg; j += 64){
    int s = srcs[beg + j];
    float e = el[s * 4 + h4] + ern;
    e = e > 0.f ? e : 0.2f * e;
    sum += __expf(e - m);
  }
  red[tid] = sum; __syncthreads();
  for (int off = 128; off >= 4; off >>= 1){
    if (tid < off) red[tid] += red[tid + off];
    __syncthreads();
  }
  if (tid < 4) sinv[tid] = 1.f / fmaxf(red[tid], 1e-9f);
  __syncthreads();
  float acc0 = 0.f, acc1 = 0.f, acc2 = 0.f, acc3 = 0.f;
  for (int c0 = 0; c0 < deg; c0 += 64){
    int cn = min(64, deg - c0);
    __syncthreads();
    if (tid < cn) ssrc[tid] = srcs[beg + c0 + tid];
    __syncthreads();
    if (j0 < cn){
      int s = ssrc[j0];
      float e = el[s * 4 + h4] + ern;
      e = e > 0.f ? e : 0.2f * e;
      sa[j0][h4] = __expf(e - sm[h4]) * sinv[h4];
    }
    __syncthreads();
    for (int j = 0; j < cn; j++){
      int s = ssrc[j];
      const float* fp = feat + (size_t)s * 1024;
      float w0 = sa[j][0], w1 = sa[j][1], w2 = sa[j][2], w3 = sa[j][3];
      acc0 += w0 * fp[tid];
      acc1 += w1 * fp[256 + tid];
      acc2 += w2 * fp[512 + tid];
      acc3 += w3 * fp[768 + tid];
    }
  }
  float qv = qk[(size_t)n * 256 + tid];
  float accs[4] = {acc0, acc1, acc2, acc3};
  #pragma unroll
  for (int h = 0; h < 4; h++){
    float v = accs[h] + gb[h * 256 + tid];
    rst[((size_t)n * 16 + t * 4 + h) * 256 + tid] = __float2bfloat16(v);
    red[tid] = v * qv;
    __syncthreads();
    for (int off = 128; off >= 1; off >>= 1){
      if (tid < off) red[tid] += red[tid + off];
      __syncthreads();
    }
    if (tid == 0) score[n * 16 + t * 4 + h] = red[0];
    __syncthreads();
  }
}

// ------------- attention finalize -------------
__global__ void k_attn(const float* __restrict__ score, const bf16* __restrict__ rst,
                       float* __restrict__ rbar){
  int n = blockIdx.x, tid = threadIdx.x; // 256
  float sc[16]; float m = -1e30f;
  #pragma unroll
  for (int s = 0; s < 16; s++){ sc[s] = score[n * 16 + s] * 0.0625f; m = fmaxf(m, sc[s]); }
  float sum = 0.f;
  #pragma unroll
  for (int s = 0; s < 16; s++){ sc[s] = __expf(sc[s] - m); sum += sc[s]; }
  float inv = 1.f / sum;
  float r = 0.f;
  #pragma unroll
  for (int s = 0; s < 16; s++)
    r += sc[s] * __bfloat162float(rst[((size_t)n * 16 + s) * 256 + tid]);
  rbar[(size_t)n * 256 + tid] = r * inv;
}

// ------------- folded-weight combine kernels -------------
__global__ void k_Wq(const float* wqw, const float* ipw, float* Wq){
  int c = blockIdx.x, j = threadIdx.x;
  float s = 0.f;
  for (int e = 0; e < 256; e++) s += wqw[c * 256 + e] * ipw[j * 256 + e];
  Wq[c * 256 + j] = s;
}
__global__ void k_bq(const float* wqb, const float* ipw, const float* ipb, float* bq){
  int j = threadIdx.x;
  float s = 0.f;
  for (int e = 0; e < 256; e++) s += wqb[e] * ipw[j * 256 + e];
  bq[j] = s + ipb[j];
}
__global__ void k_B2(const float* wkw, const float* ipw, float* B2){
  int j = blockIdx.x, c = threadIdx.x;
  float s = 0.f;
  for (int e = 0; e < 256; e++) s += wkw[c * 256 + e] * ipw[(256 + j) * 256 + e];
  B2[j * 256 + c] = s;
}
__global__ void k_M1(const float* ipw, const float* opw, float* M1){
  int e = blockIdx.x, j = threadIdx.x;
  float s = 0.f;
  for (int f = 0; f < 256; f++) s += ipw[(512 + f) * 256 + e] * opw[j * 256 + f];
  M1[e * 256 + j] = s;
}
__global__ void k_Wv(const float* wvw, const float* M1, float* Wv){
  int c = blockIdx.x, j = threadIdx.x;
  float s = 0.f;
  for (int e = 0; e < 256; e++) s += wvw[c * 256 + e] * M1[e * 256 + j];
  Wv[c * 256 + j] = s;
}
__global__ void k_bv(const float* wvb, const float* M1, const float* ipb,
                     const float* opw, const float* opb, float* bv){
  int j = threadIdx.x;
  float s = 0.f;
  for (int e = 0; e < 256; e++) s += wvb[e] * M1[e * 256 + j];
  for (int f = 0; f < 256; f++) s += ipb[512 + f] * opw[j * 256 + f];
  bv[j] = s + opb[j];
}

// ---- end-to-end canary: unfolded attention path at 5 nodes (f32 out) ----
__global__ void chk_out(const bf16* rst, const float* score,
                        const float* wvw, const float* wvb, const float* ipw, const float* ipb,
                        const float* opw, const float* opb, const float* out, int* diag){
  __shared__ float Ve[16][257];
  __shared__ float att[16];
  __shared__ float vbar[256];
  int n = c_sn[blockIdx.x], tid = threadIdx.x;
  for (int it = tid; it < 16*256; it += 256){
    int s = it >> 8, e = it & 255;
    float acc = wvb[e];
    for (int c = 0; c < 256; c++)
      acc += toF(rst[((size_t)n*16+s)*256 + c]) * wvw[c*256+e];
    Ve[s][e] = acc;
  }
  if (tid == 0){
    float m = -1e30f, sc[16];
    for (int s = 0; s < 16; s++){ sc[s] = score[n*16+s]*0.0625f; m = fmaxf(m, sc[s]); }
    float ss = 0.f;
    for (int s = 0; s < 16; s++){ sc[s] = expf(sc[s]-m); ss += sc[s]; }
    for (int s = 0; s < 16; s++) att[s] = sc[s]/ss;
  }
  __syncthreads();
  { int f = tid;
    float acc = 0.f;
    for (int s = 0; s < 16; s++){
      float vf = ipb[512+f];
      for (int e = 0; e < 256; e++) vf += Ve[s][e]*ipw[(512+f)*256+e];
      acc += att[s]*vf;
    }
    vbar[f] = acc; }
  __syncthreads();
  { int j = tid;
    float o = opb[j];
    for (int f = 0; f < 256; f++) o += vbar[f]*opw[j*256+f];
    float got = out[(size_t)n*256 + j];
    if (fabsf(o - got) > 8e-3f*(1.f+fabsf(o))) atomicOr(diag, 4); }
}

__global__ void k_diag(const int* diag, float* out, int n){
  int i = blockIdx.x * blockDim.x + threadIdx.x;
  int m = diag[0];
  if (m != 0 && i < n) out[i] = (float)(m * 16);
}

struct LWT {
  const float *gw, *al, *ar, *gb, *wqw, *wqb, *wkw, *wkb, *wvw, *wvb, *ipw, *ipb, *opw, *opb;
};

extern "C" void kernel_launch(void* const* d_in, const int* in_sizes, int n_in,
                              void* d_out, int out_size, void* d_ws, size_t ws_size,
                              hipStream_t stream)
{
  const float* x   = (const float*)d_in[0];
  const float* cf  = (const float*)d_in[1];
  const float* cfw = (const float*)d_in[2];
  const float* cfb = (const float*)d_in[3];
  const float* htw = (const float*)d_in[4];
  const float* htb = (const float*)d_in[5];
  LWT L[2];
  for (int l = 0; l < 2; l++){
    int b = 6 + l * 14;
    L[l].gw  = (const float*)d_in[b + 0];
    L[l].al  = (const float*)d_in[b + 1];
    L[l].ar  = (const float*)d_in[b + 2];
    L[l].gb  = (const float*)d_in[b + 3];
    L[l].wqw = (const float*)d_in[b + 4];
    L[l].wqb = (const float*)d_in[b + 5];
    L[l].wkw = (const float*)d_in[b + 6];
    L[l].wkb = (const float*)d_in[b + 7];
    L[l].wvw = (const float*)d_in[b + 8];
    L[l].wvb = (const float*)d_in[b + 9];
    L[l].ipw = (const float*)d_in[b + 10];
    L[l].ipb = (const float*)d_in[b + 11];
    L[l].opw = (const float*)d_in[b + 12];
    L[l].opb = (const float*)d_in[b + 13];
  }
  const int* edges = (const int*)d_in[34];

  // -------- workspace layout --------
  char* w = (char*)d_ws;
  size_t off = 0;
  auto alc = [&](size_t bytes) -> void* {
    off = (off + 255) & ~(size_t)255;
    void* p = w + off; off += bytes; return p;
  };
  float* f_cfvec = (float*)alc(64 * 128 * 4);
  float* f_cfmean= (float*)alc(128 * 4);
  float* f_duc   = (float*)alc(64 * 256 * 4);
  float* f_dfeat = (float*)alc((size_t)KN * 256 * 4);
  float* f_cfin  = (float*)alc((size_t)KN * 128 * 4);
  float* f_inf   = (float*)alc((size_t)KN * 384 * 4);
  float* f_feat  = (float*)alc((size_t)KN * 1024 * 4);
  float* f_el    = (float*)alc((size_t)KN * 4 * 4);
  float* f_er    = (float*)alc((size_t)KN * 4 * 4);
  float* f_rbar  = (float*)alc((size_t)KN * 256 * 4);   // aliased: qt then rbar
  float* f_qt    = f_rbar;
  float* f_qk    = (float*)alc((size_t)KN * 256 * 4);
  float* f_score = (float*)alc((size_t)KN * 16 * 4);
  float* f_Wq    = (float*)alc(128 * 256 * 4);
  float* f_bq    = (float*)alc(256 * 4);
  float* f_B2    = (float*)alc(256 * 256 * 4);
  float* f_M1    = (float*)alc(256 * 256 * 4);
  float* f_Wv    = (float*)alc(256 * 256 * 4);
  float* f_bv    = (float*)alc(256 * 4);
  bf16*  b_rst   = (bf16*)alc((size_t)KN * 16 * 256 * 2);
  int*   i_ptr   = (int*)alc((size_t)4 * (KN + 1) * 4);
  int*   i_src   = (int*)alc((size_t)4 * KE * 4);
  int*   i_cnt   = (int*)alc((size_t)KN * 4);
  int*   i_cur   = (int*)alc((size_t)KN * 4);
  int*   i_diag  = (int*)alc(64 * 4);
  if (off > ws_size) return;  // visible failure: d_out stays as memset

  k_zeroi<<<1, 64, 0, stream>>>(i_diag, 2);
  k_edgechk<<<(4 * 2 * KE + 255) / 256, 256, 0, stream>>>(edges, 4 * 2 * KE, i_diag);

  // -------- shared pre-phase --------
  gemm_k<float, float, float><<<dim3(2, 1), 256, 0, stream>>>(cf, cfw, cfb, f_cfvec, 64, 128, 512);
  gemm_k<float, float, float><<<dim3(4, 1), 256, 0, stream>>>(cf, htw, htb, f_duc, 64, 256, 512);
  k_mean<<<1, 128, 0, stream>>>(f_cfvec, f_cfmean);
  k_dfeat<<<KN, 256, 0, stream>>>(x, f_duc, f_dfeat);
  k_cfin <<<KN, 128, 0, stream>>>(f_cfvec, f_cfmean, f_cfin);

  // -------- CSR per relation (literal reference direction) --------
  // gat_conv(inf, src=edges[t,0], dst=edges[t,1]): aggregate AT dst, gather feat/el FROM src.
  for (int t = 0; t < 4; t++){
    const int* src_t = edges + t * 2 * KE;
    const int* dst_t = src_t + KE;
    int* ptr_t  = i_ptr + t * (KN + 1);
    int* csrc_t = i_src + t * KE;
    k_zeroi<<<(KN + 255) / 256, 256, 0, stream>>>(i_cnt, KN);
    k_count<<<(KE + 255) / 256, 256, 0, stream>>>(dst_t, i_cnt, KE);
    k_scan <<<1, 1024, 0, stream>>>(i_cnt, ptr_t, KN);
    k_copyi<<<(KN + 255) / 256, 256, 0, stream>>>(ptr_t, i_cur, KN);
    k_fill <<<(KE + 255) / 256, 256, 0, stream>>>(src_t, dst_t, i_cur, csrc_t, KE);
  }

  // -------- one layer --------
  auto run_layer = [&](const LWT& Wt, const float* dfeat_in, float* outp){
    k_inf<<<KN, 384, 0, stream>>>(dfeat_in, f_cfin, f_inf);
    k_Wq<<<128, 256, 0, stream>>>(Wt.wqw, Wt.ipw, f_Wq);
    k_bq<<<1, 256, 0, stream>>>(Wt.wqb, Wt.ipw, Wt.ipb, f_bq);
    k_B2<<<256, 256, 0, stream>>>(Wt.wkw, Wt.ipw, f_B2);
    k_M1<<<256, 256, 0, stream>>>(Wt.ipw, Wt.opw, f_M1);
    k_Wv<<<256, 256, 0, stream>>>(Wt.wvw, f_M1, f_Wv);
    k_bv<<<1, 256, 0, stream>>>(Wt.wvb, f_M1, Wt.ipb, Wt.opw, Wt.opb, f_bv);
    gemm_k<float, float, float><<<dim3(4, 131), 256, 0, stream>>>(f_cfin, f_Wq, f_bq, f_qt, KN, 256, 128);
    gemm_k<float, float, float><<<dim3(4, 131), 256, 0, stream>>>(f_qt, f_B2, nullptr, f_qk, KN, 256, 256);
    for (int t = 0; t < 4; t++){
      const float* gwt = Wt.gw + (size_t)t * 384 * 1024;
      gemm_k<float, float, float><<<dim3(16, 131), 256, 0, stream>>>(f_inf, gwt, nullptr, f_feat, KN, 1024, 384);
      k_elr<<<KN, 256, 0, stream>>>(f_feat, Wt.al + t * 1024, Wt.ar + t * 1024, f_el, f_er);
      k_agg<<<KN, 256, 0, stream>>>(i_ptr + t * (KN + 1), i_src + t * KE,
                                    f_el, f_er, f_feat, Wt.gb + t * 1024,
                                    f_qk, b_rst, f_score, t);
    }
    k_attn<<<KN, 256, 0, stream>>>(f_score, b_rst, f_rbar);
    gemm_k<float, float, float><<<dim3(4, 131), 256, 0, stream>>>(f_rbar, f_Wv, f_bv, outp, KN, 256, 256);
    chk_out<<<5, 256, 0, stream>>>(b_rst, f_score, Wt.wvw, Wt.wvb, Wt.ipw, Wt.ipb,
                                   Wt.opw, Wt.opb, outp, i_diag);
  };

  run_layer(L[0], f_dfeat, f_dfeat);          // layer 1 -> f32 h (overwrites dfeat)
  run_layer(L[1], f_dfeat, (float*)d_out);    // layer 2 -> f32 output

  k_diag<<<(out_size + 255) / 256, 256, 0, stream>>>(i_diag, (float*)d_out, out_size);
}

// Round 7
// 1303.643 us; speedup vs baseline: 2.3893x; 2.3893x over previous
//
#include <hip/hip_runtime.h>
#include <hip/hip_bf16.h>

typedef __hip_bfloat16 bf16;
typedef __attribute__((ext_vector_type(8))) short short8;
typedef __attribute__((ext_vector_type(4))) float f32x4;

#define KN 8384
#define KE 50000

__device__ __forceinline__ float toF(float v){ return v; }
__device__ __forceinline__ float toF(bf16 v){ return __bfloat162float(v); }
__device__ __forceinline__ void stor(float* p, float v){ *p = v; }
__device__ __forceinline__ void stor(bf16* p, float v){ *p = __float2bfloat16(v); }

// ---------------- generic tiled vector GEMM: C[M,N] = A[M,K] @ B[K,N] (+bias) ----------------
template<typename TA, typename TB, typename TC>
__global__ __launch_bounds__(256)
void gemm_k(const TA* __restrict__ A, const TB* __restrict__ B,
            const float* __restrict__ bias, TC* __restrict__ C,
            int M, int N, int K)
{
  __shared__ float As[16][65];
  __shared__ float Bs[16][65];
  const int bm = blockIdx.y * 64, bn = blockIdx.x * 64;
  const int tid = threadIdx.x;
  const int tm = (tid >> 4) << 2, tn = (tid & 15) << 2;
  float acc00=0,acc01=0,acc02=0,acc03=0,
        acc10=0,acc11=0,acc12=0,acc13=0,
        acc20=0,acc21=0,acc22=0,acc23=0,
        acc30=0,acc31=0,acc32=0,acc33=0;
  for (int k0 = 0; k0 < K; k0 += 16) {
    #pragma unroll
    for (int i = 0; i < 4; i++) {
      int idx = tid + i * 256;
      { int am = idx >> 4, ak = idx & 15;
        int gr = bm + am, gk = k0 + ak;
        As[ak][am] = (gr < M && gk < K) ? toF(A[(size_t)gr * K + gk]) : 0.f; }
      { int bk = idx >> 6, bn2 = idx & 63;
        int gk = k0 + bk, gn = bn + bn2;
        Bs[bk][bn2] = (gk < K && gn < N) ? toF(B[(size_t)gk * N + gn]) : 0.f; }
    }
    __syncthreads();
    #pragma unroll
    for (int kk = 0; kk < 16; kk++) {
      float a0=As[kk][tm+0], a1=As[kk][tm+1], a2=As[kk][tm+2], a3=As[kk][tm+3];
      float b0=Bs[kk][tn+0], b1=Bs[kk][tn+1], b2=Bs[kk][tn+2], b3=Bs[kk][tn+3];
      acc00+=a0*b0; acc01+=a0*b1; acc02+=a0*b2; acc03+=a0*b3;
      acc10+=a1*b0; acc11+=a1*b1; acc12+=a1*b2; acc13+=a1*b3;
      acc20+=a2*b0; acc21+=a2*b1; acc22+=a2*b2; acc23+=a2*b3;
      acc30+=a3*b0; acc31+=a3*b1; acc32+=a3*b2; acc33+=a3*b3;
    }
    __syncthreads();
  }
  float accs[4][4] = {{acc00,acc01,acc02,acc03},{acc10,acc11,acc12,acc13},
                      {acc20,acc21,acc22,acc23},{acc30,acc31,acc32,acc33}};
  #pragma unroll
  for (int r = 0; r < 4; r++) {
    int gr = bm + tm + r;
    if (gr >= M) continue;
    #pragma unroll
    for (int c = 0; c < 4; c++) {
      int gn = bn + tn + c;
      if (gn >= N) continue;
      float v = accs[r][c];
      if (bias) v += bias[gn];
      stor(&C[(size_t)gr * N + gn], v);
    }
  }
}

// ---------------- MFMA GEMM: C[M,N] f32 = A[M,K]bf16 @ BT[N,K]bf16 ----------------
// K % 32 == 0, N % 128 == 0; M guarded. 128x128 tile, 4 waves, 4x4 16x16x32 frags.
__global__ __launch_bounds__(256)
void gemm_mfma_bt(const bf16* __restrict__ A, const bf16* __restrict__ BT,
                  float* __restrict__ C, int M, int N, int K)
{
  __shared__ bf16 As[128][40];   // row stride 80 B (16-aligned, conflict-benign)
  __shared__ bf16 Bs[128][40];
  const int bm = blockIdx.y * 128, bn = blockIdx.x * 128;
  const int tid = threadIdx.x;
  const int w = tid >> 6, l = tid & 63;
  const int wr = (w >> 1) * 64, wc = (w & 1) * 64;
  const int lr = l & 15, ko = (l >> 4) * 8;
  f32x4 acc[4][4] = {};
  for (int k0 = 0; k0 < K; k0 += 32) {
    #pragma unroll
    for (int p = 0; p < 2; p++){
      int r = (tid >> 2) + p * 64;
      int kk = (tid & 3) * 8;
      int gr = bm + r;
      short8 va = {};
      if (gr < M) va = *(const short8*)&A[(size_t)gr * K + k0 + kk];
      *(short8*)&As[r][kk] = va;
      short8 vb = *(const short8*)&BT[(size_t)(bn + r) * K + k0 + kk];
      *(short8*)&Bs[r][kk] = vb;
    }
    __syncthreads();
    short8 a[4], b[4];
    #pragma unroll
    for (int i = 0; i < 4; i++) a[i] = *(short8*)&As[wr + i*16 + lr][ko];
    #pragma unroll
    for (int j = 0; j < 4; j++) b[j] = *(short8*)&Bs[wc + j*16 + lr][ko];
    #pragma unroll
    for (int i = 0; i < 4; i++)
      #pragma unroll
      for (int j = 0; j < 4; j++)
        acc[i][j] = __builtin_amdgcn_mfma_f32_16x16x32_bf16(a[i], b[j], acc[i][j], 0, 0, 0);
    __syncthreads();
  }
  const int orow = (l >> 4) * 4, ocol = l & 15;
  #pragma unroll
  for (int i = 0; i < 4; i++){
    #pragma unroll
    for (int j = 0; j < 4; j++){
      int gcol = bn + wc + j*16 + ocol;
      #pragma unroll
      for (int rg = 0; rg < 4; rg++){
        int grow = bm + wr + i*16 + orow + rg;
        if (grow < M) C[(size_t)grow * N + gcol] = acc[i][j][rg];
      }
    }
  }
}

// ---------------- transpose-cast: B f32 [K][N] -> BT bf16 [N][K] ----------------
__global__ void k_transB(const float* __restrict__ B, bf16* __restrict__ BT, int K, int N){
  __shared__ float t[32][33];
  int n0 = blockIdx.x * 32, k0 = blockIdx.y * 32;
  int tx = threadIdx.x, ty = threadIdx.y; // 32 x 8
  for (int i = ty; i < 32; i += 8)
    t[i][tx] = B[(size_t)(k0 + i) * N + n0 + tx];
  __syncthreads();
  for (int i = ty; i < 32; i += 8)
    BT[(size_t)(n0 + i) * K + k0 + tx] = __float2bfloat16(t[tx][i]);
}

// ---------------- small utility kernels ----------------
__global__ void k_mean(const float* cv, float* m){
  int o = threadIdx.x;  // 128
  float s = 0.f;
  for (int c = 0; c < 64; c++) s += cv[c * 128 + o];
  m[o] = s * (1.f / 64.f);
}
__global__ void k_dfeat(const float* x, const float* duc, float* df){
  int n = blockIdx.x, o = threadIdx.x; // 256
  float v;
  if (n < 8192)      v = x[(n & 127) * 256 + o];
  else if (n < 8256) v = duc[(n - 8192) * 256 + o];
  else               v = x[(n - 8256) * 256 + o];
  df[n * 256 + o] = v;
}
__global__ void k_cfin(const float* cv, const float* cm, float* cf){
  int n = blockIdx.x, o = threadIdx.x; // 128
  float v;
  if (n < 8192)      v = cv[(n >> 7) * 128 + o];
  else if (n < 8256) v = cv[(n - 8192) * 128 + o];
  else               v = cm[o];
  cf[n * 128 + o] = v;
}
// inf in bf16 (feeds MFMA feat GEMM only)
__global__ void k_inf_bf16(const float* df, const float* cfin, bf16* inf){
  int n = blockIdx.x, c = threadIdx.x; // 384
  float v = (c < 256) ? df[n * 256 + c] : cfin[n * 128 + (c - 256)];
  inf[n * 384 + c] = __float2bfloat16(v);
}
__global__ void k_zeroi(int* p, int n){
  int i = blockIdx.x * blockDim.x + threadIdx.x; if (i < n) p[i] = 0;
}
__global__ void k_copyi(const int* a, int* b, int n){
  int i = blockIdx.x * blockDim.x + threadIdx.x; if (i < n) b[i] = a[i];
}
__global__ void k_count(const int* dst, int* cnt, int e){
  int i = blockIdx.x * blockDim.x + threadIdx.x;
  if (i < e) atomicAdd(&cnt[dst[i]], 1);
}
__global__ void k_scan(const int* __restrict__ cnt, int* __restrict__ ptr, int n){
  __shared__ int part[1024];
  int tid = threadIdx.x;
  const int CH = (n + 1023) >> 10;
  int base = tid * CH;
  int s = 0;
  for (int i = 0; i < CH; i++){ int idx = base + i; if (idx < n) s += cnt[idx]; }
  part[tid] = s; __syncthreads();
  for (int off = 1; off < 1024; off <<= 1){
    int v = (tid >= off) ? part[tid - off] : 0;
    __syncthreads();
    part[tid] += v;
    __syncthreads();
  }
  int run = part[tid] - s;  // exclusive base
  for (int i = 0; i < CH; i++){
    int idx = base + i;
    if (idx < n){ ptr[idx] = run; run += cnt[idx]; }
  }
  if (tid == 1023) ptr[n] = part[1023];
}
__global__ void k_fill(const int* src, const int* dst, int* cur, int* csrc, int e){
  int i = blockIdx.x * blockDim.x + threadIdx.x;
  if (i < e){ int p = atomicAdd(&cur[dst[i]], 1); csrc[p] = src[i]; }
}
__global__ void k_elr(const float* __restrict__ feat, const float* __restrict__ al,
                      const float* __restrict__ ar, float* el, float* er){
  int n = blockIdx.x, tid = threadIdx.x; // 256
  int h = tid >> 6, lane = tid & 63;
  const float* f = feat + (size_t)n * 1024 + h * 256;
  float a = 0.f, b = 0.f;
  for (int i = lane; i < 256; i += 64){
    float fv = f[i];
    a += fv * al[h * 256 + i];
    b += fv * ar[h * 256 + i];
  }
  for (int off = 32; off; off >>= 1){ a += __shfl_down(a, off); b += __shfl_down(b, off); }
  if (lane == 0){ el[n * 4 + h] = a; er[n * 4 + h] = b; }
}

// ------------- per-dst GAT aggregation (no max pass; score moved to k_attn) -------------
__global__ __launch_bounds__(256)
void k_agg(const int* __restrict__ ptr, const int* __restrict__ srcs,
           const float* __restrict__ el, const float* __restrict__ er,
           const float* __restrict__ feat, const float* __restrict__ gb,
           bf16* __restrict__ rst, int t)
{
  const int n = blockIdx.x, tid = threadIdx.x;
  const int beg = ptr[n], deg = ptr[n + 1] - beg;
  const int h4 = tid & 3, j0 = tid >> 2;
  __shared__ float sinv[4];
  __shared__ float partial[16];
  __shared__ float sa[64][4];
  __shared__ int ssrc[64];
  float ern = er[n * 4 + h4];
  // sum of exp(leaky(el[src]+er[n])) per head  (|e| small -> exp safe without max-shift)
  float sum = 0.f;
  for (int j = j0; j < deg; j += 64){
    int s = srcs[beg + j];
    float e = el[s * 4 + h4] + ern;
    e = e > 0.f ? e : 0.2f * e;
    sum += __expf(e);
  }
  #pragma unroll
  for (int off = 4; off < 64; off <<= 1) sum += __shfl_xor(sum, off);
  int w = tid >> 6, lane = tid & 63;
  if (lane < 4) partial[w * 4 + lane] = sum;
  __syncthreads();
  if (tid < 4){
    float s0 = partial[tid] + partial[4 + tid] + partial[8 + tid] + partial[12 + tid];
    sinv[tid] = 1.f / fmaxf(s0, 1e-9f);
  }
  __syncthreads();
  float acc0 = 0.f, acc1 = 0.f, acc2 = 0.f, acc3 = 0.f;
  for (int c0 = 0; c0 < deg; c0 += 64){
    int cn = min(64, deg - c0);
    if (tid < cn) ssrc[tid] = srcs[beg + c0 + tid];
    __syncthreads();
    if (j0 < cn){
      int s = ssrc[j0];
      float e = el[s * 4 + h4] + ern;
      e = e > 0.f ? e : 0.2f * e;
      sa[j0][h4] = __expf(e) * sinv[h4];
    }
    __syncthreads();
    for (int j = 0; j < cn; j++){
      int s = ssrc[j];
      const float* fp = feat + (size_t)s * 1024;
      float w0 = sa[j][0], w1 = sa[j][1], w2 = sa[j][2], w3 = sa[j][3];
      acc0 += w0 * fp[tid];
      acc1 += w1 * fp[256 + tid];
      acc2 += w2 * fp[512 + tid];
      acc3 += w3 * fp[768 + tid];
    }
    __syncthreads();
  }
  rst[((size_t)n * 16 + t * 4 + 0) * 256 + tid] = __float2bfloat16(acc0 + gb[tid]);
  rst[((size_t)n * 16 + t * 4 + 1) * 256 + tid] = __float2bfloat16(acc1 + gb[256 + tid]);
  rst[((size_t)n * 16 + t * 4 + 2) * 256 + tid] = __float2bfloat16(acc2 + gb[512 + tid]);
  rst[((size_t)n * 16 + t * 4 + 3) * 256 + tid] = __float2bfloat16(acc3 + gb[768 + tid]);
}

// ------------- attention: scores (rst.qk), softmax over 16, rbar = sum att*rst -------------
__global__ __launch_bounds__(256)
void k_attn(const bf16* __restrict__ rst, const float* __restrict__ qk,
            float* __restrict__ rbar){
  int n = blockIdx.x, tid = threadIdx.x; // 256
  int w = tid >> 6, lane = tid & 63;
  __shared__ float ssc[16];
  const float* q = qk + (size_t)n * 256;
  #pragma unroll
  for (int si = 0; si < 4; si++){
    int s = w * 4 + si;
    const bf16* rp = rst + ((size_t)n * 16 + s) * 256;
    float v = 0.f;
    for (int o = lane; o < 256; o += 64) v += toF(rp[o]) * q[o];
    #pragma unroll
    for (int off = 32; off; off >>= 1) v += __shfl_down(v, off);
    if (lane == 0) ssc[s] = v * 0.0625f;
  }
  __syncthreads();
  float sc[16]; float m = -1e30f;
  #pragma unroll
  for (int s = 0; s < 16; s++){ sc[s] = ssc[s]; m = fmaxf(m, sc[s]); }
  float sum = 0.f;
  #pragma unroll
  for (int s = 0; s < 16; s++){ sc[s] = __expf(sc[s] - m); sum += sc[s]; }
  float inv = 1.f / sum;
  float r = 0.f;
  #pragma unroll
  for (int s = 0; s < 16; s++)
    r += sc[s] * toF(rst[((size_t)n * 16 + s) * 256 + tid]);
  rbar[(size_t)n * 256 + tid] = r * inv;
}

// ------------- folded-weight combine kernels -------------
__global__ void k_Wq(const float* wqw, const float* ipw, float* Wq){
  int c = blockIdx.x, j = threadIdx.x;
  float s = 0.f;
  for (int e = 0; e < 256; e++) s += wqw[c * 256 + e] * ipw[j * 256 + e];
  Wq[c * 256 + j] = s;
}
__global__ void k_bq(const float* wqb, const float* ipw, const float* ipb, float* bq){
  int j = threadIdx.x;
  float s = 0.f;
  for (int e = 0; e < 256; e++) s += wqb[e] * ipw[j * 256 + e];
  bq[j] = s + ipb[j];
}
__global__ void k_B2(const float* wkw, const float* ipw, float* B2){
  int j = blockIdx.x, c = threadIdx.x;
  float s = 0.f;
  for (int e = 0; e < 256; e++) s += wkw[c * 256 + e] * ipw[(256 + j) * 256 + e];
  B2[j * 256 + c] = s;
}
__global__ void k_M1(const float* ipw, const float* opw, float* M1){
  int e = blockIdx.x, j = threadIdx.x;
  float s = 0.f;
  for (int f = 0; f < 256; f++) s += ipw[(512 + f) * 256 + e] * opw[j * 256 + f];
  M1[e * 256 + j] = s;
}
__global__ void k_Wv(const float* wvw, const float* M1, float* Wv){
  int c = blockIdx.x, j = threadIdx.x;
  float s = 0.f;
  for (int e = 0; e < 256; e++) s += wvw[c * 256 + e] * M1[e * 256 + j];
  Wv[c * 256 + j] = s;
}
__global__ void k_bv(const float* wvb, const float* M1, const float* ipb,
                     const float* opw, const float* opb, float* bv){
  int j = threadIdx.x;
  float s = 0.f;
  for (int e = 0; e < 256; e++) s += wvb[e] * M1[e * 256 + j];
  for (int f = 0; f < 256; f++) s += ipb[512 + f] * opw[j * 256 + f];
  bv[j] = s + opb[j];
}

struct LWT {
  const float *gw, *al, *ar, *gb, *wqw, *wqb, *wkw, *wkb, *wvw, *wvb, *ipw, *ipb, *opw, *opb;
};

extern "C" void kernel_launch(void* const* d_in, const int* in_sizes, int n_in,
                              void* d_out, int out_size, void* d_ws, size_t ws_size,
                              hipStream_t stream)
{
  const float* x   = (const float*)d_in[0];
  const float* cf  = (const float*)d_in[1];
  const float* cfw = (const float*)d_in[2];
  const float* cfb = (const float*)d_in[3];
  const float* htw = (const float*)d_in[4];
  const float* htb = (const float*)d_in[5];
  LWT L[2];
  for (int l = 0; l < 2; l++){
    int b = 6 + l * 14;
    L[l].gw  = (const float*)d_in[b + 0];
    L[l].al  = (const float*)d_in[b + 1];
    L[l].ar  = (const float*)d_in[b + 2];
    L[l].gb  = (const float*)d_in[b + 3];
    L[l].wqw = (const float*)d_in[b + 4];
    L[l].wqb = (const float*)d_in[b + 5];
    L[l].wkw = (const float*)d_in[b + 6];
    L[l].wkb = (const float*)d_in[b + 7];
    L[l].wvw = (const float*)d_in[b + 8];
    L[l].wvb = (const float*)d_in[b + 9];
    L[l].ipw = (const float*)d_in[b + 10];
    L[l].ipb = (const float*)d_in[b + 11];
    L[l].opw = (const float*)d_in[b + 12];
    L[l].opb = (const float*)d_in[b + 13];
  }
  const int* edges = (const int*)d_in[34];

  // -------- workspace layout --------
  char* w = (char*)d_ws;
  size_t off = 0;
  auto alc = [&](size_t bytes) -> void* {
    off = (off + 255) & ~(size_t)255;
    void* p = w + off; off += bytes; return p;
  };
  float* f_cfvec = (float*)alc(64 * 128 * 4);
  float* f_cfmean= (float*)alc(128 * 4);
  float* f_duc   = (float*)alc(64 * 256 * 4);
  float* f_dfeat = (float*)alc((size_t)KN * 256 * 4);
  float* f_cfin  = (float*)alc((size_t)KN * 128 * 4);
  bf16*  b_inf   = (bf16*) alc((size_t)KN * 384 * 2);
  float* f_feat  = (float*)alc((size_t)KN * 1024 * 4);
  float* f_el    = (float*)alc((size_t)KN * 4 * 4);
  float* f_er    = (float*)alc((size_t)KN * 4 * 4);
  float* f_rbar  = (float*)alc((size_t)KN * 256 * 4);   // aliased: qt then rbar
  float* f_qt    = f_rbar;
  float* f_qk    = (float*)alc((size_t)KN * 256 * 4);
  float* f_Wq    = (float*)alc(128 * 256 * 4);
  float* f_bq    = (float*)alc(256 * 4);
  float* f_B2    = (float*)alc(256 * 256 * 4);
  float* f_M1    = (float*)alc(256 * 256 * 4);
  float* f_Wv    = (float*)alc(256 * 256 * 4);
  float* f_bv    = (float*)alc(256 * 4);
  bf16*  b_gwT   = (bf16*) alc((size_t)4 * 1024 * 384 * 2);  // per-layer transposed gw
  bf16*  b_rst   = (bf16*) alc((size_t)KN * 16 * 256 * 2);
  int*   i_ptr   = (int*)  alc((size_t)4 * (KN + 1) * 4);
  int*   i_src   = (int*)  alc((size_t)4 * KE * 4);
  int*   i_cnt   = (int*)  alc((size_t)KN * 4);
  int*   i_cur   = (int*)  alc((size_t)KN * 4);
  if (off > ws_size) return;  // visible failure: d_out stays as memset

  // -------- shared pre-phase --------
  gemm_k<float, float, float><<<dim3(2, 1), 256, 0, stream>>>(cf, cfw, cfb, f_cfvec, 64, 128, 512);
  gemm_k<float, float, float><<<dim3(4, 1), 256, 0, stream>>>(cf, htw, htb, f_duc, 64, 256, 512);
  k_mean<<<1, 128, 0, stream>>>(f_cfvec, f_cfmean);
  k_dfeat<<<KN, 256, 0, stream>>>(x, f_duc, f_dfeat);
  k_cfin <<<KN, 128, 0, stream>>>(f_cfvec, f_cfmean, f_cfin);

  // -------- CSR per relation: aggregate AT dst=edges[t,1], gather FROM src=edges[t,0] --------
  for (int t = 0; t < 4; t++){
    const int* src_t = edges + t * 2 * KE;
    const int* dst_t = src_t + KE;
    int* ptr_t  = i_ptr + t * (KN + 1);
    int* csrc_t = i_src + t * KE;
    k_zeroi<<<(KN + 255) / 256, 256, 0, stream>>>(i_cnt, KN);
    k_count<<<(KE + 255) / 256, 256, 0, stream>>>(dst_t, i_cnt, KE);
    k_scan <<<1, 1024, 0, stream>>>(i_cnt, ptr_t, KN);
    k_copyi<<<(KN + 255) / 256, 256, 0, stream>>>(ptr_t, i_cur, KN);
    k_fill <<<(KE + 255) / 256, 256, 0, stream>>>(src_t, dst_t, i_cur, csrc_t, KE);
  }

  // -------- one layer --------
  auto run_layer = [&](const LWT& Wt, const float* dfeat_in, float* outp){
    k_inf_bf16<<<KN, 384, 0, stream>>>(dfeat_in, f_cfin, b_inf);
    // transpose-cast gw for all 4 relations: [384][1024] f32 -> [1024][384] bf16
    for (int t = 0; t < 4; t++)
      k_transB<<<dim3(32, 12), dim3(32, 8), 0, stream>>>(Wt.gw + (size_t)t * 384 * 1024,
                                                         b_gwT + (size_t)t * 1024 * 384, 384, 1024);
    // folded projection weights
    k_Wq<<<128, 256, 0, stream>>>(Wt.wqw, Wt.ipw, f_Wq);
    k_bq<<<1, 256, 0, stream>>>(Wt.wqb, Wt.ipw, Wt.ipb, f_bq);
    k_B2<<<256, 256, 0, stream>>>(Wt.wkw, Wt.ipw, f_B2);
    k_M1<<<256, 256, 0, stream>>>(Wt.ipw, Wt.opw, f_M1);
    k_Wv<<<256, 256, 0, stream>>>(Wt.wvw, f_M1, f_Wv);
    k_bv<<<1, 256, 0, stream>>>(Wt.wvb, f_M1, Wt.ipb, Wt.opw, Wt.opb, f_bv);
    // q-tilde and qk (vector GEMMs, small)
    gemm_k<float, float, float><<<dim3(4, 131), 256, 0, stream>>>(f_cfin, f_Wq, f_bq, f_qt, KN, 256, 128);
    gemm_k<float, float, float><<<dim3(4, 131), 256, 0, stream>>>(f_qt, f_B2, nullptr, f_qk, KN, 256, 256);
    // 4 relations: MFMA feat GEMM + el/er + aggregation
    for (int t = 0; t < 4; t++){
      gemm_mfma_bt<<<dim3(8, 66), 256, 0, stream>>>(b_inf, b_gwT + (size_t)t * 1024 * 384,
                                                    f_feat, KN, 1024, 384);
      k_elr<<<KN, 256, 0, stream>>>(f_feat, Wt.al + t * 1024, Wt.ar + t * 1024, f_el, f_er);
      k_agg<<<KN, 256, 0, stream>>>(i_ptr + t * (KN + 1), i_src + t * KE,
                                    f_el, f_er, f_feat, Wt.gb + t * 1024, b_rst, t);
    }
    k_attn<<<KN, 256, 0, stream>>>(b_rst, f_qk, f_rbar);
    gemm_k<float, float, float><<<dim3(4, 131), 256, 0, stream>>>(f_rbar, f_Wv, f_bv, outp, KN, 256, 256);
  };

  run_layer(L[0], f_dfeat, f_dfeat);          // layer 1 -> f32 h (overwrites dfeat)
  run_layer(L[1], f_dfeat, (float*)d_out);    // layer 2 -> f32 output
}

// Round 8
// 1031.997 us; speedup vs baseline: 3.0182x; 1.2632x over previous
//
#include <hip/hip_runtime.h>
#include <hip/hip_bf16.h>

typedef __hip_bfloat16 bf16;
typedef __attribute__((ext_vector_type(8))) short short8;
typedef __attribute__((ext_vector_type(4))) float f32x4;

#define KN 8384
#define KE 50000

__device__ __forceinline__ float toF(float v){ return v; }
__device__ __forceinline__ float toF(bf16 v){ return __bfloat162float(v); }
__device__ __forceinline__ void stor(float* p, float v){ *p = v; }
__device__ __forceinline__ void stor(bf16* p, float v){ *p = __float2bfloat16(v); }

// ---------------- MFMA GEMM: C[M,N] = A[M,K]bf16 @ BT[N,K]bf16 (+bias) ----------------
// K % 32 == 0, N % 128 == 0; M guarded. 128x128 tile, 4 waves, 4x4 16x16x32 frags.
template<typename TC>
__global__ __launch_bounds__(256)
void gemm_mfma_bt(const bf16* __restrict__ A, const bf16* __restrict__ BT,
                  const float* __restrict__ bias, TC* __restrict__ C,
                  int M, int N, int K)
{
  __shared__ bf16 As[128][40];   // row stride 80 B
  __shared__ bf16 Bs[128][40];
  const int bm = blockIdx.y * 128, bn = blockIdx.x * 128;
  const int tid = threadIdx.x;
  const int w = tid >> 6, l = tid & 63;
  const int wr = (w >> 1) * 64, wc = (w & 1) * 64;
  const int lr = l & 15, ko = (l >> 4) * 8;
  f32x4 acc[4][4] = {};
  for (int k0 = 0; k0 < K; k0 += 32) {
    #pragma unroll
    for (int p = 0; p < 2; p++){
      int r = (tid >> 2) + p * 64;
      int kk = (tid & 3) * 8;
      int gr = bm + r;
      short8 va = {};
      if (gr < M) va = *(const short8*)&A[(size_t)gr * K + k0 + kk];
      *(short8*)&As[r][kk] = va;
      short8 vb = *(const short8*)&BT[(size_t)(bn + r) * K + k0 + kk];
      *(short8*)&Bs[r][kk] = vb;
    }
    __syncthreads();
    short8 a[4], b[4];
    #pragma unroll
    for (int i = 0; i < 4; i++) a[i] = *(short8*)&As[wr + i*16 + lr][ko];
    #pragma unroll
    for (int j = 0; j < 4; j++) b[j] = *(short8*)&Bs[wc + j*16 + lr][ko];
    #pragma unroll
    for (int i = 0; i < 4; i++)
      #pragma unroll
      for (int j = 0; j < 4; j++)
        acc[i][j] = __builtin_amdgcn_mfma_f32_16x16x32_bf16(a[i], b[j], acc[i][j], 0, 0, 0);
    __syncthreads();
  }
  const int orow = (l >> 4) * 4, ocol = l & 15;
  #pragma unroll
  for (int i = 0; i < 4; i++){
    #pragma unroll
    for (int j = 0; j < 4; j++){
      int gcol = bn + wc + j*16 + ocol;
      float bv = bias ? bias[gcol] : 0.f;
      #pragma unroll
      for (int rg = 0; rg < 4; rg++){
        int grow = bm + wr + i*16 + orow + rg;
        if (grow < M) stor(&C[(size_t)grow * N + gcol], acc[i][j][rg] + bv);
      }
    }
  }
}

// ---------------- transpose-cast: B f32 [K][N] -> BT bf16 [N][K] ----------------
__global__ void k_transB(const float* __restrict__ B, bf16* __restrict__ BT, int K, int N){
  __shared__ float t[32][33];
  int n0 = blockIdx.x * 32, k0 = blockIdx.y * 32;
  int tx = threadIdx.x, ty = threadIdx.y; // 32 x 8
  for (int i = ty; i < 32; i += 8)
    t[i][tx] = B[(size_t)(k0 + i) * N + n0 + tx];
  __syncthreads();
  for (int i = ty; i < 32; i += 8)
    BT[(size_t)(n0 + i) * K + k0 + tx] = __float2bfloat16(t[tx][i]);
}

// ---------------- fused small pre-GEMMs: cfvec = cf@cfw+cfb, duc = cf@htw+htb ----------------
__global__ __launch_bounds__(384)
void k_pre(const float* __restrict__ cf, const float* __restrict__ cfw, const float* __restrict__ cfb,
           const float* __restrict__ htw, const float* __restrict__ htb,
           float* __restrict__ cfvec, float* __restrict__ duc)
{
  int c = blockIdx.x;          // 0..63
  int col = threadIdx.x;       // 0..383
  __shared__ float row[512];
  for (int i = col; i < 512; i += 384) row[i] = cf[c * 512 + i];
  __syncthreads();
  if (col < 128){
    float acc = cfb[col];
    for (int k = 0; k < 512; k++) acc += row[k] * cfw[k * 128 + col];
    cfvec[c * 128 + col] = acc;
  } else {
    int j = col - 128;
    float acc = htb[j];
    for (int k = 0; k < 512; k++) acc += row[k] * htw[k * 256 + j];
    duc[c * 256 + j] = acc;
  }
}

// ---------------- small utility kernels ----------------
__global__ void k_mean(const float* cv, float* m){
  int o = threadIdx.x;  // 128
  float s = 0.f;
  for (int c = 0; c < 64; c++) s += cv[c * 128 + o];
  m[o] = s * (1.f / 64.f);
}
__global__ void k_dfeat(const float* x, const float* duc, float* df){
  int n = blockIdx.x, o = threadIdx.x; // 256
  float v;
  if (n < 8192)      v = x[(n & 127) * 256 + o];
  else if (n < 8256) v = duc[(n - 8192) * 256 + o];
  else               v = x[(n - 8256) * 256 + o];
  df[n * 256 + o] = v;
}
// cfin stored bf16 only (feeds bf16 consumers: inf assembly + qt MFMA)
__global__ void k_cfin(const float* cv, const float* cm, bf16* cf){
  int n = blockIdx.x, o = threadIdx.x; // 128
  float v;
  if (n < 8192)      v = cv[(n >> 7) * 128 + o];
  else if (n < 8256) v = cv[(n - 8192) * 128 + o];
  else               v = cm[o];
  cf[n * 128 + o] = __float2bfloat16(v);
}
__global__ void k_inf_bf16(const float* df, const bf16* cfin, bf16* inf){
  int n = blockIdx.x, c = threadIdx.x; // 384
  bf16 v = (c < 256) ? __float2bfloat16(df[n * 256 + c]) : cfin[n * 128 + (c - 256)];
  inf[n * 384 + c] = v;
}
__global__ void k_zeroi(int* p, int n){
  int i = blockIdx.x * blockDim.x + threadIdx.x; if (i < n) p[i] = 0;
}
__global__ void k_copyi(const int* a, int* b, int n){
  int i = blockIdx.x * blockDim.x + threadIdx.x; if (i < n) b[i] = a[i];
}
__global__ void k_count(const int* dst, int* cnt, int e){
  int i = blockIdx.x * blockDim.x + threadIdx.x;
  if (i < e) atomicAdd(&cnt[dst[i]], 1);
}
__global__ void k_scan(const int* __restrict__ cnt, int* __restrict__ ptr, int n){
  __shared__ int part[1024];
  int tid = threadIdx.x;
  const int CH = (n + 1023) >> 10;
  int base = tid * CH;
  int s = 0;
  for (int i = 0; i < CH; i++){ int idx = base + i; if (idx < n) s += cnt[idx]; }
  part[tid] = s; __syncthreads();
  for (int off = 1; off < 1024; off <<= 1){
    int v = (tid >= off) ? part[tid - off] : 0;
    __syncthreads();
    part[tid] += v;
    __syncthreads();
  }
  int run = part[tid] - s;  // exclusive base
  for (int i = 0; i < CH; i++){
    int idx = base + i;
    if (idx < n){ ptr[idx] = run; run += cnt[idx]; }
  }
  if (tid == 1023) ptr[n] = part[1023];
}
__global__ void k_fill(const int* src, const int* dst, int* cur, int* csrc, int e){
  int i = blockIdx.x * blockDim.x + threadIdx.x;
  if (i < e){ int p = atomicAdd(&cur[dst[i]], 1); csrc[p] = src[i]; }
}
__global__ void k_elr(const float* __restrict__ feat, const float* __restrict__ al,
                      const float* __restrict__ ar, float* el, float* er){
  int n = blockIdx.x, tid = threadIdx.x; // 256
  int h = tid >> 6, lane = tid & 63;
  const float* f = feat + (size_t)n * 1024 + h * 256;
  float a = 0.f, b = 0.f;
  for (int i = lane; i < 256; i += 64){
    float fv = f[i];
    a += fv * al[h * 256 + i];
    b += fv * ar[h * 256 + i];
  }
  for (int off = 32; off; off >>= 1){ a += __shfl_down(a, off); b += __shfl_down(b, off); }
  if (lane == 0){ el[n * 4 + h] = a; er[n * 4 + h] = b; }
}

// ------------- per-dst GAT aggregation -------------
__global__ __launch_bounds__(256)
void k_agg(const int* __restrict__ ptr, const int* __restrict__ srcs,
           const float* __restrict__ el, const float* __restrict__ er,
           const float* __restrict__ feat, const float* __restrict__ gb,
           bf16* __restrict__ rst, int t)
{
  const int n = blockIdx.x, tid = threadIdx.x;
  const int beg = ptr[n], deg = ptr[n + 1] - beg;
  const int h4 = tid & 3, j0 = tid >> 2;
  __shared__ float sinv[4];
  __shared__ float partial[16];
  __shared__ float sa[64][4];
  __shared__ int ssrc[64];
  float ern = er[n * 4 + h4];
  float sum = 0.f;
  for (int j = j0; j < deg; j += 64){
    int s = srcs[beg + j];
    float e = el[s * 4 + h4] + ern;
    e = e > 0.f ? e : 0.2f * e;
    sum += __expf(e);
  }
  #pragma unroll
  for (int off = 4; off < 64; off <<= 1) sum += __shfl_xor(sum, off);
  int w = tid >> 6, lane = tid & 63;
  if (lane < 4) partial[w * 4 + lane] = sum;
  __syncthreads();
  if (tid < 4){
    float s0 = partial[tid] + partial[4 + tid] + partial[8 + tid] + partial[12 + tid];
    sinv[tid] = 1.f / fmaxf(s0, 1e-9f);
  }
  __syncthreads();
  float acc0 = 0.f, acc1 = 0.f, acc2 = 0.f, acc3 = 0.f;
  for (int c0 = 0; c0 < deg; c0 += 64){
    int cn = min(64, deg - c0);
    if (tid < cn) ssrc[tid] = srcs[beg + c0 + tid];
    __syncthreads();
    if (j0 < cn){
      int s = ssrc[j0];
      float e = el[s * 4 + h4] + ern;
      e = e > 0.f ? e : 0.2f * e;
      sa[j0][h4] = __expf(e) * sinv[h4];
    }
    __syncthreads();
    for (int j = 0; j < cn; j++){
      int s = ssrc[j];
      const float* fp = feat + (size_t)s * 1024;
      float w0 = sa[j][0], w1 = sa[j][1], w2 = sa[j][2], w3 = sa[j][3];
      acc0 += w0 * fp[tid];
      acc1 += w1 * fp[256 + tid];
      acc2 += w2 * fp[512 + tid];
      acc3 += w3 * fp[768 + tid];
    }
    __syncthreads();
  }
  rst[((size_t)n * 16 + t * 4 + 0) * 256 + tid] = __float2bfloat16(acc0 + gb[tid]);
  rst[((size_t)n * 16 + t * 4 + 1) * 256 + tid] = __float2bfloat16(acc1 + gb[256 + tid]);
  rst[((size_t)n * 16 + t * 4 + 2) * 256 + tid] = __float2bfloat16(acc2 + gb[512 + tid]);
  rst[((size_t)n * 16 + t * 4 + 3) * 256 + tid] = __float2bfloat16(acc3 + gb[768 + tid]);
}

// ------------- attention: scores (rst.qk), softmax over 16, rbar(bf16) = sum att*rst -------------
__global__ __launch_bounds__(256)
void k_attn(const bf16* __restrict__ rst, const float* __restrict__ qk,
            bf16* __restrict__ rbar){
  int n = blockIdx.x, tid = threadIdx.x; // 256
  int w = tid >> 6, lane = tid & 63;
  __shared__ float ssc[16];
  const float* q = qk + (size_t)n * 256;
  #pragma unroll
  for (int si = 0; si < 4; si++){
    int s = w * 4 + si;
    const bf16* rp = rst + ((size_t)n * 16 + s) * 256;
    float v = 0.f;
    for (int o = lane; o < 256; o += 64) v += toF(rp[o]) * q[o];
    #pragma unroll
    for (int off = 32; off; off >>= 1) v += __shfl_down(v, off);
    if (lane == 0) ssc[s] = v * 0.0625f;
  }
  __syncthreads();
  float sc[16]; float m = -1e30f;
  #pragma unroll
  for (int s = 0; s < 16; s++){ sc[s] = ssc[s]; m = fmaxf(m, sc[s]); }
  float sum = 0.f;
  #pragma unroll
  for (int s = 0; s < 16; s++){ sc[s] = __expf(sc[s] - m); sum += sc[s]; }
  float inv = 1.f / sum;
  float r = 0.f;
  #pragma unroll
  for (int s = 0; s < 16; s++)
    r += sc[s] * toF(rst[((size_t)n * 16 + s) * 256 + tid]);
  rbar[(size_t)n * 256 + tid] = __float2bfloat16(r * inv);
}

// ------------- folded-weight combine kernels (f32, then transposed-cast to bf16) -------------
__global__ void k_Wq(const float* wqw, const float* ipw, float* Wq){
  int c = blockIdx.x, j = threadIdx.x;
  float s = 0.f;
  for (int e = 0; e < 256; e++) s += wqw[c * 256 + e] * ipw[j * 256 + e];
  Wq[c * 256 + j] = s;
}
__global__ void k_bq(const float* wqb, const float* ipw, const float* ipb, float* bq){
  int j = threadIdx.x;
  float s = 0.f;
  for (int e = 0; e < 256; e++) s += wqb[e] * ipw[j * 256 + e];
  bq[j] = s + ipb[j];
}
__global__ void k_B2(const float* wkw, const float* ipw, float* B2){
  int j = blockIdx.x, c = threadIdx.x;
  float s = 0.f;
  for (int e = 0; e < 256; e++) s += wkw[c * 256 + e] * ipw[(256 + j) * 256 + e];
  B2[j * 256 + c] = s;
}
__global__ void k_M1(const float* ipw, const float* opw, float* M1){
  int e = blockIdx.x, j = threadIdx.x;
  float s = 0.f;
  for (int f = 0; f < 256; f++) s += ipw[(512 + f) * 256 + e] * opw[j * 256 + f];
  M1[e * 256 + j] = s;
}
__global__ void k_Wv(const float* wvw, const float* M1, float* Wv){
  int c = blockIdx.x, j = threadIdx.x;
  float s = 0.f;
  for (int e = 0; e < 256; e++) s += wvw[c * 256 + e] * M1[e * 256 + j];
  Wv[c * 256 + j] = s;
}
__global__ void k_bv(const float* wvb, const float* M1, const float* ipb,
                     const float* opw, const float* opb, float* bv){
  int j = threadIdx.x;
  float s = 0.f;
  for (int e = 0; e < 256; e++) s += wvb[e] * M1[e * 256 + j];
  for (int f = 0; f < 256; f++) s += ipb[512 + f] * opw[j * 256 + f];
  bv[j] = s + opb[j];
}

struct LWT {
  const float *gw, *al, *ar, *gb, *wqw, *wqb, *wkw, *wkb, *wvw, *wvb, *ipw, *ipb, *opw, *opb;
};

extern "C" void kernel_launch(void* const* d_in, const int* in_sizes, int n_in,
                              void* d_out, int out_size, void* d_ws, size_t ws_size,
                              hipStream_t stream)
{
  const float* x   = (const float*)d_in[0];
  const float* cf  = (const float*)d_in[1];
  const float* cfw = (const float*)d_in[2];
  const float* cfb = (const float*)d_in[3];
  const float* htw = (const float*)d_in[4];
  const float* htb = (const float*)d_in[5];
  LWT L[2];
  for (int l = 0; l < 2; l++){
    int b = 6 + l * 14;
    L[l].gw  = (const float*)d_in[b + 0];
    L[l].al  = (const float*)d_in[b + 1];
    L[l].ar  = (const float*)d_in[b + 2];
    L[l].gb  = (const float*)d_in[b + 3];
    L[l].wqw = (const float*)d_in[b + 4];
    L[l].wqb = (const float*)d_in[b + 5];
    L[l].wkw = (const float*)d_in[b + 6];
    L[l].wkb = (const float*)d_in[b + 7];
    L[l].wvw = (const float*)d_in[b + 8];
    L[l].wvb = (const float*)d_in[b + 9];
    L[l].ipw = (const float*)d_in[b + 10];
    L[l].ipb = (const float*)d_in[b + 11];
    L[l].opw = (const float*)d_in[b + 12];
    L[l].opb = (const float*)d_in[b + 13];
  }
  const int* edges = (const int*)d_in[34];

  // -------- workspace layout --------
  char* w = (char*)d_ws;
  size_t off = 0;
  auto alc = [&](size_t bytes) -> void* {
    off = (off + 255) & ~(size_t)255;
    void* p = w + off; off += bytes; return p;
  };
  float* f_cfvec = (float*)alc(64 * 128 * 4);
  float* f_cfmean= (float*)alc(128 * 4);
  float* f_duc   = (float*)alc(64 * 256 * 4);
  float* f_dfeat = (float*)alc((size_t)KN * 256 * 4);
  bf16*  b_cfin  = (bf16*) alc((size_t)KN * 128 * 2);
  bf16*  b_inf   = (bf16*) alc((size_t)KN * 384 * 2);
  float* f_feat  = (float*)alc((size_t)KN * 1024 * 4);
  float* f_el    = (float*)alc((size_t)KN * 4 * 4);
  float* f_er    = (float*)alc((size_t)KN * 4 * 4);
  bf16*  b_qt    = (bf16*) alc((size_t)KN * 256 * 2);
  bf16*  b_rbar  = (bf16*) alc((size_t)KN * 256 * 2);
  float* f_qk    = (float*)alc((size_t)KN * 256 * 4);
  float* f_Wq    = (float*)alc(128 * 256 * 4);
  float* f_bq    = (float*)alc(256 * 4);
  float* f_B2    = (float*)alc(256 * 256 * 4);
  float* f_M1    = (float*)alc(256 * 256 * 4);
  float* f_Wv    = (float*)alc(256 * 256 * 4);
  float* f_bv    = (float*)alc(256 * 4);
  bf16*  b_WqT   = (bf16*) alc(256 * 128 * 2);
  bf16*  b_B2T   = (bf16*) alc(256 * 256 * 2);
  bf16*  b_WvT   = (bf16*) alc(256 * 256 * 2);
  bf16*  b_gwT   = (bf16*) alc((size_t)4 * 1024 * 384 * 2);
  bf16*  b_rst   = (bf16*) alc((size_t)KN * 16 * 256 * 2);
  int*   i_ptr   = (int*)  alc((size_t)4 * (KN + 1) * 4);
  int*   i_src   = (int*)  alc((size_t)4 * KE * 4);
  int*   i_cnt   = (int*)  alc((size_t)KN * 4);
  int*   i_cur   = (int*)  alc((size_t)KN * 4);
  if (off > ws_size) return;  // visible failure: d_out stays as memset

  // -------- shared pre-phase --------
  k_pre<<<64, 384, 0, stream>>>(cf, cfw, cfb, htw, htb, f_cfvec, f_duc);
  k_mean<<<1, 128, 0, stream>>>(f_cfvec, f_cfmean);
  k_dfeat<<<KN, 256, 0, stream>>>(x, f_duc, f_dfeat);
  k_cfin <<<KN, 128, 0, stream>>>(f_cfvec, f_cfmean, b_cfin);

  // -------- CSR per relation: aggregate AT dst=edges[t,1], gather FROM src=edges[t,0] --------
  for (int t = 0; t < 4; t++){
    const int* src_t = edges + t * 2 * KE;
    const int* dst_t = src_t + KE;
    int* ptr_t  = i_ptr + t * (KN + 1);
    int* csrc_t = i_src + t * KE;
    k_zeroi<<<(KN + 255) / 256, 256, 0, stream>>>(i_cnt, KN);
    k_count<<<(KE + 255) / 256, 256, 0, stream>>>(dst_t, i_cnt, KE);
    k_scan <<<1, 1024, 0, stream>>>(i_cnt, ptr_t, KN);
    k_copyi<<<(KN + 255) / 256, 256, 0, stream>>>(ptr_t, i_cur, KN);
    k_fill <<<(KE + 255) / 256, 256, 0, stream>>>(src_t, dst_t, i_cur, csrc_t, KE);
  }

  // -------- one layer --------
  auto run_layer = [&](const LWT& Wt, const float* dfeat_in, float* outp){
    k_inf_bf16<<<KN, 384, 0, stream>>>(dfeat_in, b_cfin, b_inf);
    for (int t = 0; t < 4; t++)
      k_transB<<<dim3(32, 12), dim3(32, 8), 0, stream>>>(Wt.gw + (size_t)t * 384 * 1024,
                                                         b_gwT + (size_t)t * 1024 * 384, 384, 1024);
    // folded projection weights (f32) + transpose-cast to bf16 BT
    k_Wq<<<128, 256, 0, stream>>>(Wt.wqw, Wt.ipw, f_Wq);
    k_bq<<<1, 256, 0, stream>>>(Wt.wqb, Wt.ipw, Wt.ipb, f_bq);
    k_B2<<<256, 256, 0, stream>>>(Wt.wkw, Wt.ipw, f_B2);
    k_M1<<<256, 256, 0, stream>>>(Wt.ipw, Wt.opw, f_M1);
    k_Wv<<<256, 256, 0, stream>>>(Wt.wvw, f_M1, f_Wv);
    k_bv<<<1, 256, 0, stream>>>(Wt.wvb, f_M1, Wt.ipb, Wt.opw, Wt.opb, f_bv);
    k_transB<<<dim3(8, 4), dim3(32, 8), 0, stream>>>(f_Wq, b_WqT, 128, 256);
    k_transB<<<dim3(8, 8), dim3(32, 8), 0, stream>>>(f_B2, b_B2T, 256, 256);
    k_transB<<<dim3(8, 8), dim3(32, 8), 0, stream>>>(f_Wv, b_WvT, 256, 256);
    // qt (bf16 out) and qk (f32) via MFMA
    gemm_mfma_bt<bf16> <<<dim3(2, 66), 256, 0, stream>>>(b_cfin, b_WqT, f_bq, b_qt, KN, 256, 128);
    gemm_mfma_bt<float><<<dim3(2, 66), 256, 0, stream>>>(b_qt, b_B2T, nullptr, f_qk, KN, 256, 256);
    // 4 relations: MFMA feat GEMM + el/er + aggregation
    for (int t = 0; t < 4; t++){
      gemm_mfma_bt<float><<<dim3(8, 66), 256, 0, stream>>>(b_inf, b_gwT + (size_t)t * 1024 * 384,
                                                           nullptr, f_feat, KN, 1024, 384);
      k_elr<<<KN, 256, 0, stream>>>(f_feat, Wt.al + t * 1024, Wt.ar + t * 1024, f_el, f_er);
      k_agg<<<KN, 256, 0, stream>>>(i_ptr + t * (KN + 1), i_src + t * KE,
                                    f_el, f_er, f_feat, Wt.gb + t * 1024, b_rst, t);
    }
    k_attn<<<KN, 256, 0, stream>>>(b_rst, f_qk, b_rbar);
    gemm_mfma_bt<float><<<dim3(2, 66), 256, 0, stream>>>(b_rbar, b_WvT, f_bv, outp, KN, 256, 256);
  };

  run_layer(L[0], f_dfeat, f_dfeat);          // layer 1 -> f32 h (overwrites dfeat)
  run_layer(L[1], f_dfeat, (float*)d_out);    // layer 2 -> f32 output
}

// Round 10
// 802.900 us; speedup vs baseline: 3.8794x; 1.2853x over previous
//
#include <hip/hip_runtime.h>
#include <hip/hip_bf16.h>

typedef __hip_bfloat16 bf16;
typedef __attribute__((ext_vector_type(8))) short short8;
typedef __attribute__((ext_vector_type(4))) short short4v;
typedef __attribute__((ext_vector_type(4))) float f32x4;

#define KN 8384
#define KE 50000

__device__ __forceinline__ float toF(float v){ return v; }
__device__ __forceinline__ float toF(bf16 v){ return __bfloat162float(v); }
__device__ __forceinline__ float b2f(short u){ return __uint_as_float(((unsigned int)(unsigned short)u) << 16); }
__device__ __forceinline__ void stor(float* p, float v){ *p = v; }
__device__ __forceinline__ void stor(bf16* p, float v){ *p = __float2bfloat16(v); }

// ---------------- MFMA GEMM: C[M,N] = A[M,K]bf16 @ BT[N,K]bf16 (+bias) ----------------
template<typename TC>
__global__ __launch_bounds__(256)
void gemm_mfma_bt(const bf16* __restrict__ A, const bf16* __restrict__ BT,
                  const float* __restrict__ bias, TC* __restrict__ C,
                  int M, int N, int K)
{
  __shared__ bf16 As[128][40];
  __shared__ bf16 Bs[128][40];
  const int bm = blockIdx.y * 128, bn = blockIdx.x * 128;
  const int tid = threadIdx.x;
  const int w = tid >> 6, l = tid & 63;
  const int wr = (w >> 1) * 64, wc = (w & 1) * 64;
  const int lr = l & 15, ko = (l >> 4) * 8;
  f32x4 acc[4][4] = {};
  for (int k0 = 0; k0 < K; k0 += 32) {
    #pragma unroll
    for (int p = 0; p < 2; p++){
      int r = (tid >> 2) + p * 64;
      int kk = (tid & 3) * 8;
      int gr = bm + r;
      short8 va = {};
      if (gr < M) va = *(const short8*)&A[(size_t)gr * K + k0 + kk];
      *(short8*)&As[r][kk] = va;
      short8 vb = *(const short8*)&BT[(size_t)(bn + r) * K + k0 + kk];
      *(short8*)&Bs[r][kk] = vb;
    }
    __syncthreads();
    short8 a[4], b[4];
    #pragma unroll
    for (int i = 0; i < 4; i++) a[i] = *(short8*)&As[wr + i*16 + lr][ko];
    #pragma unroll
    for (int j = 0; j < 4; j++) b[j] = *(short8*)&Bs[wc + j*16 + lr][ko];
    #pragma unroll
    for (int i = 0; i < 4; i++)
      #pragma unroll
      for (int j = 0; j < 4; j++)
        acc[i][j] = __builtin_amdgcn_mfma_f32_16x16x32_bf16(a[i], b[j], acc[i][j], 0, 0, 0);
    __syncthreads();
  }
  const int orow = (l >> 4) * 4, ocol = l & 15;
  #pragma unroll
  for (int i = 0; i < 4; i++){
    #pragma unroll
    for (int j = 0; j < 4; j++){
      int gcol = bn + wc + j*16 + ocol;
      float bv = bias ? bias[gcol] : 0.f;
      #pragma unroll
      for (int rg = 0; rg < 4; rg++){
        int grow = bm + wr + i*16 + orow + rg;
        if (grow < M) stor(&C[(size_t)grow * N + gcol], acc[i][j][rg] + bv);
      }
    }
  }
}

// ---------------- transpose-cast: B f32 [K][N] -> BT bf16 [N][K] ----------------
__global__ void k_transB(const float* __restrict__ B, bf16* __restrict__ BT, int K, int N){
  __shared__ float t[32][33];
  int n0 = blockIdx.x * 32, k0 = blockIdx.y * 32;
  int tx = threadIdx.x, ty = threadIdx.y; // 32 x 8
  for (int i = ty; i < 32; i += 8)
    t[i][tx] = B[(size_t)(k0 + i) * N + n0 + tx];
  __syncthreads();
  for (int i = ty; i < 32; i += 8)
    BT[(size_t)(n0 + i) * K + k0 + tx] = __float2bfloat16(t[tx][i]);
}
// batched over 4 relations: gw[t] f32 [384][1024] -> gwT rows [t*1024..)
__global__ void k_transGW(const float* __restrict__ gw, bf16* __restrict__ gwT){
  __shared__ float t[32][33];
  int rel = blockIdx.z;
  const float* B = gw + (size_t)rel * 384 * 1024;
  bf16* BT = gwT + (size_t)rel * 1024 * 384;
  int n0 = blockIdx.x * 32, k0 = blockIdx.y * 32;
  int tx = threadIdx.x, ty = threadIdx.y;
  for (int i = ty; i < 32; i += 8)
    t[i][tx] = B[(size_t)(k0 + i) * 1024 + n0 + tx];
  __syncthreads();
  for (int i = ty; i < 32; i += 8)
    BT[(size_t)(n0 + i) * 384 + k0 + tx] = __float2bfloat16(t[tx][i]);
}

// ---------------- fused small pre-GEMMs ----------------
__global__ __launch_bounds__(384)
void k_pre(const float* __restrict__ cf, const float* __restrict__ cfw, const float* __restrict__ cfb,
           const float* __restrict__ htw, const float* __restrict__ htb,
           float* __restrict__ cfvec, float* __restrict__ duc)
{
  int c = blockIdx.x;          // 0..63
  int col = threadIdx.x;       // 0..383
  __shared__ float row[512];
  for (int i = col; i < 512; i += 384) row[i] = cf[c * 512 + i];
  __syncthreads();
  if (col < 128){
    float acc = cfb[col];
    for (int k = 0; k < 512; k++) acc += row[k] * cfw[k * 128 + col];
    cfvec[c * 128 + col] = acc;
  } else {
    int j = col - 128;
    float acc = htb[j];
    for (int k = 0; k < 512; k++) acc += row[k] * htw[k * 256 + j];
    duc[c * 256 + j] = acc;
  }
}

// ---------------- small utility kernels ----------------
__global__ void k_mean(const float* cv, float* m){
  int o = threadIdx.x;
  float s = 0.f;
  for (int c = 0; c < 64; c++) s += cv[c * 128 + o];
  m[o] = s * (1.f / 64.f);
}
__global__ void k_dfeat(const float* x, const float* duc, float* df){
  int n = blockIdx.x, o = threadIdx.x;
  float v;
  if (n < 8192)      v = x[(n & 127) * 256 + o];
  else if (n < 8256) v = duc[(n - 8192) * 256 + o];
  else               v = x[(n - 8256) * 256 + o];
  df[n * 256 + o] = v;
}
__global__ void k_cfin(const float* cv, const float* cm, bf16* cf){
  int n = blockIdx.x, o = threadIdx.x;
  float v;
  if (n < 8192)      v = cv[(n >> 7) * 128 + o];
  else if (n < 8256) v = cv[(n - 8192) * 128 + o];
  else               v = cm[o];
  cf[n * 128 + o] = __float2bfloat16(v);
}
__global__ void k_inf_bf16(const float* df, const bf16* cfin, bf16* inf){
  int n = blockIdx.x, c = threadIdx.x;
  bf16 v = (c < 256) ? __float2bfloat16(df[n * 256 + c]) : cfin[n * 128 + (c - 256)];
  inf[n * 384 + c] = v;
}
__global__ void k_zeroi(int* p, int n){
  int i = blockIdx.x * blockDim.x + threadIdx.x; if (i < n) p[i] = 0;
}
__global__ void k_copyi(const int* a, int* b, int n){
  int i = blockIdx.x * blockDim.x + threadIdx.x; if (i < n) b[i] = a[i];
}
// batched CSR over 4 relations
__global__ void k_countB(const int* __restrict__ edges, int* __restrict__ cnt){
  int i = blockIdx.x * blockDim.x + threadIdx.x;
  if (i < 4 * KE){
    int t = i / KE, idx = i - t * KE;
    int d = edges[t * 2 * KE + KE + idx];
    atomicAdd(&cnt[t * KN + d], 1);
  }
}
__global__ void k_fillB(const int* __restrict__ edges, int* __restrict__ cur, int* __restrict__ csrc){
  int i = blockIdx.x * blockDim.x + threadIdx.x;
  if (i < 4 * KE){
    int t = i / KE, idx = i - t * KE;
    int s = edges[t * 2 * KE + idx];
    int d = edges[t * 2 * KE + KE + idx];
    int p = atomicAdd(&cur[t * KN + d], 1);
    csrc[p] = s;
  }
}
__global__ void k_scan(const int* __restrict__ cnt, int* __restrict__ ptr, int n){
  __shared__ int part[1024];
  int tid = threadIdx.x;
  const int CH = (n + 1023) >> 10;
  int base = tid * CH;
  int s = 0;
  for (int i = 0; i < CH; i++){ int idx = base + i; if (idx < n) s += cnt[idx]; }
  part[tid] = s; __syncthreads();
  for (int off = 1; off < 1024; off <<= 1){
    int v = (tid >= off) ? part[tid - off] : 0;
    __syncthreads();
    part[tid] += v;
    __syncthreads();
  }
  int run = part[tid] - s;
  for (int i = 0; i < CH; i++){
    int idx = base + i;
    if (idx < n){ ptr[idx] = run; run += cnt[idx]; }
  }
  if (tid == 1023) ptr[n] = part[1023];
}

// el/er for all 4 relations: feat bf16 [KN][4096], el/er [4][KN][4]
__global__ __launch_bounds__(256)
void k_elr(const bf16* __restrict__ feat, const float* __restrict__ al,
           const float* __restrict__ ar, float* __restrict__ el, float* __restrict__ er){
  int n = blockIdx.x, t = blockIdx.y, tid = threadIdx.x;
  int h = tid >> 6, lane = tid & 63;
  const bf16* f = feat + (size_t)n * 4096 + t * 1024 + h * 256;
  const float* alh = al + t * 1024 + h * 256;
  const float* arh = ar + t * 1024 + h * 256;
  short4v v = *(const short4v*)&f[lane * 4];
  float a = 0.f, b = 0.f;
  #pragma unroll
  for (int i = 0; i < 4; i++){
    float fv = b2f(v[i]);
    a += fv * alh[lane * 4 + i];
    b += fv * arh[lane * 4 + i];
  }
  #pragma unroll
  for (int off = 32; off; off >>= 1){ a += __shfl_down(a, off); b += __shfl_down(b, off); }
  if (lane == 0){
    el[((size_t)t * KN + n) * 4 + h] = a;
    er[((size_t)t * KN + n) * 4 + h] = b;
  }
}

// ------------- per-dst GAT aggregation, all relations (grid.y = t), bf16 gather -------------
__global__ __launch_bounds__(256)
void k_agg(const int* __restrict__ ptr, const int* __restrict__ csrc,
           const float* __restrict__ el, const float* __restrict__ er,
           const bf16* __restrict__ feat, const float* __restrict__ gb,
           bf16* __restrict__ rst)
{
  const int n = blockIdx.x, t = blockIdx.y, tid = threadIdx.x;
  const int beg = ptr[t * KN + n], deg = ptr[t * KN + n + 1] - beg;
  const int h4 = tid & 3, j0 = tid >> 2;
  __shared__ float sinv[4];
  __shared__ float partial[16];
  __shared__ float sa[64][4];
  __shared__ int ssrc[64];
  const float* elt = el + (size_t)t * KN * 4;
  float ern = er[((size_t)t * KN + n) * 4 + h4];
  float sum = 0.f;
  for (int j = j0; j < deg; j += 64){
    int s = csrc[beg + j];
    float e = elt[s * 4 + h4] + ern;
    e = e > 0.f ? e : 0.2f * e;
    sum += __expf(e);
  }
  #pragma unroll
  for (int off = 4; off < 64; off <<= 1) sum += __shfl_xor(sum, off);
  int w = tid >> 6, lane = tid & 63;
  if (lane < 4) partial[w * 4 + lane] = sum;
  __syncthreads();
  if (tid < 4){
    float s0 = partial[tid] + partial[4 + tid] + partial[8 + tid] + partial[12 + tid];
    sinv[tid] = 1.f / fmaxf(s0, 1e-9f);
  }
  __syncthreads();
  // gather: thread owns head = tid>>6, 4 consecutive cols c4 = (tid&63)*4
  const int head = tid >> 6, c4 = (tid & 63) * 4;
  float acc0 = 0.f, acc1 = 0.f, acc2 = 0.f, acc3 = 0.f;
  const size_t foff = (size_t)t * 1024 + head * 256 + c4;
  for (int c0 = 0; c0 < deg; c0 += 64){
    int cn = min(64, deg - c0);
    if (tid < cn) ssrc[tid] = csrc[beg + c0 + tid];
    __syncthreads();
    if (j0 < cn){
      int s = ssrc[j0];
      float e = elt[s * 4 + h4] + ern;
      e = e > 0.f ? e : 0.2f * e;
      sa[j0][h4] = __expf(e) * sinv[h4];
    }
    __syncthreads();
    for (int j = 0; j < cn; j++){
      int s = ssrc[j];
      float wj = sa[j][head];
      short4v v = *(const short4v*)&feat[(size_t)s * 4096 + foff];
      acc0 += wj * b2f(v[0]);
      acc1 += wj * b2f(v[1]);
      acc2 += wj * b2f(v[2]);
      acc3 += wj * b2f(v[3]);
    }
    __syncthreads();
  }
  const float* gbh = gb + t * 1024 + head * 256 + c4;
  bf16* rp = rst + ((size_t)n * 16 + t * 4 + head) * 256 + c4;
  rp[0] = __float2bfloat16(acc0 + gbh[0]);
  rp[1] = __float2bfloat16(acc1 + gbh[1]);
  rp[2] = __float2bfloat16(acc2 + gbh[2]);
  rp[3] = __float2bfloat16(acc3 + gbh[3]);
}

// ------------- attention: scores (rst.qk), softmax over 16, rbar(bf16) -------------
__global__ __launch_bounds__(256)
void k_attn(const bf16* __restrict__ rst, const float* __restrict__ qk,
            bf16* __restrict__ rbar){
  int n = blockIdx.x, tid = threadIdx.x;
  int w = tid >> 6, lane = tid & 63;
  __shared__ float ssc[16];
  const float* q = qk + (size_t)n * 256;
  #pragma unroll
  for (int si = 0; si < 4; si++){
    int s = w * 4 + si;
    const bf16* rp = rst + ((size_t)n * 16 + s) * 256;
    float v = 0.f;
    for (int o = lane; o < 256; o += 64) v += toF(rp[o]) * q[o];
    #pragma unroll
    for (int off = 32; off; off >>= 1) v += __shfl_down(v, off);
    if (lane == 0) ssc[s] = v * 0.0625f;
  }
  __syncthreads();
  float sc[16]; float m = -1e30f;
  #pragma unroll
  for (int s = 0; s < 16; s++){ sc[s] = ssc[s]; m = fmaxf(m, sc[s]); }
  float sum = 0.f;
  #pragma unroll
  for (int s = 0; s < 16; s++){ sc[s] = __expf(sc[s] - m); sum += sc[s]; }
  float inv = 1.f / sum;
  float r = 0.f;
  #pragma unroll
  for (int s = 0; s < 16; s++)
    r += sc[s] * toF(rst[((size_t)n * 16 + s) * 256 + tid]);
  rbar[(size_t)n * 256 + tid] = __float2bfloat16(r * inv);
}

// ------------- folded-weight combine kernels -------------
__global__ void k_Wq(const float* wqw, const float* ipw, float* Wq){
  int c = blockIdx.x, j = threadIdx.x;
  float s = 0.f;
  for (int e = 0; e < 256; e++) s += wqw[c * 256 + e] * ipw[j * 256 + e];
  Wq[c * 256 + j] = s;
}
__global__ void k_bq(const float* wqb, const float* ipw, const float* ipb, float* bq){
  int j = threadIdx.x;
  float s = 0.f;
  for (int e = 0; e < 256; e++) s += wqb[e] * ipw[j * 256 + e];
  bq[j] = s + ipb[j];
}
__global__ void k_B2(const float* wkw, const float* ipw, float* B2){
  int j = blockIdx.x, c = threadIdx.x;
  float s = 0.f;
  for (int e = 0; e < 256; e++) s += wkw[c * 256 + e] * ipw[(256 + j) * 256 + e];
  B2[j * 256 + c] = s;
}
__global__ void k_M1(const float* ipw, const float* opw, float* M1){
  int e = blockIdx.x, j = threadIdx.x;
  float s = 0.f;
  for (int f = 0; f < 256; f++) s += ipw[(512 + f) * 256 + e] * opw[j * 256 + f];
  M1[e * 256 + j] = s;
}
__global__ void k_Wv(const float* wvw, const float* M1, float* Wv){
  int c = blockIdx.x, j = threadIdx.x;
  float s = 0.f;
  for (int e = 0; e < 256; e++) s += wvw[c * 256 + e] * M1[e * 256 + j];
  Wv[c * 256 + j] = s;
}
__global__ void k_bv(const float* wvb, const float* M1, const float* ipb,
                     const float* opw, const float* opb, float* bv){
  int j = threadIdx.x;
  float s = 0.f;
  for (int e = 0; e < 256; e++) s += wvb[e] * M1[e * 256 + j];
  for (int f = 0; f < 256; f++) s += ipb[512 + f] * opw[j * 256 + f];
  bv[j] = s + opb[j];
}

struct LWT {
  const float *gw, *al, *ar, *gb, *wqw, *wqb, *wkw, *wkb, *wvw, *wvb, *ipw, *ipb, *opw, *opb;
};

extern "C" void kernel_launch(void* const* d_in, const int* in_sizes, int n_in,
                              void* d_out, int out_size, void* d_ws, size_t ws_size,
                              hipStream_t stream)
{
  const float* x   = (const float*)d_in[0];
  const float* cf  = (const float*)d_in[1];
  const float* cfw = (const float*)d_in[2];
  const float* cfb = (const float*)d_in[3];
  const float* htw = (const float*)d_in[4];
  const float* htb = (const float*)d_in[5];
  LWT L[2];
  for (int l = 0; l < 2; l++){
    int b = 6 + l * 14;
    L[l].gw  = (const float*)d_in[b + 0];
    L[l].al  = (const float*)d_in[b + 1];
    L[l].ar  = (const float*)d_in[b + 2];
    L[l].gb  = (const float*)d_in[b + 3];
    L[l].wqw = (const float*)d_in[b + 4];
    L[l].wqb = (const float*)d_in[b + 5];
    L[l].wkw = (const float*)d_in[b + 6];
    L[l].wkb = (const float*)d_in[b + 7];
    L[l].wvw = (const float*)d_in[b + 8];
    L[l].wvb = (const float*)d_in[b + 9];
    L[l].ipw = (const float*)d_in[b + 10];
    L[l].ipb = (const float*)d_in[b + 11];
    L[l].opw = (const float*)d_in[b + 12];
    L[l].opb = (const float*)d_in[b + 13];
  }
  const int* edges = (const int*)d_in[34];

  // -------- workspace layout --------
  char* w = (char*)d_ws;
  size_t off = 0;
  auto alc = [&](size_t bytes) -> void* {
    off = (off + 255) & ~(size_t)255;
    void* p = w + off; off += bytes; return p;
  };
  float* f_cfvec = (float*)alc(64 * 128 * 4);
  float* f_cfmean= (float*)alc(128 * 4);
  float* f_duc   = (float*)alc(64 * 256 * 4);
  float* f_dfeat = (float*)alc((size_t)KN * 256 * 4);
  bf16*  b_cfin  = (bf16*) alc((size_t)KN * 128 * 2);
  bf16*  b_inf   = (bf16*) alc((size_t)KN * 384 * 2);
  bf16*  b_feat  = (bf16*) alc((size_t)KN * 4096 * 2);
  float* f_el    = (float*)alc((size_t)4 * KN * 4 * 4);
  float* f_er    = (float*)alc((size_t)4 * KN * 4 * 4);
  bf16*  b_qt    = (bf16*) alc((size_t)KN * 256 * 2);
  bf16*  b_rbar  = (bf16*) alc((size_t)KN * 256 * 2);
  float* f_qk    = (float*)alc((size_t)KN * 256 * 4);
  float* f_Wq    = (float*)alc(128 * 256 * 4);
  float* f_bq    = (float*)alc(256 * 4);
  float* f_B2    = (float*)alc(256 * 256 * 4);
  float* f_M1    = (float*)alc(256 * 256 * 4);
  float* f_Wv    = (float*)alc(256 * 256 * 4);
  float* f_bv    = (float*)alc(256 * 4);
  bf16*  b_WqT   = (bf16*) alc(256 * 128 * 2);
  bf16*  b_B2T   = (bf16*) alc(256 * 256 * 2);
  bf16*  b_WvT   = (bf16*) alc(256 * 256 * 2);
  bf16*  b_gwT   = (bf16*) alc((size_t)4 * 1024 * 384 * 2);
  bf16*  b_rst   = (bf16*) alc((size_t)KN * 16 * 256 * 2);
  int*   i_ptr   = (int*)  alc((size_t)(4 * KN + 1) * 4);
  int*   i_src   = (int*)  alc((size_t)4 * KE * 4);
  int*   i_cnt   = (int*)  alc((size_t)4 * KN * 4);
  int*   i_cur   = (int*)  alc((size_t)4 * KN * 4);
  if (off > ws_size) return;

  // -------- shared pre-phase --------
  k_pre<<<64, 384, 0, stream>>>(cf, cfw, cfb, htw, htb, f_cfvec, f_duc);
  k_mean<<<1, 128, 0, stream>>>(f_cfvec, f_cfmean);
  k_dfeat<<<KN, 256, 0, stream>>>(x, f_duc, f_dfeat);
  k_cfin <<<KN, 128, 0, stream>>>(f_cfvec, f_cfmean, b_cfin);

  // -------- batched CSR over 4 relations --------
  k_zeroi<<<(4 * KN + 255) / 256, 256, 0, stream>>>(i_cnt, 4 * KN);
  k_countB<<<(4 * KE + 255) / 256, 256, 0, stream>>>(edges, i_cnt);
  k_scan<<<1, 1024, 0, stream>>>(i_cnt, i_ptr, 4 * KN);
  k_copyi<<<(4 * KN + 255) / 256, 256, 0, stream>>>(i_ptr, i_cur, 4 * KN);
  k_fillB<<<(4 * KE + 255) / 256, 256, 0, stream>>>(edges, i_cur, i_src);

  // -------- one layer --------
  auto run_layer = [&](const LWT& Wt, const float* dfeat_in, float* outp){
    k_inf_bf16<<<KN, 384, 0, stream>>>(dfeat_in, b_cfin, b_inf);
    k_transGW<<<dim3(32, 12, 4), dim3(32, 8), 0, stream>>>(Wt.gw, b_gwT);
    k_Wq<<<128, 256, 0, stream>>>(Wt.wqw, Wt.ipw, f_Wq);
    k_bq<<<1, 256, 0, stream>>>(Wt.wqb, Wt.ipw, Wt.ipb, f_bq);
    k_B2<<<256, 256, 0, stream>>>(Wt.wkw, Wt.ipw, f_B2);
    k_M1<<<256, 256, 0, stream>>>(Wt.ipw, Wt.opw, f_M1);
    k_Wv<<<256, 256, 0, stream>>>(Wt.wvw, f_M1, f_Wv);
    k_bv<<<1, 256, 0, stream>>>(Wt.wvb, f_M1, Wt.ipb, Wt.opw, Wt.opb, f_bv);
    k_transB<<<dim3(8, 4), dim3(32, 8), 0, stream>>>(f_Wq, b_WqT, 128, 256);
    k_transB<<<dim3(8, 8), dim3(32, 8), 0, stream>>>(f_B2, b_B2T, 256, 256);
    k_transB<<<dim3(8, 8), dim3(32, 8), 0, stream>>>(f_Wv, b_WvT, 256, 256);
    gemm_mfma_bt<bf16> <<<dim3(2, 66), 256, 0, stream>>>(b_cfin, b_WqT, f_bq, b_qt, KN, 256, 128);
    gemm_mfma_bt<float><<<dim3(2, 66), 256, 0, stream>>>(b_qt, b_B2T, nullptr, f_qk, KN, 256, 256);
    // fused feat GEMM over all 4 relations: [KN][4096] bf16
    gemm_mfma_bt<bf16><<<dim3(32, 66), 256, 0, stream>>>(b_inf, b_gwT, nullptr, b_feat, KN, 4096, 384);
    k_elr<<<dim3(KN, 4), 256, 0, stream>>>(b_feat, Wt.al, Wt.ar, f_el, f_er);
    k_agg<<<dim3(KN, 4), 256, 0, stream>>>(i_ptr, i_src, f_el, f_er, b_feat, Wt.gb, b_rst);
    k_attn<<<KN, 256, 0, stream>>>(b_rst, f_qk, b_rbar);
    gemm_mfma_bt<float><<<dim3(2, 66), 256, 0, stream>>>(b_rbar, b_WvT, f_bv, outp, KN, 256, 256);
  };

  run_layer(L[0], f_dfeat, f_dfeat);
  run_layer(L[1], f_dfeat, (float*)d_out);
}

// Round 11
// 682.321 us; speedup vs baseline: 4.5649x; 1.1767x over previous
//
#include <hip/hip_runtime.h>
#include <hip/hip_bf16.h>

typedef __hip_bfloat16 bf16;
typedef __attribute__((ext_vector_type(8))) short short8;
typedef __attribute__((ext_vector_type(4))) short short4v;
typedef __attribute__((ext_vector_type(4))) float f32x4;

#define KN 8384
#define KE 50000
#define NBIG 4480   /* 4096 feat + 256 qk + 128 elr(pad) = 35*128 */

__device__ __forceinline__ float toF(float v){ return v; }
__device__ __forceinline__ float toF(bf16 v){ return __bfloat162float(v); }
__device__ __forceinline__ float b2f(short u){ return __uint_as_float(((unsigned int)(unsigned short)u) << 16); }
__device__ __forceinline__ void stor(float* p, float v){ *p = v; }
__device__ __forceinline__ void stor(bf16* p, float v){ *p = __float2bfloat16(v); }

// ---------------- MFMA GEMM: C[M,N](ldc) = A[M,K]bf16 @ BT[N,K]bf16 (+bias) ----------------
template<typename TC>
__global__ __launch_bounds__(256)
void gemm_mfma_bt(const bf16* __restrict__ A, const bf16* __restrict__ BT,
                  const float* __restrict__ bias, TC* __restrict__ C,
                  int M, int N, int K, int ldc)
{
  __shared__ bf16 As[128][40];
  __shared__ bf16 Bs[128][40];
  const int bm = blockIdx.y * 128, bn = blockIdx.x * 128;
  const int tid = threadIdx.x;
  const int w = tid >> 6, l = tid & 63;
  const int wr = (w >> 1) * 64, wc = (w & 1) * 64;
  const int lr = l & 15, ko = (l >> 4) * 8;
  f32x4 acc[4][4] = {};
  for (int k0 = 0; k0 < K; k0 += 32) {
    #pragma unroll
    for (int p = 0; p < 2; p++){
      int r = (tid >> 2) + p * 64;
      int kk = (tid & 3) * 8;
      int gr = bm + r;
      short8 va = {};
      if (gr < M) va = *(const short8*)&A[(size_t)gr * K + k0 + kk];
      *(short8*)&As[r][kk] = va;
      short8 vb = *(const short8*)&BT[(size_t)(bn + r) * K + k0 + kk];
      *(short8*)&Bs[r][kk] = vb;
    }
    __syncthreads();
    short8 a[4], b[4];
    #pragma unroll
    for (int i = 0; i < 4; i++) a[i] = *(short8*)&As[wr + i*16 + lr][ko];
    #pragma unroll
    for (int j = 0; j < 4; j++) b[j] = *(short8*)&Bs[wc + j*16 + lr][ko];
    #pragma unroll
    for (int i = 0; i < 4; i++)
      #pragma unroll
      for (int j = 0; j < 4; j++)
        acc[i][j] = __builtin_amdgcn_mfma_f32_16x16x32_bf16(a[i], b[j], acc[i][j], 0, 0, 0);
    __syncthreads();
  }
  const int orow = (l >> 4) * 4, ocol = l & 15;
  #pragma unroll
  for (int i = 0; i < 4; i++){
    #pragma unroll
    for (int j = 0; j < 4; j++){
      int gcol = bn + wc + j*16 + ocol;
      float bv = bias ? bias[gcol] : 0.f;
      #pragma unroll
      for (int rg = 0; rg < 4; rg++){
        int grow = bm + wr + i*16 + orow + rg;
        if (grow < M) stor(&C[(size_t)grow * ldc + gcol], acc[i][j][rg] + bv);
      }
    }
  }
}

// ---------------- batched gw transpose-cast into BT_big rows 0..4095 ----------------
__global__ void k_transGW(const float* __restrict__ gw, bf16* __restrict__ bigBT){
  __shared__ float t[32][33];
  int rel = blockIdx.z;
  const float* B = gw + (size_t)rel * 384 * 1024;
  bf16* BT = bigBT + (size_t)rel * 1024 * 384;
  int n0 = blockIdx.x * 32, k0 = blockIdx.y * 32;
  int tx = threadIdx.x, ty = threadIdx.y;
  for (int i = ty; i < 32; i += 8)
    t[i][tx] = B[(size_t)(k0 + i) * 1024 + n0 + tx];
  __syncthreads();
  for (int i = ty; i < 32; i += 8)
    BT[(size_t)(n0 + i) * 384 + k0 + tx] = __float2bfloat16(t[tx][i]);
}

// ---------------- GALR rows 4352..4479 of BT_big: (gw@al | gw@ar), pad zeros ----------------
__global__ __launch_bounds__(384)
void k_galr(const float* __restrict__ gw, const float* __restrict__ al,
            const float* __restrict__ ar, bf16* __restrict__ bigBT){
  int r = blockIdx.x;      // 0..127
  int k = threadIdx.x;     // 0..383
  float val = 0.f;
  if (r < 32){
    int rr = r & 15, t = rr >> 2, h = rr & 3;
    const float* wsrc = ((r < 16) ? al : ar) + t * 1024 + h * 256;
    const float* gp = gw + (size_t)t * 384 * 1024 + (size_t)k * 1024 + h * 256;
    for (int o = 0; o < 256; o++) val += gp[o] * wsrc[o];
  }
  bigBT[(size_t)(4352 + r) * 384 + k] = __float2bfloat16(val);
}

// ---------------- F1: Wq[128][256], B2[256][256], M1[256][256], bq[256] ----------------
__global__ __launch_bounds__(256)
void k_fold1(const float* __restrict__ wqw, const float* __restrict__ wqb,
             const float* __restrict__ wkw, const float* __restrict__ ipw,
             const float* __restrict__ ipb, const float* __restrict__ opw,
             float* __restrict__ Wq, float* __restrict__ B2,
             float* __restrict__ M1, float* __restrict__ bq){
  int b = blockIdx.x, tid = threadIdx.x;
  if (b < 128){                       // Wq[c][j] = sum_e wqw[c][e]*ipw[j][e]
    int c = b; float s = 0.f;
    for (int e = 0; e < 256; e++) s += wqw[c * 256 + e] * ipw[tid * 256 + e];
    Wq[c * 256 + tid] = s;
  } else if (b < 384){                // B2[j][c] = sum_e wkw[c][e]*ipw[256+j][e]
    int j = b - 128; float s = 0.f;
    for (int e = 0; e < 256; e++) s += wkw[tid * 256 + e] * ipw[(256 + j) * 256 + e];
    B2[j * 256 + tid] = s;
  } else if (b < 640){                // M1[e][j] = sum_f ipw[512+f][e]*opw[j][f]
    int e = b - 384; float s = 0.f;
    for (int f = 0; f < 256; f++) s += ipw[(512 + f) * 256 + e] * opw[tid * 256 + f];
    M1[e * 256 + tid] = s;
  } else {                            // bq[j]
    float s = 0.f;
    for (int e = 0; e < 256; e++) s += wqb[e] * ipw[tid * 256 + e];
    bq[tid] = s + ipb[tid];
  }
}

// ---------------- F2: W2T->BT_big rows 4096..4351, WvT, bv, bias_comb ----------------
__global__ __launch_bounds__(256)
void k_fold2(const float* __restrict__ Wq, const float* __restrict__ B2,
             const float* __restrict__ M1, const float* __restrict__ bq,
             const float* __restrict__ wvw, const float* __restrict__ wvb,
             const float* __restrict__ ipb, const float* __restrict__ opw,
             const float* __restrict__ opb,
             bf16* __restrict__ bigBT, bf16* __restrict__ WvT,
             float* __restrict__ bv, float* __restrict__ biasc){
  int b = blockIdx.x, tid = threadIdx.x;
  if (b < 256){            // BT_big[4096+c][k] = (k<256)?0 : W2T: sum_j Wq[k-256][j]*B2[j][c]
    int c = b;
    for (int k = tid; k < 384; k += 256){
      float s = 0.f;
      if (k >= 256){
        int d = k - 256;
        for (int j = 0; j < 256; j++) s += Wq[d * 256 + j] * B2[j * 256 + c];
      }
      bigBT[(size_t)(4096 + c) * 384 + k] = __float2bfloat16(s);
    }
  } else if (b < 512){     // WvT[j][c] = Wv[c][j] = sum_e wvw[c][e]*M1[e][j]
    int j = b - 256; float s = 0.f;
    for (int e = 0; e < 256; e++) s += wvw[tid * 256 + e] * M1[e * 256 + j];
    WvT[j * 256 + tid] = s >= 0.f || s < 0.f ? s : s, WvT[j * 256 + tid] = __float2bfloat16(s);
  } else {                 // bias2 -> biasc, bv
    float b2 = 0.f;
    for (int j = 0; j < 256; j++) b2 += bq[j] * B2[j * 256 + tid];
    float s = 0.f;
    for (int e = 0; e < 256; e++) s += wvb[e] * M1[e * 256 + tid];
    for (int f = 0; f < 256; f++) s += ipb[512 + f] * opw[tid * 256 + f];
    bv[tid] = s + opb[tid];
    for (int i = tid; i < NBIG; i += 256)
      biasc[i] = (i - 4096 == tid) ? b2 : 0.f;
  }
}

// ---------------- pre-phase ----------------
__global__ __launch_bounds__(384)
void k_pre(const float* __restrict__ cf, const float* __restrict__ cfw, const float* __restrict__ cfb,
           const float* __restrict__ htw, const float* __restrict__ htb,
           float* __restrict__ cfvec, float* __restrict__ duc)
{
  int c = blockIdx.x;
  int col = threadIdx.x;
  __shared__ float row[512];
  for (int i = col; i < 512; i += 384) row[i] = cf[c * 512 + i];
  __syncthreads();
  if (col < 128){
    float acc = cfb[col];
    for (int k = 0; k < 512; k++) acc += row[k] * cfw[k * 128 + col];
    cfvec[c * 128 + col] = acc;
  } else {
    int j = col - 128;
    float acc = htb[j];
    for (int k = 0; k < 512; k++) acc += row[k] * htw[k * 256 + j];
    duc[c * 256 + j] = acc;
  }
}
__global__ void k_mean(const float* cv, float* m){
  int o = threadIdx.x;
  float s = 0.f;
  for (int c = 0; c < 64; c++) s += cv[c * 128 + o];
  m[o] = s * (1.f / 64.f);
}
// inf cols 0..255 (layer-1 dfeat), bf16, in place
__global__ void k_dfeatinf(const float* x, const float* duc, bf16* inf){
  int n = blockIdx.x, o = threadIdx.x;
  float v;
  if (n < 8192)      v = x[(n & 127) * 256 + o];
  else if (n < 8256) v = duc[(n - 8192) * 256 + o];
  else               v = x[(n - 8256) * 256 + o];
  inf[(size_t)n * 384 + o] = __float2bfloat16(v);
}
// inf cols 256..383 (cfin, both layers), bf16
__global__ void k_cfininf(const float* cv, const float* cm, bf16* inf){
  int n = blockIdx.x, o = threadIdx.x; // 128
  float v;
  if (n < 8192)      v = cv[(n >> 7) * 128 + o];
  else if (n < 8256) v = cv[(n - 8192) * 128 + o];
  else               v = cm[o];
  inf[(size_t)n * 384 + 256 + o] = __float2bfloat16(v);
}
__global__ void k_zeroi(int* p, int n){
  int i = blockIdx.x * blockDim.x + threadIdx.x; if (i < n) p[i] = 0;
}
__global__ void k_copyi(const int* a, int* b, int n){
  int i = blockIdx.x * blockDim.x + threadIdx.x; if (i < n) b[i] = a[i];
}
__global__ void k_countB(const int* __restrict__ edges, int* __restrict__ cnt){
  int i = blockIdx.x * blockDim.x + threadIdx.x;
  if (i < 4 * KE){
    int t = i / KE, idx = i - t * KE;
    int d = edges[t * 2 * KE + KE + idx];
    atomicAdd(&cnt[t * KN + d], 1);
  }
}
__global__ void k_fillB(const int* __restrict__ edges, int* __restrict__ cur, int* __restrict__ csrc){
  int i = blockIdx.x * blockDim.x + threadIdx.x;
  if (i < 4 * KE){
    int t = i / KE, idx = i - t * KE;
    int s = edges[t * 2 * KE + idx];
    int d = edges[t * 2 * KE + KE + idx];
    int p = atomicAdd(&cur[t * KN + d], 1);
    csrc[p] = s;
  }
}
__global__ void k_scan(const int* __restrict__ cnt, int* __restrict__ ptr, int n){
  __shared__ int part[1024];
  int tid = threadIdx.x;
  const int CH = (n + 1023) >> 10;
  int base = tid * CH;
  int s = 0;
  for (int i = 0; i < CH; i++){ int idx = base + i; if (idx < n) s += cnt[idx]; }
  part[tid] = s; __syncthreads();
  for (int off = 1; off < 1024; off <<= 1){
    int v = (tid >= off) ? part[tid - off] : 0;
    __syncthreads();
    part[tid] += v;
    __syncthreads();
  }
  int run = part[tid] - s;
  for (int i = 0; i < CH; i++){
    int idx = base + i;
    if (idx < n){ ptr[idx] = run; run += cnt[idx]; }
  }
  if (tid == 1023) ptr[n] = part[1023];
}

// ------------- per-dst GAT aggregation over C_big (feat + el/er columns) -------------
__global__ __launch_bounds__(256)
void k_agg(const int* __restrict__ ptr, const int* __restrict__ csrc,
           const bf16* __restrict__ big, const float* __restrict__ gb,
           bf16* __restrict__ rst)
{
  const int n = blockIdx.x, t = blockIdx.y, tid = threadIdx.x;
  const int beg = ptr[t * KN + n], deg = ptr[t * KN + n + 1] - beg;
  const int h4 = tid & 3, j0 = tid >> 2;
  __shared__ float sinv[4];
  __shared__ float partial[16];
  __shared__ float sa[64][4];
  __shared__ int ssrc[64];
  const int elc = 4352 + t * 4 + h4;
  float ern = toF(big[(size_t)n * NBIG + 4368 + t * 4 + h4]);
  float sum = 0.f;
  for (int j = j0; j < deg; j += 64){
    int s = csrc[beg + j];
    float e = toF(big[(size_t)s * NBIG + elc]) + ern;
    e = e > 0.f ? e : 0.2f * e;
    sum += __expf(e);
  }
  #pragma unroll
  for (int off = 4; off < 64; off <<= 1) sum += __shfl_xor(sum, off);
  int w = tid >> 6, lane = tid & 63;
  if (lane < 4) partial[w * 4 + lane] = sum;
  __syncthreads();
  if (tid < 4){
    float s0 = partial[tid] + partial[4 + tid] + partial[8 + tid] + partial[12 + tid];
    sinv[tid] = 1.f / fmaxf(s0, 1e-9f);
  }
  __syncthreads();
  const int head = tid >> 6, c4 = (tid & 63) * 4;
  float acc0 = 0.f, acc1 = 0.f, acc2 = 0.f, acc3 = 0.f;
  const size_t foff = (size_t)t * 1024 + head * 256 + c4;
  for (int c0 = 0; c0 < deg; c0 += 64){
    int cn = min(64, deg - c0);
    if (tid < cn) ssrc[tid] = csrc[beg + c0 + tid];
    __syncthreads();
    if (j0 < cn){
      int s = ssrc[j0];
      float e = toF(big[(size_t)s * NBIG + elc]) + ern;
      e = e > 0.f ? e : 0.2f * e;
      sa[j0][h4] = __expf(e) * sinv[h4];
    }
    __syncthreads();
    for (int j = 0; j < cn; j++){
      int s = ssrc[j];
      float wj = sa[j][head];
      short4v v = *(const short4v*)&big[(size_t)s * NBIG + foff];
      acc0 += wj * b2f(v[0]);
      acc1 += wj * b2f(v[1]);
      acc2 += wj * b2f(v[2]);
      acc3 += wj * b2f(v[3]);
    }
    __syncthreads();
  }
  const float* gbh = gb + t * 1024 + head * 256 + c4;
  bf16* rp = rst + ((size_t)n * 16 + t * 4 + head) * 256 + c4;
  rp[0] = __float2bfloat16(acc0 + gbh[0]);
  rp[1] = __float2bfloat16(acc1 + gbh[1]);
  rp[2] = __float2bfloat16(acc2 + gbh[2]);
  rp[3] = __float2bfloat16(acc3 + gbh[3]);
}

// ------------- attention: scores (rst.qk from C_big), softmax, rbar bf16 -------------
__global__ __launch_bounds__(256)
void k_attn(const bf16* __restrict__ rst, const bf16* __restrict__ big,
            bf16* __restrict__ rbar){
  int n = blockIdx.x, tid = threadIdx.x;
  int w = tid >> 6, lane = tid & 63;
  __shared__ float ssc[16];
  const bf16* q = big + (size_t)n * NBIG + 4096;
  #pragma unroll
  for (int si = 0; si < 4; si++){
    int s = w * 4 + si;
    const bf16* rp = rst + ((size_t)n * 16 + s) * 256;
    float v = 0.f;
    for (int o = lane; o < 256; o += 64) v += toF(rp[o]) * toF(q[o]);
    #pragma unroll
    for (int off = 32; off; off >>= 1) v += __shfl_down(v, off);
    if (lane == 0) ssc[s] = v * 0.0625f;
  }
  __syncthreads();
  float sc[16]; float m = -1e30f;
  #pragma unroll
  for (int s = 0; s < 16; s++){ sc[s] = ssc[s]; m = fmaxf(m, sc[s]); }
  float sum = 0.f;
  #pragma unroll
  for (int s = 0; s < 16; s++){ sc[s] = __expf(sc[s] - m); sum += sc[s]; }
  float inv = 1.f / sum;
  float r = 0.f;
  #pragma unroll
  for (int s = 0; s < 16; s++)
    r += sc[s] * toF(rst[((size_t)n * 16 + s) * 256 + tid]);
  rbar[(size_t)n * 256 + tid] = __float2bfloat16(r * inv);
}

struct LWT {
  const float *gw, *al, *ar, *gb, *wqw, *wqb, *wkw, *wkb, *wvw, *wvb, *ipw, *ipb, *opw, *opb;
};

extern "C" void kernel_launch(void* const* d_in, const int* in_sizes, int n_in,
                              void* d_out, int out_size, void* d_ws, size_t ws_size,
                              hipStream_t stream)
{
  const float* x   = (const float*)d_in[0];
  const float* cf  = (const float*)d_in[1];
  const float* cfw = (const float*)d_in[2];
  const float* cfb = (const float*)d_in[3];
  const float* htw = (const float*)d_in[4];
  const float* htb = (const float*)d_in[5];
  LWT L[2];
  for (int l = 0; l < 2; l++){
    int b = 6 + l * 14;
    L[l].gw  = (const float*)d_in[b + 0];
    L[l].al  = (const float*)d_in[b + 1];
    L[l].ar  = (const float*)d_in[b + 2];
    L[l].gb  = (const float*)d_in[b + 3];
    L[l].wqw = (const float*)d_in[b + 4];
    L[l].wqb = (const float*)d_in[b + 5];
    L[l].wkw = (const float*)d_in[b + 6];
    L[l].wkb = (const float*)d_in[b + 7];
    L[l].wvw = (const float*)d_in[b + 8];
    L[l].wvb = (const float*)d_in[b + 9];
    L[l].ipw = (const float*)d_in[b + 10];
    L[l].ipb = (const float*)d_in[b + 11];
    L[l].opw = (const float*)d_in[b + 12];
    L[l].opb = (const float*)d_in[b + 13];
  }
  const int* edges = (const int*)d_in[34];

  // -------- workspace layout --------
  char* w = (char*)d_ws;
  size_t off = 0;
  auto alc = [&](size_t bytes) -> void* {
    off = (off + 255) & ~(size_t)255;
    void* p = w + off; off += bytes; return p;
  };
  float* f_cfvec = (float*)alc(64 * 128 * 4);
  float* f_cfmean= (float*)alc(128 * 4);
  float* f_duc   = (float*)alc(64 * 256 * 4);
  bf16*  b_inf   = (bf16*) alc((size_t)KN * 384 * 2);
  bf16*  b_big   = (bf16*) alc((size_t)KN * NBIG * 2);   // feat | qk | elr
  bf16*  b_bigBT = (bf16*) alc((size_t)NBIG * 384 * 2);
  float* f_biasc = (float*)alc((size_t)NBIG * 4);
  bf16*  b_rst   = (bf16*) alc((size_t)KN * 16 * 256 * 2);
  bf16*  b_rbar  = (bf16*) alc((size_t)KN * 256 * 2);
  float* f_Wq    = (float*)alc(128 * 256 * 4);
  float* f_B2    = (float*)alc(256 * 256 * 4);
  float* f_M1    = (float*)alc(256 * 256 * 4);
  float* f_bq    = (float*)alc(256 * 4);
  float* f_bv    = (float*)alc(256 * 4);
  bf16*  b_WvT   = (bf16*) alc(256 * 256 * 2);
  int*   i_ptr   = (int*)  alc((size_t)(4 * KN + 1) * 4);
  int*   i_src   = (int*)  alc((size_t)4 * KE * 4);
  int*   i_cnt   = (int*)  alc((size_t)4 * KN * 4);
  int*   i_cur   = (int*)  alc((size_t)4 * KN * 4);
  if (off > ws_size) return;

  // -------- pre-phase --------
  k_pre<<<64, 384, 0, stream>>>(cf, cfw, cfb, htw, htb, f_cfvec, f_duc);
  k_mean<<<1, 128, 0, stream>>>(f_cfvec, f_cfmean);
  k_dfeatinf<<<KN, 256, 0, stream>>>(x, f_duc, b_inf);
  k_cfininf <<<KN, 128, 0, stream>>>(f_cfvec, f_cfmean, b_inf);

  // -------- batched CSR --------
  k_zeroi<<<(4 * KN + 255) / 256, 256, 0, stream>>>(i_cnt, 4 * KN);
  k_countB<<<(4 * KE + 255) / 256, 256, 0, stream>>>(edges, i_cnt);
  k_scan<<<1, 1024, 0, stream>>>(i_cnt, i_ptr, 4 * KN);
  k_copyi<<<(4 * KN + 255) / 256, 256, 0, stream>>>(i_ptr, i_cur, 4 * KN);
  k_fillB<<<(4 * KE + 255) / 256, 256, 0, stream>>>(edges, i_cur, i_src);

  // -------- one layer --------
  auto run_layer = [&](const LWT& Wt, bool last){
    k_transGW<<<dim3(32, 12, 4), dim3(32, 8), 0, stream>>>(Wt.gw, b_bigBT);
    k_galr<<<128, 384, 0, stream>>>(Wt.gw, Wt.al, Wt.ar, b_bigBT);
    k_fold1<<<641, 256, 0, stream>>>(Wt.wqw, Wt.wqb, Wt.wkw, Wt.ipw, Wt.ipb, Wt.opw,
                                     f_Wq, f_B2, f_M1, f_bq);
    k_fold2<<<513, 256, 0, stream>>>(f_Wq, f_B2, f_M1, f_bq, Wt.wvw, Wt.wvb,
                                     Wt.ipb, Wt.opw, Wt.opb,
                                     b_bigBT, b_WvT, f_bv, f_biasc);
    // mega GEMM: feat | qk | elr in one pass
    gemm_mfma_bt<bf16><<<dim3(NBIG / 128, 66), 256, 0, stream>>>(
        b_inf, b_bigBT, f_biasc, b_big, KN, NBIG, 384, NBIG);
    k_agg<<<dim3(KN, 4), 256, 0, stream>>>(i_ptr, i_src, b_big, Wt.gb, b_rst);
    k_attn<<<KN, 256, 0, stream>>>(b_rst, b_big, b_rbar);
    if (last)
      gemm_mfma_bt<float><<<dim3(2, 66), 256, 0, stream>>>(
          b_rbar, b_WvT, f_bv, (float*)d_out, KN, 256, 256, 256);
    else
      gemm_mfma_bt<bf16><<<dim3(2, 66), 256, 0, stream>>>(
          b_rbar, b_WvT, f_bv, b_inf, KN, 256, 256, 384);  // h -> inf cols 0..255
  };

  run_layer(L[0], false);
  run_layer(L[1], true);
}

// Round 12
// 583.078 us; speedup vs baseline: 5.3419x; 1.1702x over previous
//
#include <hip/hip_runtime.h>
#include <hip/hip_bf16.h>

typedef __hip_bfloat16 bf16;
typedef __attribute__((ext_vector_type(8))) short short8;
typedef __attribute__((ext_vector_type(4))) short short4v;
typedef __attribute__((ext_vector_type(4))) float f32x4;

#define KN 8384
#define KNPAD 8448   /* 66*128, pad rows for unguarded A staging */
#define KE 50000
#define NBIG 4480    /* 4096 feat + 256 qk + 128 elr(pad) = 35*128 */

__device__ __forceinline__ float toF(float v){ return v; }
__device__ __forceinline__ float toF(bf16 v){ return __bfloat162float(v); }
__device__ __forceinline__ float b2f(short u){ return __uint_as_float(((unsigned int)(unsigned short)u) << 16); }
__device__ __forceinline__ void stor(float* p, float v){ *p = v; }
__device__ __forceinline__ void stor(bf16* p, float v){ *p = __float2bfloat16(v); }

// async global->LDS, 16B per lane; LDS dest = wave-uniform base + lane*16
__device__ __forceinline__ void glds16(const bf16* g, bf16* l){
  __builtin_amdgcn_global_load_lds(
      (const __attribute__((address_space(1))) unsigned int*)(g),
      (__attribute__((address_space(3))) unsigned int*)(l), 16, 0, 0);
}

// ---------------- MFMA GEMM: C[M,N](ldc) = A[M,K]bf16 @ BT[N,K]bf16 (+bias) ----------------
// K%32==0, N%128==0, A/BT rows must be readable up to ceil128 (pad). Swizzled gload_lds staging.
template<typename TC>
__global__ __launch_bounds__(256)
void gemm_mfma_bt(const bf16* __restrict__ A, const bf16* __restrict__ BT,
                  const float* __restrict__ bias, TC* __restrict__ C,
                  int M, int N, int K, int ldc)
{
  __shared__ bf16 As[128 * 32];   // linear, 32 bf16 (64 B) per row, quad-swizzled
  __shared__ bf16 Bs[128 * 32];
  const int bm = blockIdx.y * 128, bn = blockIdx.x * 128;
  const int tid = threadIdx.x;
  const int w = tid >> 6, l = tid & 63;
  const int wr = (w >> 1) * 64, wc = (w & 1) * 64;
  const int lr = l & 15;
  // staging lanes: instr i covers rows w*32+i*16 + l/4, physical quad l&3
  int rS[2], lqS[2];
  #pragma unroll
  for (int i = 0; i < 2; i++){
    rS[i] = w * 32 + i * 16 + (l >> 2);
    lqS[i] = (l & 3) ^ ((rS[i] >> 1) & 3);   // logical quad stored at physical l&3
  }
  const bf16* gA0 = A  + (size_t)(bm + rS[0]) * K + lqS[0] * 8;
  const bf16* gA1 = A  + (size_t)(bm + rS[1]) * K + lqS[1] * 8;
  const bf16* gB0 = BT + (size_t)(bn + rS[0]) * K + lqS[0] * 8;
  const bf16* gB1 = BT + (size_t)(bn + rS[1]) * K + lqS[1] * 8;
  bf16* lA0 = &As[w * 1024];
  bf16* lA1 = &As[w * 1024 + 512];
  bf16* lB0 = &Bs[w * 1024];
  bf16* lB1 = &Bs[w * 1024 + 512];
  f32x4 acc[4][4] = {};
  for (int k0 = 0; k0 < K; k0 += 32) {
    glds16(gA0 + k0, lA0);
    glds16(gA1 + k0, lA1);
    glds16(gB0 + k0, lB0);
    glds16(gB1 + k0, lB1);
    __syncthreads();
    short8 a[4], b[4];
    #pragma unroll
    for (int i = 0; i < 4; i++){
      int R = wr + i * 16 + lr;
      int pq = (l >> 4) ^ ((R >> 1) & 3);
      a[i] = *(short8*)&As[R * 32 + pq * 8];
    }
    #pragma unroll
    for (int j = 0; j < 4; j++){
      int R = wc + j * 16 + lr;
      int pq = (l >> 4) ^ ((R >> 1) & 3);
      b[j] = *(short8*)&Bs[R * 32 + pq * 8];
    }
    #pragma unroll
    for (int i = 0; i < 4; i++)
      #pragma unroll
      for (int j = 0; j < 4; j++)
        acc[i][j] = __builtin_amdgcn_mfma_f32_16x16x32_bf16(a[i], b[j], acc[i][j], 0, 0, 0);
    __syncthreads();
  }
  const int orow = (l >> 4) * 4, ocol = l & 15;
  #pragma unroll
  for (int i = 0; i < 4; i++){
    #pragma unroll
    for (int j = 0; j < 4; j++){
      int gcol = bn + wc + j * 16 + ocol;
      float bv = bias ? bias[gcol] : 0.f;
      #pragma unroll
      for (int rg = 0; rg < 4; rg++){
        int grow = bm + wr + i * 16 + orow + rg;
        if (grow < M) stor(&C[(size_t)grow * ldc + gcol], acc[i][j][rg] + bv);
      }
    }
  }
}

// ---------------- batched gw transpose-cast into BT_big rows 0..4095 ----------------
__global__ void k_transGW(const float* __restrict__ gw, bf16* __restrict__ bigBT){
  __shared__ float t[32][33];
  int rel = blockIdx.z;
  const float* B = gw + (size_t)rel * 384 * 1024;
  bf16* BT = bigBT + (size_t)rel * 1024 * 384;
  int n0 = blockIdx.x * 32, k0 = blockIdx.y * 32;
  int tx = threadIdx.x, ty = threadIdx.y;
  for (int i = ty; i < 32; i += 8)
    t[i][tx] = B[(size_t)(k0 + i) * 1024 + n0 + tx];
  __syncthreads();
  for (int i = ty; i < 32; i += 8)
    BT[(size_t)(n0 + i) * 384 + k0 + tx] = __float2bfloat16(t[tx][i]);
}

// ---------------- GALR rows 4352..4383: (gw@al | gw@ar), wave-parallel ----------------
__global__ __launch_bounds__(256)
void k_galr(const float* __restrict__ gw, const float* __restrict__ al,
            const float* __restrict__ ar, bf16* __restrict__ bigBT){
  int r = blockIdx.y;                 // 0..31
  int k = blockIdx.x * 4 + (threadIdx.x >> 6);  // 0..383
  int lane = threadIdx.x & 63;
  int rr = r & 15, t = rr >> 2, h = rr & 3;
  const float* wsrc = ((r < 16) ? al : ar) + t * 1024 + h * 256;
  const float* gp = gw + (size_t)t * 384 * 1024 + (size_t)k * 1024 + h * 256;
  float v = 0.f;
  #pragma unroll
  for (int i = 0; i < 4; i++){
    int o = lane + i * 64;
    v += gp[o] * wsrc[o];
  }
  #pragma unroll
  for (int off = 32; off; off >>= 1) v += __shfl_down(v, off);
  if (lane == 0) bigBT[(size_t)(4352 + r) * 384 + k] = __float2bfloat16(v);
}

// zero pad rows 4384..4479 of BT_big (once)
__global__ void k_zpad(bf16* bigBT){
  int i = blockIdx.x * blockDim.x + threadIdx.x;
  if (i < 96 * 384) bigBT[(size_t)4384 * 384 + i] = __float2bfloat16(0.f);
}

// ---------------- weight prep: transpose 4x [256][256] f32 ----------------
__global__ void k_wprep(const float* __restrict__ ipw, const float* __restrict__ wkw,
                        const float* __restrict__ opw, const float* __restrict__ wvw,
                        float* __restrict__ ipwQT, float* __restrict__ wkwT,
                        float* __restrict__ opwT, float* __restrict__ wvwT){
  __shared__ float t[32][33];
  const float* S; float* D;
  switch (blockIdx.z){
    case 0: S = ipw; D = ipwQT; break;
    case 1: S = wkw; D = wkwT; break;
    case 2: S = opw; D = opwT; break;
    default: S = wvw; D = wvwT; break;
  }
  int c0 = blockIdx.x * 32, r0 = blockIdx.y * 32;
  int tx = threadIdx.x, ty = threadIdx.y;
  for (int i = ty; i < 32; i += 8)
    t[i][tx] = S[(size_t)(r0 + i) * 256 + c0 + tx];
  __syncthreads();
  for (int i = ty; i < 32; i += 8)
    D[(size_t)(c0 + i) * 256 + r0 + tx] = t[tx][i];
}

// ---------------- F1 (coalesced): Wq, B2, M1, bq ----------------
__global__ __launch_bounds__(256)
void k_fold1(const float* __restrict__ wqw, const float* __restrict__ wqb,
             const float* __restrict__ ipw, const float* __restrict__ ipb,
             const float* __restrict__ ipwQT, const float* __restrict__ wkwT,
             const float* __restrict__ opwT,
             float* __restrict__ Wq, float* __restrict__ B2,
             float* __restrict__ M1, float* __restrict__ bq){
  int b = blockIdx.x, tid = threadIdx.x;
  if (b < 128){                       // Wq[c][j]
    int c = b; float s = 0.f;
    for (int e = 0; e < 256; e++) s += wqw[c * 256 + e] * ipwQT[e * 256 + tid];
    Wq[c * 256 + tid] = s;
  } else if (b < 384){                // B2[j][c]
    int j = b - 128; float s = 0.f;
    for (int e = 0; e < 256; e++) s += wkwT[e * 256 + tid] * ipw[(256 + j) * 256 + e];
    B2[j * 256 + tid] = s;
  } else if (b < 640){                // M1[e][j]
    int e = b - 384; float s = 0.f;
    for (int f = 0; f < 256; f++) s += ipw[(512 + f) * 256 + e] * opwT[f * 256 + tid];
    M1[e * 256 + tid] = s;
  } else {                            // bq[j]
    float s = 0.f;
    for (int e = 0; e < 256; e++) s += wqb[e] * ipwQT[e * 256 + tid];
    bq[tid] = s + ipb[tid];
  }
}

// ---------------- F2 (coalesced): W2->bigBT qk rows, WvT, bv, biasc ----------------
__global__ __launch_bounds__(256)
void k_fold2(const float* __restrict__ Wq, const float* __restrict__ B2,
             const float* __restrict__ M1, const float* __restrict__ bq,
             const float* __restrict__ wvb, const float* __restrict__ ipb,
             const float* __restrict__ opb,
             const float* __restrict__ wvwT, const float* __restrict__ opwT,
             bf16* __restrict__ bigBT, bf16* __restrict__ WvT,
             float* __restrict__ bv, float* __restrict__ biasc){
  int b = blockIdx.x, tid = threadIdx.x;
  if (b < 256){            // W2[d][c] = sum_j Wq[d][j]*B2[j][c] -> bigBT[(4096+c)][256+d]
    int d = b; float s = 0.f;
    for (int j = 0; j < 256; j++) s += Wq[d * 256 + j] * B2[j * 256 + tid];
    bigBT[(size_t)(4096 + tid) * 384 + 256 + d] = __float2bfloat16(s);
  } else if (b < 512){     // WvT[j][c] = sum_e wvw[c][e]*M1[e][j]
    int j = b - 256; float s = 0.f;
    for (int e = 0; e < 256; e++) s += wvwT[e * 256 + tid] * M1[e * 256 + j];
    WvT[j * 256 + tid] = __float2bfloat16(s);
  } else {                 // bias2->biasc, bv, zero qk-row K<256 region
    float b2 = 0.f;
    for (int j = 0; j < 256; j++) b2 += bq[j] * B2[j * 256 + tid];
    float s = 0.f;
    for (int e = 0; e < 256; e++) s += wvb[e] * M1[e * 256 + tid];
    for (int f = 0; f < 256; f++) s += ipb[512 + f] * opwT[f * 256 + tid];
    bv[tid] = s + opb[tid];
    for (int i = tid; i < NBIG; i += 256)
      biasc[i] = (i - 4096 == tid) ? b2 : 0.f;
    for (int k = 0; k < 256; k++)
      bigBT[(size_t)(4096 + tid) * 384 + k] = __float2bfloat16(0.f);
  }
}

// ---------------- pre-phase ----------------
__global__ __launch_bounds__(384)
void k_pre(const float* __restrict__ cf, const float* __restrict__ cfw, const float* __restrict__ cfb,
           const float* __restrict__ htw, const float* __restrict__ htb,
           float* __restrict__ cfvec, float* __restrict__ duc)
{
  int c = blockIdx.x;
  int col = threadIdx.x;
  __shared__ float row[512];
  for (int i = col; i < 512; i += 384) row[i] = cf[c * 512 + i];
  __syncthreads();
  if (col < 128){
    float acc = cfb[col];
    for (int k = 0; k < 512; k++) acc += row[k] * cfw[k * 128 + col];
    cfvec[c * 128 + col] = acc;
  } else {
    int j = col - 128;
    float acc = htb[j];
    for (int k = 0; k < 512; k++) acc += row[k] * htw[k * 256 + j];
    duc[c * 256 + j] = acc;
  }
}
__global__ void k_mean(const float* cv, float* m){
  int o = threadIdx.x;
  float s = 0.f;
  for (int c = 0; c < 64; c++) s += cv[c * 128 + o];
  m[o] = s * (1.f / 64.f);
}
__global__ void k_dfeatinf(const float* x, const float* duc, bf16* inf){
  int n = blockIdx.x, o = threadIdx.x;
  float v;
  if (n < 8192)      v = x[(n & 127) * 256 + o];
  else if (n < 8256) v = duc[(n - 8192) * 256 + o];
  else               v = x[(n - 8256) * 256 + o];
  inf[(size_t)n * 384 + o] = __float2bfloat16(v);
}
__global__ void k_cfininf(const float* cv, const float* cm, bf16* inf){
  int n = blockIdx.x, o = threadIdx.x;
  float v;
  if (n < 8192)      v = cv[(n >> 7) * 128 + o];
  else if (n < 8256) v = cv[(n - 8192) * 128 + o];
  else               v = cm[o];
  inf[(size_t)n * 384 + 256 + o] = __float2bfloat16(v);
}
__global__ void k_zeroi(int* p, int n){
  int i = blockIdx.x * blockDim.x + threadIdx.x; if (i < n) p[i] = 0;
}
__global__ void k_copyi(const int* a, int* b, int n){
  int i = blockIdx.x * blockDim.x + threadIdx.x; if (i < n) b[i] = a[i];
}
__global__ void k_countB(const int* __restrict__ edges, int* __restrict__ cnt){
  int i = blockIdx.x * blockDim.x + threadIdx.x;
  if (i < 4 * KE){
    int t = i / KE, idx = i - t * KE;
    int d = edges[t * 2 * KE + KE + idx];
    atomicAdd(&cnt[t * KN + d], 1);
  }
}
__global__ void k_fillB(const int* __restrict__ edges, int* __restrict__ cur, int* __restrict__ csrc){
  int i = blockIdx.x * blockDim.x + threadIdx.x;
  if (i < 4 * KE){
    int t = i / KE, idx = i - t * KE;
    int s = edges[t * 2 * KE + idx];
    int d = edges[t * 2 * KE + KE + idx];
    int p = atomicAdd(&cur[t * KN + d], 1);
    csrc[p] = s;
  }
}
__global__ void k_scan(const int* __restrict__ cnt, int* __restrict__ ptr, int n){
  __shared__ int part[1024];
  int tid = threadIdx.x;
  const int CH = (n + 1023) >> 10;
  int base = tid * CH;
  int s = 0;
  for (int i = 0; i < CH; i++){ int idx = base + i; if (idx < n) s += cnt[idx]; }
  part[tid] = s; __syncthreads();
  for (int off = 1; off < 1024; off <<= 1){
    int v = (tid >= off) ? part[tid - off] : 0;
    __syncthreads();
    part[tid] += v;
    __syncthreads();
  }
  int run = part[tid] - s;
  for (int i = 0; i < CH; i++){
    int idx = base + i;
    if (idx < n){ ptr[idx] = run; run += cnt[idx]; }
  }
  if (tid == 1023) ptr[n] = part[1023];
}

// ------------- fused GAT aggregation (4 relations) + 16-key attention, per node -------------
__global__ __launch_bounds__(256)
void k_aggattn(const int* __restrict__ ptr, const int* __restrict__ csrc,
               const bf16* __restrict__ big, const float* __restrict__ gb,
               bf16* __restrict__ rbar)
{
  const int n = blockIdx.x, tid = threadIdx.x;
  const int h4 = tid & 3, j0 = tid >> 2;
  const int w = tid >> 6, lane = tid & 63;
  const int head = w, c4 = lane * 4;
  __shared__ float s_rst[16][260];
  __shared__ float s_sc[16];
  __shared__ float sinv4[4];
  __shared__ float partial[16];
  __shared__ float sa[64][4];
  __shared__ int ssrc[64];
  for (int t = 0; t < 4; t++){
    const int beg = ptr[t * KN + n], deg = ptr[t * KN + n + 1] - beg;
    const int elc = 4352 + t * 4 + h4;
    float ern = toF(big[(size_t)n * NBIG + 4368 + t * 4 + h4]);
    float sum = 0.f;
    for (int j = j0; j < deg; j += 64){
      int s = csrc[beg + j];
      float e = toF(big[(size_t)s * NBIG + elc]) + ern;
      e = e > 0.f ? e : 0.2f * e;
      sum += __expf(e);
    }
    #pragma unroll
    for (int off = 4; off < 64; off <<= 1) sum += __shfl_xor(sum, off);
    if (lane < 4) partial[w * 4 + lane] = sum;
    __syncthreads();
    if (tid < 4){
      float s0 = partial[tid] + partial[4 + tid] + partial[8 + tid] + partial[12 + tid];
      sinv4[tid] = 1.f / fmaxf(s0, 1e-9f);
    }
    __syncthreads();
    float acc0 = 0.f, acc1 = 0.f, acc2 = 0.f, acc3 = 0.f;
    const size_t foff = (size_t)t * 1024 + head * 256 + c4;
    for (int c0 = 0; c0 < deg; c0 += 64){
      int cn = min(64, deg - c0);
      if (tid < cn) ssrc[tid] = csrc[beg + c0 + tid];
      __syncthreads();
      if (j0 < cn){
        int s = ssrc[j0];
        float e = toF(big[(size_t)s * NBIG + elc]) + ern;
        e = e > 0.f ? e : 0.2f * e;
        sa[j0][h4] = __expf(e) * sinv4[h4];
      }
      __syncthreads();
      for (int j = 0; j < cn; j++){
        int s = ssrc[j];
        float wj = sa[j][head];
        short4v v = *(const short4v*)&big[(size_t)s * NBIG + foff];
        acc0 += wj * b2f(v[0]);
        acc1 += wj * b2f(v[1]);
        acc2 += wj * b2f(v[2]);
        acc3 += wj * b2f(v[3]);
      }
      __syncthreads();
    }
    const float* gbh = gb + t * 1024 + head * 256 + c4;
    float* rp = &s_rst[t * 4 + head][c4];
    rp[0] = acc0 + gbh[0];
    rp[1] = acc1 + gbh[1];
    rp[2] = acc2 + gbh[2];
    rp[3] = acc3 + gbh[3];
    __syncthreads();
  }
  // scores: wave w handles s = w*4+si : dot(s_rst[s], qk)
  const bf16* q = big + (size_t)n * NBIG + 4096;
  #pragma unroll
  for (int si = 0; si < 4; si++){
    int s = w * 4 + si;
    float v = 0.f;
    #pragma unroll
    for (int i = 0; i < 4; i++){
      int o = lane + i * 64;
      v += s_rst[s][o] * toF(q[o]);
    }
    #pragma unroll
    for (int off = 32; off; off >>= 1) v += __shfl_down(v, off);
    if (lane == 0) s_sc[s] = v * 0.0625f;
  }
  __syncthreads();
  float sc[16]; float m = -1e30f;
  #pragma unroll
  for (int s = 0; s < 16; s++){ sc[s] = s_sc[s]; m = fmaxf(m, sc[s]); }
  float sum = 0.f;
  #pragma unroll
  for (int s = 0; s < 16; s++){ sc[s] = __expf(sc[s] - m); sum += sc[s]; }
  float inv = 1.f / sum;
  float r = 0.f;
  #pragma unroll
  for (int s = 0; s < 16; s++) r += sc[s] * s_rst[s][tid];
  rbar[(size_t)n * 256 + tid] = __float2bfloat16(r * inv);
}

struct LWT {
  const float *gw, *al, *ar, *gb, *wqw, *wqb, *wkw, *wkb, *wvw, *wvb, *ipw, *ipb, *opw, *opb;
};

extern "C" void kernel_launch(void* const* d_in, const int* in_sizes, int n_in,
                              void* d_out, int out_size, void* d_ws, size_t ws_size,
                              hipStream_t stream)
{
  const float* x   = (const float*)d_in[0];
  const float* cf  = (const float*)d_in[1];
  const float* cfw = (const float*)d_in[2];
  const float* cfb = (const float*)d_in[3];
  const float* htw = (const float*)d_in[4];
  const float* htb = (const float*)d_in[5];
  LWT L[2];
  for (int l = 0; l < 2; l++){
    int b = 6 + l * 14;
    L[l].gw  = (const float*)d_in[b + 0];
    L[l].al  = (const float*)d_in[b + 1];
    L[l].ar  = (const float*)d_in[b + 2];
    L[l].gb  = (const float*)d_in[b + 3];
    L[l].wqw = (const float*)d_in[b + 4];
    L[l].wqb = (const float*)d_in[b + 5];
    L[l].wkw = (const float*)d_in[b + 6];
    L[l].wkb = (const float*)d_in[b + 7];
    L[l].wvw = (const float*)d_in[b + 8];
    L[l].wvb = (const float*)d_in[b + 9];
    L[l].ipw = (const float*)d_in[b + 10];
    L[l].ipb = (const float*)d_in[b + 11];
    L[l].opw = (const float*)d_in[b + 12];
    L[l].opb = (const float*)d_in[b + 13];
  }
  const int* edges = (const int*)d_in[34];

  // -------- workspace layout --------
  char* w = (char*)d_ws;
  size_t off = 0;
  auto alc = [&](size_t bytes) -> void* {
    off = (off + 255) & ~(size_t)255;
    void* p = w + off; off += bytes; return p;
  };
  float* f_cfvec = (float*)alc(64 * 128 * 4);
  float* f_cfmean= (float*)alc(128 * 4);
  float* f_duc   = (float*)alc(64 * 256 * 4);
  bf16*  b_inf   = (bf16*) alc((size_t)KNPAD * 384 * 2);
  bf16*  b_big   = (bf16*) alc((size_t)KN * NBIG * 2);
  bf16*  b_bigBT = (bf16*) alc((size_t)NBIG * 384 * 2);
  float* f_biasc = (float*)alc((size_t)NBIG * 4);
  bf16*  b_rbar  = (bf16*) alc((size_t)KNPAD * 256 * 2);
  float* f_Wq    = (float*)alc(128 * 256 * 4);
  float* f_B2    = (float*)alc(256 * 256 * 4);
  float* f_M1    = (float*)alc(256 * 256 * 4);
  float* f_bq    = (float*)alc(256 * 4);
  float* f_bv    = (float*)alc(256 * 4);
  bf16*  b_WvT   = (bf16*) alc(256 * 256 * 2);
  float* f_ipwQT = (float*)alc(256 * 256 * 4);
  float* f_wkwT  = (float*)alc(256 * 256 * 4);
  float* f_opwT  = (float*)alc(256 * 256 * 4);
  float* f_wvwT  = (float*)alc(256 * 256 * 4);
  int*   i_ptr   = (int*)  alc((size_t)(4 * KN + 1) * 4);
  int*   i_src   = (int*)  alc((size_t)4 * KE * 4);
  int*   i_cnt   = (int*)  alc((size_t)4 * KN * 4);
  int*   i_cur   = (int*)  alc((size_t)4 * KN * 4);
  if (off > ws_size) return;

  // -------- pre-phase --------
  k_pre<<<64, 384, 0, stream>>>(cf, cfw, cfb, htw, htb, f_cfvec, f_duc);
  k_mean<<<1, 128, 0, stream>>>(f_cfvec, f_cfmean);
  k_dfeatinf<<<KN, 256, 0, stream>>>(x, f_duc, b_inf);
  k_cfininf <<<KN, 128, 0, stream>>>(f_cfvec, f_cfmean, b_inf);
  k_zpad<<<(96 * 384 + 255) / 256, 256, 0, stream>>>(b_bigBT);

  // -------- batched CSR --------
  k_zeroi<<<(4 * KN + 255) / 256, 256, 0, stream>>>(i_cnt, 4 * KN);
  k_countB<<<(4 * KE + 255) / 256, 256, 0, stream>>>(edges, i_cnt);
  k_scan<<<1, 1024, 0, stream>>>(i_cnt, i_ptr, 4 * KN);
  k_copyi<<<(4 * KN + 255) / 256, 256, 0, stream>>>(i_ptr, i_cur, 4 * KN);
  k_fillB<<<(4 * KE + 255) / 256, 256, 0, stream>>>(edges, i_cur, i_src);

  // -------- one layer --------
  auto run_layer = [&](const LWT& Wt, bool last){
    k_transGW<<<dim3(32, 12, 4), dim3(32, 8), 0, stream>>>(Wt.gw, b_bigBT);
    k_galr<<<dim3(96, 32), 256, 0, stream>>>(Wt.gw, Wt.al, Wt.ar, b_bigBT);
    k_wprep<<<dim3(8, 8, 4), dim3(32, 8), 0, stream>>>(Wt.ipw, Wt.wkw, Wt.opw, Wt.wvw,
                                                       f_ipwQT, f_wkwT, f_opwT, f_wvwT);
    k_fold1<<<641, 256, 0, stream>>>(Wt.wqw, Wt.wqb, Wt.ipw, Wt.ipb,
                                     f_ipwQT, f_wkwT, f_opwT,
                                     f_Wq, f_B2, f_M1, f_bq);
    k_fold2<<<513, 256, 0, stream>>>(f_Wq, f_B2, f_M1, f_bq, Wt.wvb, Wt.ipb, Wt.opb,
                                     f_wvwT, f_opwT,
                                     b_bigBT, b_WvT, f_bv, f_biasc);
    // mega GEMM: feat | qk | elr
    gemm_mfma_bt<bf16><<<dim3(NBIG / 128, 66), 256, 0, stream>>>(
        b_inf, b_bigBT, f_biasc, b_big, KN, NBIG, 384, NBIG);
    k_aggattn<<<KN, 256, 0, stream>>>(i_ptr, i_src, b_big, Wt.gb, b_rbar);
    if (last)
      gemm_mfma_bt<float><<<dim3(2, 66), 256, 0, stream>>>(
          b_rbar, b_WvT, f_bv, (float*)d_out, KN, 256, 256, 256);
    else
      gemm_mfma_bt<bf16><<<dim3(2, 66), 256, 0, stream>>>(
          b_rbar, b_WvT, f_bv, b_inf, KN, 256, 256, 384);
  };

  run_layer(L[0], false);
  run_layer(L[1], true);
}

// Round 13
// 582.821 us; speedup vs baseline: 5.3443x; 1.0004x over previous
//
#include <hip/hip_runtime.h>
#include <hip/hip_bf16.h>

typedef __hip_bfloat16 bf16;
typedef __attribute__((ext_vector_type(8))) short short8;
typedef __attribute__((ext_vector_type(4))) short short4v;
typedef __attribute__((ext_vector_type(4))) float f32x4;

#define KN 8384
#define KNPAD 8448   /* 66*128, pad rows for unguarded A staging */
#define KE 50000
#define NBIG 4480    /* 4096 feat + 256 qk + 128 elr(pad) = 35*128 */

__device__ __forceinline__ float toF(float v){ return v; }
__device__ __forceinline__ float toF(bf16 v){ return __bfloat162float(v); }
__device__ __forceinline__ float b2f(short u){ return __uint_as_float(((unsigned int)(unsigned short)u) << 16); }
__device__ __forceinline__ void stor(float* p, float v){ *p = v; }
__device__ __forceinline__ void stor(bf16* p, float v){ *p = __float2bfloat16(v); }

// async global->LDS, 16B per lane; LDS dest = wave-uniform base + lane*16
__device__ __forceinline__ void glds16(const bf16* g, bf16* l){
  __builtin_amdgcn_global_load_lds(
      (const __attribute__((address_space(1))) unsigned int*)(g),
      (__attribute__((address_space(3))) unsigned int*)(l), 16, 0, 0);
}

// ---------------- MFMA GEMM: C[M,N](ldc) = A[M,K]bf16 @ BT[N,K]bf16 (+bias) ----------------
// K%32==0, N%128==0, A/BT rows must be readable up to ceil128 (pad). Swizzled gload_lds staging.
template<typename TC>
__global__ __launch_bounds__(256)
void gemm_mfma_bt(const bf16* __restrict__ A, const bf16* __restrict__ BT,
                  const float* __restrict__ bias, TC* __restrict__ C,
                  int M, int N, int K, int ldc)
{
  __shared__ bf16 As[128 * 32];   // linear, 32 bf16 (64 B) per row, quad-swizzled
  __shared__ bf16 Bs[128 * 32];
  const int bm = blockIdx.y * 128, bn = blockIdx.x * 128;
  const int tid = threadIdx.x;
  const int w = tid >> 6, l = tid & 63;
  const int wr = (w >> 1) * 64, wc = (w & 1) * 64;
  const int lr = l & 15;
  // staging lanes: instr i covers rows w*32+i*16 + l/4, physical quad l&3
  int rS[2], lqS[2];
  #pragma unroll
  for (int i = 0; i < 2; i++){
    rS[i] = w * 32 + i * 16 + (l >> 2);
    lqS[i] = (l & 3) ^ ((rS[i] >> 1) & 3);   // logical quad stored at physical l&3
  }
  const bf16* gA0 = A  + (size_t)(bm + rS[0]) * K + lqS[0] * 8;
  const bf16* gA1 = A  + (size_t)(bm + rS[1]) * K + lqS[1] * 8;
  const bf16* gB0 = BT + (size_t)(bn + rS[0]) * K + lqS[0] * 8;
  const bf16* gB1 = BT + (size_t)(bn + rS[1]) * K + lqS[1] * 8;
  bf16* lA0 = &As[w * 1024];
  bf16* lA1 = &As[w * 1024 + 512];
  bf16* lB0 = &Bs[w * 1024];
  bf16* lB1 = &Bs[w * 1024 + 512];
  f32x4 acc[4][4] = {};
  for (int k0 = 0; k0 < K; k0 += 32) {
    glds16(gA0 + k0, lA0);
    glds16(gA1 + k0, lA1);
    glds16(gB0 + k0, lB0);
    glds16(gB1 + k0, lB1);
    __syncthreads();
    short8 a[4], b[4];
    #pragma unroll
    for (int i = 0; i < 4; i++){
      int R = wr + i * 16 + lr;
      int pq = (l >> 4) ^ ((R >> 1) & 3);
      a[i] = *(short8*)&As[R * 32 + pq * 8];
    }
    #pragma unroll
    for (int j = 0; j < 4; j++){
      int R = wc + j * 16 + lr;
      int pq = (l >> 4) ^ ((R >> 1) & 3);
      b[j] = *(short8*)&Bs[R * 32 + pq * 8];
    }
    #pragma unroll
    for (int i = 0; i < 4; i++)
      #pragma unroll
      for (int j = 0; j < 4; j++)
        acc[i][j] = __builtin_amdgcn_mfma_f32_16x16x32_bf16(a[i], b[j], acc[i][j], 0, 0, 0);
    __syncthreads();
  }
  const int orow = (l >> 4) * 4, ocol = l & 15;
  #pragma unroll
  for (int i = 0; i < 4; i++){
    #pragma unroll
    for (int j = 0; j < 4; j++){
      int gcol = bn + wc + j * 16 + ocol;
      float bv = bias ? bias[gcol] : 0.f;
      #pragma unroll
      for (int rg = 0; rg < 4; rg++){
        int grow = bm + wr + i * 16 + orow + rg;
        if (grow < M) stor(&C[(size_t)grow * ldc + gcol], acc[i][j][rg] + bv);
      }
    }
  }
}

// ---------------- batched gw transpose-cast into BT_big rows 0..4095 ----------------
__global__ void k_transGW(const float* __restrict__ gw, bf16* __restrict__ bigBT){
  __shared__ float t[32][33];
  int rel = blockIdx.z;
  const float* B = gw + (size_t)rel * 384 * 1024;
  bf16* BT = bigBT + (size_t)rel * 1024 * 384;
  int n0 = blockIdx.x * 32, k0 = blockIdx.y * 32;
  int tx = threadIdx.x, ty = threadIdx.y;
  for (int i = ty; i < 32; i += 8)
    t[i][tx] = B[(size_t)(k0 + i) * 1024 + n0 + tx];
  __syncthreads();
  for (int i = ty; i < 32; i += 8)
    BT[(size_t)(n0 + i) * 384 + k0 + tx] = __float2bfloat16(t[tx][i]);
}

// ---------------- GALR rows 4352..4383: (gw@al | gw@ar), wave-parallel ----------------
__global__ __launch_bounds__(256)
void k_galr(const float* __restrict__ gw, const float* __restrict__ al,
            const float* __restrict__ ar, bf16* __restrict__ bigBT){
  int r = blockIdx.y;                 // 0..31
  int k = blockIdx.x * 4 + (threadIdx.x >> 6);  // 0..383
  int lane = threadIdx.x & 63;
  int rr = r & 15, t = rr >> 2, h = rr & 3;
  const float* wsrc = ((r < 16) ? al : ar) + t * 1024 + h * 256;
  const float* gp = gw + (size_t)t * 384 * 1024 + (size_t)k * 1024 + h * 256;
  float v = 0.f;
  #pragma unroll
  for (int i = 0; i < 4; i++){
    int o = lane + i * 64;
    v += gp[o] * wsrc[o];
  }
  #pragma unroll
  for (int off = 32; off; off >>= 1) v += __shfl_down(v, off);
  if (lane == 0) bigBT[(size_t)(4352 + r) * 384 + k] = __float2bfloat16(v);
}

// zero pad rows 4384..4479 of BT_big (once)
__global__ void k_zpad(bf16* bigBT){
  int i = blockIdx.x * blockDim.x + threadIdx.x;
  if (i < 96 * 384) bigBT[(size_t)4384 * 384 + i] = __float2bfloat16(0.f);
}

// ---------------- weight prep: transpose 4x [256][256] f32 ----------------
__global__ void k_wprep(const float* __restrict__ ipw, const float* __restrict__ wkw,
                        const float* __restrict__ opw, const float* __restrict__ wvw,
                        float* __restrict__ ipwQT, float* __restrict__ wkwT,
                        float* __restrict__ opwT, float* __restrict__ wvwT){
  __shared__ float t[32][33];
  const float* S; float* D;
  switch (blockIdx.z){
    case 0: S = ipw; D = ipwQT; break;
    case 1: S = wkw; D = wkwT; break;
    case 2: S = opw; D = opwT; break;
    default: S = wvw; D = wvwT; break;
  }
  int c0 = blockIdx.x * 32, r0 = blockIdx.y * 32;
  int tx = threadIdx.x, ty = threadIdx.y;
  for (int i = ty; i < 32; i += 8)
    t[i][tx] = S[(size_t)(r0 + i) * 256 + c0 + tx];
  __syncthreads();
  for (int i = ty; i < 32; i += 8)
    D[(size_t)(c0 + i) * 256 + r0 + tx] = t[tx][i];
}

// ---------------- F1 (coalesced): Wq, B2, M1, bq ----------------
__global__ __launch_bounds__(256)
void k_fold1(const float* __restrict__ wqw, const float* __restrict__ wqb,
             const float* __restrict__ ipw, const float* __restrict__ ipb,
             const float* __restrict__ ipwQT, const float* __restrict__ wkwT,
             const float* __restrict__ opwT,
             float* __restrict__ Wq, float* __restrict__ B2,
             float* __restrict__ M1, float* __restrict__ bq){
  int b = blockIdx.x, tid = threadIdx.x;
  if (b < 128){                       // Wq[c][j]
    int c = b; float s = 0.f;
    for (int e = 0; e < 256; e++) s += wqw[c * 256 + e] * ipwQT[e * 256 + tid];
    Wq[c * 256 + tid] = s;
  } else if (b < 384){                // B2[j][c]
    int j = b - 128; float s = 0.f;
    for (int e = 0; e < 256; e++) s += wkwT[e * 256 + tid] * ipw[(256 + j) * 256 + e];
    B2[j * 256 + tid] = s;
  } else if (b < 640){                // M1[e][j]
    int e = b - 384; float s = 0.f;
    for (int f = 0; f < 256; f++) s += ipw[(512 + f) * 256 + e] * opwT[f * 256 + tid];
    M1[e * 256 + tid] = s;
  } else {                            // bq[j]
    float s = 0.f;
    for (int e = 0; e < 256; e++) s += wqb[e] * ipwQT[e * 256 + tid];
    bq[tid] = s + ipb[tid];
  }
}

// ---------------- F2 (coalesced): W2->bigBT qk rows, WvT, bv, biasc ----------------
__global__ __launch_bounds__(256)
void k_fold2(const float* __restrict__ Wq, const float* __restrict__ B2,
             const float* __restrict__ M1, const float* __restrict__ bq,
             const float* __restrict__ wvb, const float* __restrict__ ipb,
             const float* __restrict__ opb,
             const float* __restrict__ wvwT, const float* __restrict__ opwT,
             bf16* __restrict__ bigBT, bf16* __restrict__ WvT,
             float* __restrict__ bv, float* __restrict__ biasc){
  int b = blockIdx.x, tid = threadIdx.x;
  if (b < 256){            // W2[d][c] = sum_j Wq[d][j]*B2[j][c] -> bigBT[(4096+c)][256+d]
    int d = b; float s = 0.f;
    for (int j = 0; j < 256; j++) s += Wq[d * 256 + j] * B2[j * 256 + tid];
    bigBT[(size_t)(4096 + tid) * 384 + 256 + d] = __float2bfloat16(s);
  } else if (b < 512){     // WvT[j][c] = sum_e wvw[c][e]*M1[e][j]
    int j = b - 256; float s = 0.f;
    for (int e = 0; e < 256; e++) s += wvwT[e * 256 + tid] * M1[e * 256 + j];
    WvT[j * 256 + tid] = __float2bfloat16(s);
  } else {                 // bias2->biasc, bv, zero qk-row K<256 region
    float b2 = 0.f;
    for (int j = 0; j < 256; j++) b2 += bq[j] * B2[j * 256 + tid];
    float s = 0.f;
    for (int e = 0; e < 256; e++) s += wvb[e] * M1[e * 256 + tid];
    for (int f = 0; f < 256; f++) s += ipb[512 + f] * opwT[f * 256 + tid];
    bv[tid] = s + opb[tid];
    for (int i = tid; i < NBIG; i += 256)
      biasc[i] = (i - 4096 == tid) ? b2 : 0.f;
    for (int k = 0; k < 256; k++)
      bigBT[(size_t)(4096 + tid) * 384 + k] = __float2bfloat16(0.f);
  }
}

// ---------------- pre-phase ----------------
__global__ __launch_bounds__(384)
void k_pre(const float* __restrict__ cf, const float* __restrict__ cfw, const float* __restrict__ cfb,
           const float* __restrict__ htw, const float* __restrict__ htb,
           float* __restrict__ cfvec, float* __restrict__ duc)
{
  int c = blockIdx.x;
  int col = threadIdx.x;
  __shared__ float row[512];
  for (int i = col; i < 512; i += 384) row[i] = cf[c * 512 + i];
  __syncthreads();
  if (col < 128){
    float acc = cfb[col];
    for (int k = 0; k < 512; k++) acc += row[k] * cfw[k * 128 + col];
    cfvec[c * 128 + col] = acc;
  } else {
    int j = col - 128;
    float acc = htb[j];
    for (int k = 0; k < 512; k++) acc += row[k] * htw[k * 256 + j];
    duc[c * 256 + j] = acc;
  }
}
__global__ void k_mean(const float* cv, float* m){
  int o = threadIdx.x;
  float s = 0.f;
  for (int c = 0; c < 64; c++) s += cv[c * 128 + o];
  m[o] = s * (1.f / 64.f);
}
__global__ void k_dfeatinf(const float* x, const float* duc, bf16* inf){
  int n = blockIdx.x, o = threadIdx.x;
  float v;
  if (n < 8192)      v = x[(n & 127) * 256 + o];
  else if (n < 8256) v = duc[(n - 8192) * 256 + o];
  else               v = x[(n - 8256) * 256 + o];
  inf[(size_t)n * 384 + o] = __float2bfloat16(v);
}
__global__ void k_cfininf(const float* cv, const float* cm, bf16* inf){
  int n = blockIdx.x, o = threadIdx.x;
  float v;
  if (n < 8192)      v = cv[(n >> 7) * 128 + o];
  else if (n < 8256) v = cv[(n - 8192) * 128 + o];
  else               v = cm[o];
  inf[(size_t)n * 384 + 256 + o] = __float2bfloat16(v);
}
__global__ void k_zeroi(int* p, int n){
  int i = blockIdx.x * blockDim.x + threadIdx.x; if (i < n) p[i] = 0;
}
__global__ void k_copyi(const int* a, int* b, int n){
  int i = blockIdx.x * blockDim.x + threadIdx.x; if (i < n) b[i] = a[i];
}
__global__ void k_countB(const int* __restrict__ edges, int* __restrict__ cnt){
  int i = blockIdx.x * blockDim.x + threadIdx.x;
  if (i < 4 * KE){
    int t = i / KE, idx = i - t * KE;
    int d = edges[t * 2 * KE + KE + idx];
    atomicAdd(&cnt[t * KN + d], 1);
  }
}
__global__ void k_fillB(const int* __restrict__ edges, int* __restrict__ cur, int* __restrict__ csrc){
  int i = blockIdx.x * blockDim.x + threadIdx.x;
  if (i < 4 * KE){
    int t = i / KE, idx = i - t * KE;
    int s = edges[t * 2 * KE + idx];
    int d = edges[t * 2 * KE + KE + idx];
    int p = atomicAdd(&cur[t * KN + d], 1);
    csrc[p] = s;
  }
}
__global__ void k_scan(const int* __restrict__ cnt, int* __restrict__ ptr, int n){
  __shared__ int part[1024];
  int tid = threadIdx.x;
  const int CH = (n + 1023) >> 10;
  int base = tid * CH;
  int s = 0;
  for (int i = 0; i < CH; i++){ int idx = base + i; if (idx < n) s += cnt[idx]; }
  part[tid] = s; __syncthreads();
  for (int off = 1; off < 1024; off <<= 1){
    int v = (tid >= off) ? part[tid - off] : 0;
    __syncthreads();
    part[tid] += v;
    __syncthreads();
  }
  int run = part[tid] - s;
  for (int i = 0; i < CH; i++){
    int idx = base + i;
    if (idx < n){ ptr[idx] = run; run += cnt[idx]; }
  }
  if (tid == 1023) ptr[n] = part[1023];
}

// ------------- fused GAT aggregation (4 relations) + 16-key attention, per node -------------
__global__ __launch_bounds__(256)
void k_aggattn(const int* __restrict__ ptr, const int* __restrict__ csrc,
               const bf16* __restrict__ big, const float* __restrict__ gb,
               bf16* __restrict__ rbar)
{
  const int n = blockIdx.x, tid = threadIdx.x;
  const int h4 = tid & 3, j0 = tid >> 2;
  const int w = tid >> 6, lane = tid & 63;
  const int head = w, c4 = lane * 4;
  __shared__ float s_rst[16][260];
  __shared__ float s_sc[16];
  __shared__ float sinv4[4];
  __shared__ float partial[16];
  __shared__ float sa[64][4];
  __shared__ int ssrc[64];
  for (int t = 0; t < 4; t++){
    const int beg = ptr[t * KN + n], deg = ptr[t * KN + n + 1] - beg;
    const int elc = 4352 + t * 4 + h4;
    float ern = toF(big[(size_t)n * NBIG + 4368 + t * 4 + h4]);
    float sum = 0.f;
    for (int j = j0; j < deg; j += 64){
      int s = csrc[beg + j];
      float e = toF(big[(size_t)s * NBIG + elc]) + ern;
      e = e > 0.f ? e : 0.2f * e;
      sum += __expf(e);
    }
    #pragma unroll
    for (int off = 4; off < 64; off <<= 1) sum += __shfl_xor(sum, off);
    if (lane < 4) partial[w * 4 + lane] = sum;
    __syncthreads();
    if (tid < 4){
      float s0 = partial[tid] + partial[4 + tid] + partial[8 + tid] + partial[12 + tid];
      sinv4[tid] = 1.f / fmaxf(s0, 1e-9f);
    }
    __syncthreads();
    float acc0 = 0.f, acc1 = 0.f, acc2 = 0.f, acc3 = 0.f;
    const size_t foff = (size_t)t * 1024 + head * 256 + c4;
    for (int c0 = 0; c0 < deg; c0 += 64){
      int cn = min(64, deg - c0);
      if (tid < cn) ssrc[tid] = csrc[beg + c0 + tid];
      __syncthreads();
      if (j0 < cn){
        int s = ssrc[j0];
        float e = toF(big[(size_t)s * NBIG + elc]) + ern;
        e = e > 0.f ? e : 0.2f * e;
        sa[j0][h4] = __expf(e) * sinv4[h4];
      }
      __syncthreads();
      for (int j = 0; j < cn; j++){
        int s = ssrc[j];
        float wj = sa[j][head];
        short4v v = *(const short4v*)&big[(size_t)s * NBIG + foff];
        acc0 += wj * b2f(v[0]);
        acc1 += wj * b2f(v[1]);
        acc2 += wj * b2f(v[2]);
        acc3 += wj * b2f(v[3]);
      }
      __syncthreads();
    }
    const float* gbh = gb + t * 1024 + head * 256 + c4;
    float* rp = &s_rst[t * 4 + head][c4];
    rp[0] = acc0 + gbh[0];
    rp[1] = acc1 + gbh[1];
    rp[2] = acc2 + gbh[2];
    rp[3] = acc3 + gbh[3];
    __syncthreads();
  }
  // scores: wave w handles s = w*4+si : dot(s_rst[s], qk)
  const bf16* q = big + (size_t)n * NBIG + 4096;
  #pragma unroll
  for (int si = 0; si < 4; si++){
    int s = w * 4 + si;
    float v = 0.f;
    #pragma unroll
    for (int i = 0; i < 4; i++){
      int o = lane + i * 64;
      v += s_rst[s][o] * toF(q[o]);
    }
    #pragma unroll
    for (int off = 32; off; off >>= 1) v += __shfl_down(v, off);
    if (lane == 0) s_sc[s] = v * 0.0625f;
  }
  __syncthreads();
  float sc[16]; float m = -1e30f;
  #pragma unroll
  for (int s = 0; s < 16; s++){ sc[s] = s_sc[s]; m = fmaxf(m, sc[s]); }
  float sum = 0.f;
  #pragma unroll
  for (int s = 0; s < 16; s++){ sc[s] = __expf(sc[s] - m); sum += sc[s]; }
  float inv = 1.f / sum;
  float r = 0.f;
  #pragma unroll
  for (int s = 0; s < 16; s++) r += sc[s] * s_rst[s][tid];
  rbar[(size_t)n * 256 + tid] = __float2bfloat16(r * inv);
}

struct LWT {
  const float *gw, *al, *ar, *gb, *wqw, *wqb, *wkw, *wkb, *wvw, *wvb, *ipw, *ipb, *opw, *opb;
};

extern "C" void kernel_launch(void* const* d_in, const int* in_sizes, int n_in,
                              void* d_out, int out_size, void* d_ws, size_t ws_size,
                              hipStream_t stream)
{
  const float* x   = (const float*)d_in[0];
  const float* cf  = (const float*)d_in[1];
  const float* cfw = (const float*)d_in[2];
  const float* cfb = (const float*)d_in[3];
  const float* htw = (const float*)d_in[4];
  const float* htb = (const float*)d_in[5];
  LWT L[2];
  for (int l = 0; l < 2; l++){
    int b = 6 + l * 14;
    L[l].gw  = (const float*)d_in[b + 0];
    L[l].al  = (const float*)d_in[b + 1];
    L[l].ar  = (const float*)d_in[b + 2];
    L[l].gb  = (const float*)d_in[b + 3];
    L[l].wqw = (const float*)d_in[b + 4];
    L[l].wqb = (const float*)d_in[b + 5];
    L[l].wkw = (const float*)d_in[b + 6];
    L[l].wkb = (const float*)d_in[b + 7];
    L[l].wvw = (const float*)d_in[b + 8];
    L[l].wvb = (const float*)d_in[b + 9];
    L[l].ipw = (const float*)d_in[b + 10];
    L[l].ipb = (const float*)d_in[b + 11];
    L[l].opw = (const float*)d_in[b + 12];
    L[l].opb = (const float*)d_in[b + 13];
  }
  const int* edges = (const int*)d_in[34];

  // -------- workspace layout --------
  char* w = (char*)d_ws;
  size_t off = 0;
  auto alc = [&](size_t bytes) -> void* {
    off = (off + 255) & ~(size_t)255;
    void* p = w + off; off += bytes; return p;
  };
  float* f_cfvec = (float*)alc(64 * 128 * 4);
  float* f_cfmean= (float*)alc(128 * 4);
  float* f_duc   = (float*)alc(64 * 256 * 4);
  bf16*  b_inf   = (bf16*) alc((size_t)KNPAD * 384 * 2);
  bf16*  b_big   = (bf16*) alc((size_t)KN * NBIG * 2);
  bf16*  b_bigBT = (bf16*) alc((size_t)NBIG * 384 * 2);
  float* f_biasc = (float*)alc((size_t)NBIG * 4);
  bf16*  b_rbar  = (bf16*) alc((size_t)KNPAD * 256 * 2);
  float* f_Wq    = (float*)alc(128 * 256 * 4);
  float* f_B2    = (float*)alc(256 * 256 * 4);
  float* f_M1    = (float*)alc(256 * 256 * 4);
  float* f_bq    = (float*)alc(256 * 4);
  float* f_bv    = (float*)alc(256 * 4);
  bf16*  b_WvT   = (bf16*) alc(256 * 256 * 2);
  float* f_ipwQT = (float*)alc(256 * 256 * 4);
  float* f_wkwT  = (float*)alc(256 * 256 * 4);
  float* f_opwT  = (float*)alc(256 * 256 * 4);
  float* f_wvwT  = (float*)alc(256 * 256 * 4);
  int*   i_ptr   = (int*)  alc((size_t)(4 * KN + 1) * 4);
  int*   i_src   = (int*)  alc((size_t)4 * KE * 4);
  int*   i_cnt   = (int*)  alc((size_t)4 * KN * 4);
  int*   i_cur   = (int*)  alc((size_t)4 * KN * 4);
  if (off > ws_size) return;

  // -------- pre-phase --------
  k_pre<<<64, 384, 0, stream>>>(cf, cfw, cfb, htw, htb, f_cfvec, f_duc);
  k_mean<<<1, 128, 0, stream>>>(f_cfvec, f_cfmean);
  k_dfeatinf<<<KN, 256, 0, stream>>>(x, f_duc, b_inf);
  k_cfininf <<<KN, 128, 0, stream>>>(f_cfvec, f_cfmean, b_inf);
  k_zpad<<<(96 * 384 + 255) / 256, 256, 0, stream>>>(b_bigBT);

  // -------- batched CSR --------
  k_zeroi<<<(4 * KN + 255) / 256, 256, 0, stream>>>(i_cnt, 4 * KN);
  k_countB<<<(4 * KE + 255) / 256, 256, 0, stream>>>(edges, i_cnt);
  k_scan<<<1, 1024, 0, stream>>>(i_cnt, i_ptr, 4 * KN);
  k_copyi<<<(4 * KN + 255) / 256, 256, 0, stream>>>(i_ptr, i_cur, 4 * KN);
  k_fillB<<<(4 * KE + 255) / 256, 256, 0, stream>>>(edges, i_cur, i_src);

  // -------- one layer --------
  auto run_layer = [&](const LWT& Wt, bool last){
    k_transGW<<<dim3(32, 12, 4), dim3(32, 8), 0, stream>>>(Wt.gw, b_bigBT);
    k_galr<<<dim3(96, 32), 256, 0, stream>>>(Wt.gw, Wt.al, Wt.ar, b_bigBT);
    k_wprep<<<dim3(8, 8, 4), dim3(32, 8), 0, stream>>>(Wt.ipw, Wt.wkw, Wt.opw, Wt.wvw,
                                                       f_ipwQT, f_wkwT, f_opwT, f_wvwT);
    k_fold1<<<641, 256, 0, stream>>>(Wt.wqw, Wt.wqb, Wt.ipw, Wt.ipb,
                                     f_ipwQT, f_wkwT, f_opwT,
                                     f_Wq, f_B2, f_M1, f_bq);
    k_fold2<<<513, 256, 0, stream>>>(f_Wq, f_B2, f_M1, f_bq, Wt.wvb, Wt.ipb, Wt.opb,
                                     f_wvwT, f_opwT,
                                     b_bigBT, b_WvT, f_bv, f_biasc);
    // mega GEMM: feat | qk | elr
    gemm_mfma_bt<bf16><<<dim3(NBIG / 128, 66), 256, 0, stream>>>(
        b_inf, b_bigBT, f_biasc, b_big, KN, NBIG, 384, NBIG);
    k_aggattn<<<KN, 256, 0, stream>>>(i_ptr, i_src, b_big, Wt.gb, b_rbar);
    if (last)
      gemm_mfma_bt<float><<<dim3(2, 66), 256, 0, stream>>>(
          b_rbar, b_WvT, f_bv, (float*)d_out, KN, 256, 256, 256);
    else
      gemm_mfma_bt<bf16><<<dim3(2, 66), 256, 0, stream>>>(
          b_rbar, b_WvT, f_bv, b_inf, KN, 256, 256, 384);
  };

  run_layer(L[0], false);
  run_layer(L[1], true);
}

// Round 14
// 558.483 us; speedup vs baseline: 5.5772x; 1.0436x over previous
//
#include <hip/hip_runtime.h>
#include <hip/hip_bf16.h>

typedef __hip_bfloat16 bf16;
typedef __attribute__((ext_vector_type(8))) short short8;
typedef __attribute__((ext_vector_type(4))) short short4v;
typedef __attribute__((ext_vector_type(4))) float f32x4;

#define KN 8384
#define KNPAD 8448   /* 66*128, pad rows for unguarded A staging */
#define KE 50000
#define NBIG 4480    /* 4096 feat + 256 qk + 128 elr(pad) = 35*128 */

__device__ __forceinline__ float toF(float v){ return v; }
__device__ __forceinline__ float toF(bf16 v){ return __bfloat162float(v); }
__device__ __forceinline__ float b2f(short u){ return __uint_as_float(((unsigned int)(unsigned short)u) << 16); }
__device__ __forceinline__ void stor(float* p, float v){ *p = v; }
__device__ __forceinline__ void stor(bf16* p, float v){ *p = __float2bfloat16(v); }

// async global->LDS, 16B per lane; LDS dest = wave-uniform base + lane*16
__device__ __forceinline__ void glds16(const bf16* g, bf16* l){
  __builtin_amdgcn_global_load_lds(
      (const __attribute__((address_space(1))) unsigned int*)(g),
      (__attribute__((address_space(3))) unsigned int*)(l), 16, 0, 0);
}

// ---------------- MFMA GEMM: C[M,N](ldc) = A[M,K]bf16 @ BT[N,K]bf16 (+bias) ----------------
template<typename TC>
__global__ __launch_bounds__(256)
void gemm_mfma_bt(const bf16* __restrict__ A, const bf16* __restrict__ BT,
                  const float* __restrict__ bias, TC* __restrict__ C,
                  int M, int N, int K, int ldc)
{
  __shared__ bf16 As[128 * 32];
  __shared__ bf16 Bs[128 * 32];
  const int bm = blockIdx.y * 128, bn = blockIdx.x * 128;
  const int tid = threadIdx.x;
  const int w = tid >> 6, l = tid & 63;
  const int wr = (w >> 1) * 64, wc = (w & 1) * 64;
  const int lr = l & 15;
  int rS[2], lqS[2];
  #pragma unroll
  for (int i = 0; i < 2; i++){
    rS[i] = w * 32 + i * 16 + (l >> 2);
    lqS[i] = (l & 3) ^ ((rS[i] >> 1) & 3);
  }
  const bf16* gA0 = A  + (size_t)(bm + rS[0]) * K + lqS[0] * 8;
  const bf16* gA1 = A  + (size_t)(bm + rS[1]) * K + lqS[1] * 8;
  const bf16* gB0 = BT + (size_t)(bn + rS[0]) * K + lqS[0] * 8;
  const bf16* gB1 = BT + (size_t)(bn + rS[1]) * K + lqS[1] * 8;
  bf16* lA0 = &As[w * 1024];
  bf16* lA1 = &As[w * 1024 + 512];
  bf16* lB0 = &Bs[w * 1024];
  bf16* lB1 = &Bs[w * 1024 + 512];
  f32x4 acc[4][4] = {};
  for (int k0 = 0; k0 < K; k0 += 32) {
    glds16(gA0 + k0, lA0);
    glds16(gA1 + k0, lA1);
    glds16(gB0 + k0, lB0);
    glds16(gB1 + k0, lB1);
    __syncthreads();
    short8 a[4], b[4];
    #pragma unroll
    for (int i = 0; i < 4; i++){
      int R = wr + i * 16 + lr;
      int pq = (l >> 4) ^ ((R >> 1) & 3);
      a[i] = *(short8*)&As[R * 32 + pq * 8];
    }
    #pragma unroll
    for (int j = 0; j < 4; j++){
      int R = wc + j * 16 + lr;
      int pq = (l >> 4) ^ ((R >> 1) & 3);
      b[j] = *(short8*)&Bs[R * 32 + pq * 8];
    }
    #pragma unroll
    for (int i = 0; i < 4; i++)
      #pragma unroll
      for (int j = 0; j < 4; j++)
        acc[i][j] = __builtin_amdgcn_mfma_f32_16x16x32_bf16(a[i], b[j], acc[i][j], 0, 0, 0);
    __syncthreads();
  }
  const int orow = (l >> 4) * 4, ocol = l & 15;
  #pragma unroll
  for (int i = 0; i < 4; i++){
    #pragma unroll
    for (int j = 0; j < 4; j++){
      int gcol = bn + wc + j * 16 + ocol;
      float bv = bias ? bias[gcol] : 0.f;
      #pragma unroll
      for (int rg = 0; rg < 4; rg++){
        int grow = bm + wr + i * 16 + orow + rg;
        if (grow < M) stor(&C[(size_t)grow * ldc + gcol], acc[i][j][rg] + bv);
      }
    }
  }
}

// ---------------- batched gw transpose-cast into BT_big rows 0..4095 ----------------
__global__ void k_transGW(const float* __restrict__ gw, bf16* __restrict__ bigBT){
  __shared__ float t[32][33];
  int rel = blockIdx.z;
  const float* B = gw + (size_t)rel * 384 * 1024;
  bf16* BT = bigBT + (size_t)rel * 1024 * 384;
  int n0 = blockIdx.x * 32, k0 = blockIdx.y * 32;
  int tx = threadIdx.x, ty = threadIdx.y;
  for (int i = ty; i < 32; i += 8)
    t[i][tx] = B[(size_t)(k0 + i) * 1024 + n0 + tx];
  __syncthreads();
  for (int i = ty; i < 32; i += 8)
    BT[(size_t)(n0 + i) * 384 + k0 + tx] = __float2bfloat16(t[tx][i]);
}

// ---------------- GALR rows 4352..4383: (gw@al | gw@ar), wave-parallel ----------------
__global__ __launch_bounds__(256)
void k_galr(const float* __restrict__ gw, const float* __restrict__ al,
            const float* __restrict__ ar, bf16* __restrict__ bigBT){
  int r = blockIdx.y;
  int k = blockIdx.x * 4 + (threadIdx.x >> 6);
  int lane = threadIdx.x & 63;
  int rr = r & 15, t = rr >> 2, h = rr & 3;
  const float* wsrc = ((r < 16) ? al : ar) + t * 1024 + h * 256;
  const float* gp = gw + (size_t)t * 384 * 1024 + (size_t)k * 1024 + h * 256;
  float v = 0.f;
  #pragma unroll
  for (int i = 0; i < 4; i++){
    int o = lane + i * 64;
    v += gp[o] * wsrc[o];
  }
  #pragma unroll
  for (int off = 32; off; off >>= 1) v += __shfl_down(v, off);
  if (lane == 0) bigBT[(size_t)(4352 + r) * 384 + k] = __float2bfloat16(v);
}

__global__ void k_zpad(bf16* bigBT){
  int i = blockIdx.x * blockDim.x + threadIdx.x;
  if (i < 96 * 384) bigBT[(size_t)4384 * 384 + i] = __float2bfloat16(0.f);
}

// ---------------- weight prep: transpose 4x [256][256] f32 ----------------
__global__ void k_wprep(const float* __restrict__ ipw, const float* __restrict__ wkw,
                        const float* __restrict__ opw, const float* __restrict__ wvw,
                        float* __restrict__ ipwQT, float* __restrict__ wkwT,
                        float* __restrict__ opwT, float* __restrict__ wvwT){
  __shared__ float t[32][33];
  const float* S; float* D;
  switch (blockIdx.z){
    case 0: S = ipw; D = ipwQT; break;
    case 1: S = wkw; D = wkwT; break;
    case 2: S = opw; D = opwT; break;
    default: S = wvw; D = wvwT; break;
  }
  int c0 = blockIdx.x * 32, r0 = blockIdx.y * 32;
  int tx = threadIdx.x, ty = threadIdx.y;
  for (int i = ty; i < 32; i += 8)
    t[i][tx] = S[(size_t)(r0 + i) * 256 + c0 + tx];
  __syncthreads();
  for (int i = ty; i < 32; i += 8)
    D[(size_t)(c0 + i) * 256 + r0 + tx] = t[tx][i];
}

// ---------------- F1 (coalesced): Wq, B2, M1, bq ----------------
__global__ __launch_bounds__(256)
void k_fold1(const float* __restrict__ wqw, const float* __restrict__ wqb,
             const float* __restrict__ ipw, const float* __restrict__ ipb,
             const float* __restrict__ ipwQT, const float* __restrict__ wkwT,
             const float* __restrict__ opwT,
             float* __restrict__ Wq, float* __restrict__ B2,
             float* __restrict__ M1, float* __restrict__ bq){
  int b = blockIdx.x, tid = threadIdx.x;
  if (b < 128){
    int c = b; float s = 0.f;
    for (int e = 0; e < 256; e++) s += wqw[c * 256 + e] * ipwQT[e * 256 + tid];
    Wq[c * 256 + tid] = s;
  } else if (b < 384){
    int j = b - 128; float s = 0.f;
    for (int e = 0; e < 256; e++) s += wkwT[e * 256 + tid] * ipw[(256 + j) * 256 + e];
    B2[j * 256 + tid] = s;
  } else if (b < 640){
    int e = b - 384; float s = 0.f;
    for (int f = 0; f < 256; f++) s += ipw[(512 + f) * 256 + e] * opwT[f * 256 + tid];
    M1[e * 256 + tid] = s;
  } else {
    float s = 0.f;
    for (int e = 0; e < 256; e++) s += wqb[e] * ipwQT[e * 256 + tid];
    bq[tid] = s + ipb[tid];
  }
}

// ---------------- F2 (coalesced): W2->bigBT qk rows, WvT, bv, biasc ----------------
__global__ __launch_bounds__(256)
void k_fold2(const float* __restrict__ Wq, const float* __restrict__ B2,
             const float* __restrict__ M1, const float* __restrict__ bq,
             const float* __restrict__ wvb, const float* __restrict__ ipb,
             const float* __restrict__ opb,
             const float* __restrict__ wvwT, const float* __restrict__ opwT,
             bf16* __restrict__ bigBT, bf16* __restrict__ WvT,
             float* __restrict__ bv, float* __restrict__ biasc){
  int b = blockIdx.x, tid = threadIdx.x;
  if (b < 256){
    int d = b; float s = 0.f;
    for (int j = 0; j < 256; j++) s += Wq[d * 256 + j] * B2[j * 256 + tid];
    bigBT[(size_t)(4096 + tid) * 384 + 256 + d] = __float2bfloat16(s);
  } else if (b < 512){
    int j = b - 256; float s = 0.f;
    for (int e = 0; e < 256; e++) s += wvwT[e * 256 + tid] * M1[e * 256 + j];
    WvT[j * 256 + tid] = __float2bfloat16(s);
  } else {
    float b2 = 0.f;
    for (int j = 0; j < 256; j++) b2 += bq[j] * B2[j * 256 + tid];
    float s = 0.f;
    for (int e = 0; e < 256; e++) s += wvb[e] * M1[e * 256 + tid];
    for (int f = 0; f < 256; f++) s += ipb[512 + f] * opwT[f * 256 + tid];
    bv[tid] = s + opb[tid];
    for (int i = tid; i < NBIG; i += 256)
      biasc[i] = (i - 4096 == tid) ? b2 : 0.f;
    for (int k = 0; k < 256; k++)
      bigBT[(size_t)(4096 + tid) * 384 + k] = __float2bfloat16(0.f);
  }
}

// ---------------- pre-phase ----------------
__global__ __launch_bounds__(384)
void k_pre(const float* __restrict__ cf, const float* __restrict__ cfw, const float* __restrict__ cfb,
           const float* __restrict__ htw, const float* __restrict__ htb,
           float* __restrict__ cfvec, float* __restrict__ duc)
{
  int c = blockIdx.x;
  int col = threadIdx.x;
  __shared__ float row[512];
  for (int i = col; i < 512; i += 384) row[i] = cf[c * 512 + i];
  __syncthreads();
  if (col < 128){
    float acc = cfb[col];
    for (int k = 0; k < 512; k++) acc += row[k] * cfw[k * 128 + col];
    cfvec[c * 128 + col] = acc;
  } else {
    int j = col - 128;
    float acc = htb[j];
    for (int k = 0; k < 512; k++) acc += row[k] * htw[k * 256 + j];
    duc[c * 256 + j] = acc;
  }
}
__global__ void k_mean(const float* cv, float* m){
  int o = threadIdx.x;
  float s = 0.f;
  for (int c = 0; c < 64; c++) s += cv[c * 128 + o];
  m[o] = s * (1.f / 64.f);
}
// fused inf assembly: cols 0..255 = dfeat, 256..383 = cfin
__global__ __launch_bounds__(384)
void k_infasm(const float* __restrict__ x, const float* __restrict__ duc,
              const float* __restrict__ cv, const float* __restrict__ cm,
              bf16* __restrict__ inf){
  int n = blockIdx.x, o = threadIdx.x;
  float v;
  if (o < 256){
    if (n < 8192)      v = x[(n & 127) * 256 + o];
    else if (n < 8256) v = duc[(n - 8192) * 256 + o];
    else               v = x[(n - 8256) * 256 + o];
  } else {
    int oo = o - 256;
    if (n < 8192)      v = cv[(n >> 7) * 128 + oo];
    else if (n < 8256) v = cv[(n - 8192) * 128 + oo];
    else               v = cm[oo];
  }
  inf[(size_t)n * 384 + o] = __float2bfloat16(v);
}
__global__ void k_zeroi(int* p, int n){
  int i = blockIdx.x * blockDim.x + threadIdx.x; if (i < n) p[i] = 0;
}
__global__ void k_copyi(const int* a, int* b, int n){
  int i = blockIdx.x * blockDim.x + threadIdx.x; if (i < n) b[i] = a[i];
}
__global__ void k_countB(const int* __restrict__ edges, int* __restrict__ cnt){
  int i = blockIdx.x * blockDim.x + threadIdx.x;
  if (i < 4 * KE){
    int t = i / KE, idx = i - t * KE;
    int d = edges[t * 2 * KE + KE + idx];
    atomicAdd(&cnt[t * KN + d], 1);
  }
}
__global__ void k_fillB(const int* __restrict__ edges, int* __restrict__ cur, int* __restrict__ csrc){
  int i = blockIdx.x * blockDim.x + threadIdx.x;
  if (i < 4 * KE){
    int t = i / KE, idx = i - t * KE;
    int s = edges[t * 2 * KE + idx];
    int d = edges[t * 2 * KE + KE + idx];
    int p = atomicAdd(&cur[t * KN + d], 1);
    csrc[p] = s;
  }
}
__global__ void k_scan(const int* __restrict__ cnt, int* __restrict__ ptr, int n){
  __shared__ int part[1024];
  int tid = threadIdx.x;
  const int CH = (n + 1023) >> 10;
  int base = tid * CH;
  int s = 0;
  for (int i = 0; i < CH; i++){ int idx = base + i; if (idx < n) s += cnt[idx]; }
  part[tid] = s; __syncthreads();
  for (int off = 1; off < 1024; off <<= 1){
    int v = (tid >= off) ? part[tid - off] : 0;
    __syncthreads();
    part[tid] += v;
    __syncthreads();
  }
  int run = part[tid] - s;
  for (int i = 0; i < CH; i++){
    int idx = base + i;
    if (idx < n){ ptr[idx] = run; run += cnt[idx]; }
  }
  if (tid == 1023) ptr[n] = part[1023];
}

// ------------- fused GAT agg + attention: wave w = relation w, barrier-free gather -------------
__global__ __launch_bounds__(256)
void k_aggattn(const int* __restrict__ ptr, const int* __restrict__ csrc,
               const bf16* __restrict__ big, const float* __restrict__ gb,
               bf16* __restrict__ rbar)
{
  const int n = blockIdx.x, tid = threadIdx.x;
  const int w = tid >> 6, lane = tid & 63;
  const int t = w;                       // wave == relation
  const int head = lane >> 4;            // lane's head within the relation
  __shared__ float s_rst[16][260];
  __shared__ float s_sc[16];
  __shared__ float sa4[4][64][4];
  __shared__ int ssrcW[4][64];
  const int beg = ptr[t * KN + n], deg = ptr[t * KN + n + 1] - beg;
  // er (4 heads, adjacent cols)
  short4v e4 = *(const short4v*)&big[(size_t)n * NBIG + 4368 + t * 4];
  float ern[4] = {b2f(e4[0]), b2f(e4[1]), b2f(e4[2]), b2f(e4[3])};
  // pass 1: per-head sum of exp
  float sums[4] = {0.f, 0.f, 0.f, 0.f};
  for (int j = lane; j < deg; j += 64){
    int s = csrc[beg + j];
    short4v l4 = *(const short4v*)&big[(size_t)s * NBIG + 4352 + t * 4];
    #pragma unroll
    for (int h = 0; h < 4; h++){
      float e = b2f(l4[h]) + ern[h];
      e = e > 0.f ? e : 0.2f * e;
      sums[h] += __expf(e);
    }
  }
  #pragma unroll
  for (int off = 32; off; off >>= 1){
    #pragma unroll
    for (int h = 0; h < 4; h++) sums[h] += __shfl_xor(sums[h], off);
  }
  float sinv[4];
  #pragma unroll
  for (int h = 0; h < 4; h++) sinv[h] = 1.f / fmaxf(sums[h], 1e-9f);
  // pass 2: chunked gather, per-wave LDS staging (no barriers; same-wave lgkmcnt)
  float acc[16];
  #pragma unroll
  for (int i = 0; i < 16; i++) acc[i] = 0.f;
  const size_t cbase = (size_t)t * 1024 + lane * 16;
  for (int c0 = 0; c0 < deg; c0 += 64){
    int cn = min(64, deg - c0);
    if (lane < cn){
      int s = csrc[beg + c0 + lane];
      ssrcW[t][lane] = s;
      short4v l4 = *(const short4v*)&big[(size_t)s * NBIG + 4352 + t * 4];
      #pragma unroll
      for (int h = 0; h < 4; h++){
        float e = b2f(l4[h]) + ern[h];
        e = e > 0.f ? e : 0.2f * e;
        sa4[t][lane][h] = __expf(e) * sinv[h];
      }
    }
    for (int j = 0; j < cn; j++){
      int s = ssrcW[t][j];
      float wj = sa4[t][j][head];
      const bf16* fp = &big[(size_t)s * NBIG + cbase];
      short8 v0 = *(const short8*)fp;
      short8 v1 = *(const short8*)(fp + 8);
      #pragma unroll
      for (int i = 0; i < 8; i++) acc[i] += wj * b2f(v0[i]);
      #pragma unroll
      for (int i = 0; i < 8; i++) acc[8 + i] += wj * b2f(v1[i]);
    }
  }
  // epilogue: +gb, stash rst row slice in LDS (f32)
  {
    const float* gbp = gb + t * 1024 + lane * 16;
    float* rp = &s_rst[t * 4 + head][(lane & 15) * 16];
    #pragma unroll
    for (int i = 0; i < 16; i++) rp[i] = acc[i] + gbp[i];
  }
  __syncthreads();
  // scores: wave w handles s = w*4+si : dot(s_rst[s], qk)
  const bf16* q = big + (size_t)n * NBIG + 4096;
  #pragma unroll
  for (int si = 0; si < 4; si++){
    int s = w * 4 + si;
    float v = 0.f;
    #pragma unroll
    for (int i = 0; i < 4; i++){
      int o = lane + i * 64;
      v += s_rst[s][o] * toF(q[o]);
    }
    #pragma unroll
    for (int off = 32; off; off >>= 1) v += __shfl_down(v, off);
    if (lane == 0) s_sc[s] = v * 0.0625f;
  }
  __syncthreads();
  float sc[16]; float m = -1e30f;
  #pragma unroll
  for (int s = 0; s < 16; s++){ sc[s] = s_sc[s]; m = fmaxf(m, sc[s]); }
  float sum = 0.f;
  #pragma unroll
  for (int s = 0; s < 16; s++){ sc[s] = __expf(sc[s] - m); sum += sc[s]; }
  float inv = 1.f / sum;
  float r = 0.f;
  #pragma unroll
  for (int s = 0; s < 16; s++) r += sc[s] * s_rst[s][tid];
  rbar[(size_t)n * 256 + tid] = __float2bfloat16(r * inv);
}

struct LWT {
  const float *gw, *al, *ar, *gb, *wqw, *wqb, *wkw, *wkb, *wvw, *wvb, *ipw, *ipb, *opw, *opb;
};

extern "C" void kernel_launch(void* const* d_in, const int* in_sizes, int n_in,
                              void* d_out, int out_size, void* d_ws, size_t ws_size,
                              hipStream_t stream)
{
  const float* x   = (const float*)d_in[0];
  const float* cf  = (const float*)d_in[1];
  const float* cfw = (const float*)d_in[2];
  const float* cfb = (const float*)d_in[3];
  const float* htw = (const float*)d_in[4];
  const float* htb = (const float*)d_in[5];
  LWT L[2];
  for (int l = 0; l < 2; l++){
    int b = 6 + l * 14;
    L[l].gw  = (const float*)d_in[b + 0];
    L[l].al  = (const float*)d_in[b + 1];
    L[l].ar  = (const float*)d_in[b + 2];
    L[l].gb  = (const float*)d_in[b + 3];
    L[l].wqw = (const float*)d_in[b + 4];
    L[l].wqb = (const float*)d_in[b + 5];
    L[l].wkw = (const float*)d_in[b + 6];
    L[l].wkb = (const float*)d_in[b + 7];
    L[l].wvw = (const float*)d_in[b + 8];
    L[l].wvb = (const float*)d_in[b + 9];
    L[l].ipw = (const float*)d_in[b + 10];
    L[l].ipb = (const float*)d_in[b + 11];
    L[l].opw = (const float*)d_in[b + 12];
    L[l].opb = (const float*)d_in[b + 13];
  }
  const int* edges = (const int*)d_in[34];

  // -------- workspace layout --------
  char* w = (char*)d_ws;
  size_t off = 0;
  auto alc = [&](size_t bytes) -> void* {
    off = (off + 255) & ~(size_t)255;
    void* p = w + off; off += bytes; return p;
  };
  float* f_cfvec = (float*)alc(64 * 128 * 4);
  float* f_cfmean= (float*)alc(128 * 4);
  float* f_duc   = (float*)alc(64 * 256 * 4);
  bf16*  b_inf   = (bf16*) alc((size_t)KNPAD * 384 * 2);
  bf16*  b_big   = (bf16*) alc((size_t)KN * NBIG * 2);
  bf16*  b_bigBT = (bf16*) alc((size_t)NBIG * 384 * 2);
  float* f_biasc = (float*)alc((size_t)NBIG * 4);
  bf16*  b_rbar  = (bf16*) alc((size_t)KNPAD * 256 * 2);
  float* f_Wq    = (float*)alc(128 * 256 * 4);
  float* f_B2    = (float*)alc(256 * 256 * 4);
  float* f_M1    = (float*)alc(256 * 256 * 4);
  float* f_bq    = (float*)alc(256 * 4);
  float* f_bv    = (float*)alc(256 * 4);
  bf16*  b_WvT   = (bf16*) alc(256 * 256 * 2);
  float* f_ipwQT = (float*)alc(256 * 256 * 4);
  float* f_wkwT  = (float*)alc(256 * 256 * 4);
  float* f_opwT  = (float*)alc(256 * 256 * 4);
  float* f_wvwT  = (float*)alc(256 * 256 * 4);
  int*   i_ptr   = (int*)  alc((size_t)(4 * KN + 1) * 4);
  int*   i_src   = (int*)  alc((size_t)4 * KE * 4);
  int*   i_cnt   = (int*)  alc((size_t)4 * KN * 4);
  int*   i_cur   = (int*)  alc((size_t)4 * KN * 4);
  if (off > ws_size) return;

  // -------- pre-phase --------
  k_pre<<<64, 384, 0, stream>>>(cf, cfw, cfb, htw, htb, f_cfvec, f_duc);
  k_mean<<<1, 128, 0, stream>>>(f_cfvec, f_cfmean);
  k_infasm<<<KN, 384, 0, stream>>>(x, f_duc, f_cfvec, f_cfmean, b_inf);
  k_zpad<<<(96 * 384 + 255) / 256, 256, 0, stream>>>(b_bigBT);

  // -------- batched CSR --------
  k_zeroi<<<(4 * KN + 255) / 256, 256, 0, stream>>>(i_cnt, 4 * KN);
  k_countB<<<(4 * KE + 255) / 256, 256, 0, stream>>>(edges, i_cnt);
  k_scan<<<1, 1024, 0, stream>>>(i_cnt, i_ptr, 4 * KN);
  k_copyi<<<(4 * KN + 255) / 256, 256, 0, stream>>>(i_ptr, i_cur, 4 * KN);
  k_fillB<<<(4 * KE + 255) / 256, 256, 0, stream>>>(edges, i_cur, i_src);

  // -------- one layer --------
  auto run_layer = [&](const LWT& Wt, bool last){
    k_transGW<<<dim3(32, 12, 4), dim3(32, 8), 0, stream>>>(Wt.gw, b_bigBT);
    k_galr<<<dim3(96, 32), 256, 0, stream>>>(Wt.gw, Wt.al, Wt.ar, b_bigBT);
    k_wprep<<<dim3(8, 8, 4), dim3(32, 8), 0, stream>>>(Wt.ipw, Wt.wkw, Wt.opw, Wt.wvw,
                                                       f_ipwQT, f_wkwT, f_opwT, f_wvwT);
    k_fold1<<<641, 256, 0, stream>>>(Wt.wqw, Wt.wqb, Wt.ipw, Wt.ipb,
                                     f_ipwQT, f_wkwT, f_opwT,
                                     f_Wq, f_B2, f_M1, f_bq);
    k_fold2<<<513, 256, 0, stream>>>(f_Wq, f_B2, f_M1, f_bq, Wt.wvb, Wt.ipb, Wt.opb,
                                     f_wvwT, f_opwT,
                                     b_bigBT, b_WvT, f_bv, f_biasc);
    gemm_mfma_bt<bf16><<<dim3(NBIG / 128, 66), 256, 0, stream>>>(
        b_inf, b_bigBT, f_biasc, b_big, KN, NBIG, 384, NBIG);
    k_aggattn<<<KN, 256, 0, stream>>>(i_ptr, i_src, b_big, Wt.gb, b_rbar);
    if (last)
      gemm_mfma_bt<float><<<dim3(2, 66), 256, 0, stream>>>(
          b_rbar, b_WvT, f_bv, (float*)d_out, KN, 256, 256, 256);
    else
      gemm_mfma_bt<bf16><<<dim3(2, 66), 256, 0, stream>>>(
          b_rbar, b_WvT, f_bv, b_inf, KN, 256, 256, 384);
  };

  run_layer(L[0], false);
  run_layer(L[1], true);
}

// Round 15
// 545.410 us; speedup vs baseline: 5.7108x; 1.0240x over previous
//
#include <hip/hip_runtime.h>
#include <hip/hip_bf16.h>

typedef __hip_bfloat16 bf16;
typedef __attribute__((ext_vector_type(8))) short short8;
typedef __attribute__((ext_vector_type(4))) short short4v;
typedef __attribute__((ext_vector_type(4))) float f32x4;

#define KN 8384
#define KNPAD 8448   /* 66*128, pad rows for unguarded A staging */
#define KE 50000
#define NBIG 4480    /* 4096 feat + 256 qk + 128 elr(pad) = 35*128 */

__device__ __forceinline__ float toF(float v){ return v; }
__device__ __forceinline__ float toF(bf16 v){ return __bfloat162float(v); }
__device__ __forceinline__ float b2f(short u){ return __uint_as_float(((unsigned int)(unsigned short)u) << 16); }
__device__ __forceinline__ void stor(float* p, float v){ *p = v; }
__device__ __forceinline__ void stor(bf16* p, float v){ *p = __float2bfloat16(v); }

// async global->LDS, 16B per lane; LDS dest = wave-uniform base + lane*16
__device__ __forceinline__ void glds16(const bf16* g, bf16* l){
  __builtin_amdgcn_global_load_lds(
      (const __attribute__((address_space(1))) unsigned int*)(g),
      (__attribute__((address_space(3))) unsigned int*)(l), 16, 0, 0);
}

// ---------------- MFMA GEMM: C[M,N](ldc) = A[M,K]bf16 @ BT[N,K]bf16 (+bias) ----------------
// 3-deep glds pipeline, counted vmcnt(4), one s_barrier/iter; XCD-chunked block swizzle.
template<typename TC>
__global__ __launch_bounds__(256)
void gemm_mfma_bt(const bf16* __restrict__ A, const bf16* __restrict__ BT,
                  const float* __restrict__ bias, TC* __restrict__ C,
                  int M, int N, int K, int ldc, int nbx)
{
  __shared__ bf16 As[3][128 * 32];
  __shared__ bf16 Bs[3][128 * 32];
  // bijective XCD-chunked swizzle (m204): contiguous sw-range per XCD
  const int nwg = gridDim.x;
  const int q = nwg >> 3, r = nwg & 7;
  const int xcd = blockIdx.x & 7, idx = blockIdx.x >> 3;
  const int sw = (xcd < r) ? xcd * (q + 1) + idx : r * (q + 1) + (xcd - r) * q + idx;
  const int bn = (sw % nbx) * 128, bm = (sw / nbx) * 128;
  const int tid = threadIdx.x;
  const int w = tid >> 6, l = tid & 63;
  const int wr = (w >> 1) * 64, wc = (w & 1) * 64;
  const int lr = l & 15;
  int rS[2], lqS[2];
  #pragma unroll
  for (int i = 0; i < 2; i++){
    rS[i] = w * 32 + i * 16 + (l >> 2);
    lqS[i] = (l & 3) ^ ((rS[i] >> 1) & 3);
  }
  const bf16* gA0 = A  + (size_t)(bm + rS[0]) * K + lqS[0] * 8;
  const bf16* gA1 = A  + (size_t)(bm + rS[1]) * K + lqS[1] * 8;
  const bf16* gB0 = BT + (size_t)(bn + rS[0]) * K + lqS[0] * 8;
  const bf16* gB1 = BT + (size_t)(bn + rS[1]) * K + lqS[1] * 8;
  const int nt = K >> 5;
  auto issue = [&](int t){
    int b = t - (t / 3) * 3;
    int k0 = t << 5;
    glds16(gA0 + k0, &As[b][w * 1024]);
    glds16(gA1 + k0, &As[b][w * 1024 + 512]);
    glds16(gB0 + k0, &Bs[b][w * 1024]);
    glds16(gB1 + k0, &Bs[b][w * 1024 + 512]);
  };
  f32x4 acc[4][4] = {};
  issue(0);
  issue(1);
  for (int t = 0; t < nt; t++){
    if (t < nt - 1) asm volatile("s_waitcnt vmcnt(4)\ns_barrier" ::: "memory");
    else            asm volatile("s_waitcnt vmcnt(0)\ns_barrier" ::: "memory");
    int b = t - (t / 3) * 3;
    short8 a[4], bb[4];
    #pragma unroll
    for (int i = 0; i < 4; i++){
      int R = wr + i * 16 + lr;
      int pq = (l >> 4) ^ ((R >> 1) & 3);
      a[i] = *(short8*)&As[b][R * 32 + pq * 8];
    }
    #pragma unroll
    for (int j = 0; j < 4; j++){
      int R = wc + j * 16 + lr;
      int pq = (l >> 4) ^ ((R >> 1) & 3);
      bb[j] = *(short8*)&Bs[b][R * 32 + pq * 8];
    }
    #pragma unroll
    for (int i = 0; i < 4; i++)
      #pragma unroll
      for (int j = 0; j < 4; j++)
        acc[i][j] = __builtin_amdgcn_mfma_f32_16x16x32_bf16(a[i], bb[j], acc[i][j], 0, 0, 0);
    if (t + 2 < nt) issue(t + 2);
  }
  const int orow = (l >> 4) * 4, ocol = l & 15;
  #pragma unroll
  for (int i = 0; i < 4; i++){
    #pragma unroll
    for (int j = 0; j < 4; j++){
      int gcol = bn + wc + j * 16 + ocol;
      float bv = bias ? bias[gcol] : 0.f;
      #pragma unroll
      for (int rg = 0; rg < 4; rg++){
        int grow = bm + wr + i * 16 + orow + rg;
        if (grow < M) stor(&C[(size_t)grow * ldc + gcol], acc[i][j][rg] + bv);
      }
    }
  }
}

// ---------------- batched gw transpose-cast into BT_big rows 0..4095 ----------------
__global__ void k_transGW(const float* __restrict__ gw, bf16* __restrict__ bigBT){
  __shared__ float t[32][33];
  int rel = blockIdx.z;
  const float* B = gw + (size_t)rel * 384 * 1024;
  bf16* BT = bigBT + (size_t)rel * 1024 * 384;
  int n0 = blockIdx.x * 32, k0 = blockIdx.y * 32;
  int tx = threadIdx.x, ty = threadIdx.y;
  for (int i = ty; i < 32; i += 8)
    t[i][tx] = B[(size_t)(k0 + i) * 1024 + n0 + tx];
  __syncthreads();
  for (int i = ty; i < 32; i += 8)
    BT[(size_t)(n0 + i) * 384 + k0 + tx] = __float2bfloat16(t[tx][i]);
}

// ---------------- GALR rows 4352..4383: (gw@al | gw@ar), wave-parallel ----------------
__global__ __launch_bounds__(256)
void k_galr(const float* __restrict__ gw, const float* __restrict__ al,
            const float* __restrict__ ar, bf16* __restrict__ bigBT){
  int r = blockIdx.y;
  int k = blockIdx.x * 4 + (threadIdx.x >> 6);
  int lane = threadIdx.x & 63;
  int rr = r & 15, t = rr >> 2, h = rr & 3;
  const float* wsrc = ((r < 16) ? al : ar) + t * 1024 + h * 256;
  const float* gp = gw + (size_t)t * 384 * 1024 + (size_t)k * 1024 + h * 256;
  float v = 0.f;
  #pragma unroll
  for (int i = 0; i < 4; i++){
    int o = lane + i * 64;
    v += gp[o] * wsrc[o];
  }
  #pragma unroll
  for (int off = 32; off; off >>= 1) v += __shfl_down(v, off);
  if (lane == 0) bigBT[(size_t)(4352 + r) * 384 + k] = __float2bfloat16(v);
}

__global__ void k_zpad(bf16* bigBT){
  int i = blockIdx.x * blockDim.x + threadIdx.x;
  if (i < 96 * 384) bigBT[(size_t)4384 * 384 + i] = __float2bfloat16(0.f);
}

// ---------------- weight prep: transpose 4x [256][256] f32 ----------------
__global__ void k_wprep(const float* __restrict__ ipw, const float* __restrict__ wkw,
                        const float* __restrict__ opw, const float* __restrict__ wvw,
                        float* __restrict__ ipwQT, float* __restrict__ wkwT,
                        float* __restrict__ opwT, float* __restrict__ wvwT){
  __shared__ float t[32][33];
  const float* S; float* D;
  switch (blockIdx.z){
    case 0: S = ipw; D = ipwQT; break;
    case 1: S = wkw; D = wkwT; break;
    case 2: S = opw; D = opwT; break;
    default: S = wvw; D = wvwT; break;
  }
  int c0 = blockIdx.x * 32, r0 = blockIdx.y * 32;
  int tx = threadIdx.x, ty = threadIdx.y;
  for (int i = ty; i < 32; i += 8)
    t[i][tx] = S[(size_t)(r0 + i) * 256 + c0 + tx];
  __syncthreads();
  for (int i = ty; i < 32; i += 8)
    D[(size_t)(c0 + i) * 256 + r0 + tx] = t[tx][i];
}

// ---------------- F1 (coalesced): Wq, B2, M1, bq ----------------
__global__ __launch_bounds__(256)
void k_fold1(const float* __restrict__ wqw, const float* __restrict__ wqb,
             const float* __restrict__ ipw, const float* __restrict__ ipb,
             const float* __restrict__ ipwQT, const float* __restrict__ wkwT,
             const float* __restrict__ opwT,
             float* __restrict__ Wq, float* __restrict__ B2,
             float* __restrict__ M1, float* __restrict__ bq){
  int b = blockIdx.x, tid = threadIdx.x;
  if (b < 128){
    int c = b; float s = 0.f;
    for (int e = 0; e < 256; e++) s += wqw[c * 256 + e] * ipwQT[e * 256 + tid];
    Wq[c * 256 + tid] = s;
  } else if (b < 384){
    int j = b - 128; float s = 0.f;
    for (int e = 0; e < 256; e++) s += wkwT[e * 256 + tid] * ipw[(256 + j) * 256 + e];
    B2[j * 256 + tid] = s;
  } else if (b < 640){
    int e = b - 384; float s = 0.f;
    for (int f = 0; f < 256; f++) s += ipw[(512 + f) * 256 + e] * opwT[f * 256 + tid];
    M1[e * 256 + tid] = s;
  } else {
    float s = 0.f;
    for (int e = 0; e < 256; e++) s += wqb[e] * ipwQT[e * 256 + tid];
    bq[tid] = s + ipb[tid];
  }
}

// ---------------- F2 (coalesced): W2->bigBT qk rows, WvT, bv, biasc ----------------
__global__ __launch_bounds__(256)
void k_fold2(const float* __restrict__ Wq, const float* __restrict__ B2,
             const float* __restrict__ M1, const float* __restrict__ bq,
             const float* __restrict__ wvb, const float* __restrict__ ipb,
             const float* __restrict__ opb,
             const float* __restrict__ wvwT, const float* __restrict__ opwT,
             bf16* __restrict__ bigBT, bf16* __restrict__ WvT,
             float* __restrict__ bv, float* __restrict__ biasc){
  int b = blockIdx.x, tid = threadIdx.x;
  if (b < 256){
    int d = b; float s = 0.f;
    for (int j = 0; j < 256; j++) s += Wq[d * 256 + j] * B2[j * 256 + tid];
    bigBT[(size_t)(4096 + tid) * 384 + 256 + d] = __float2bfloat16(s);
  } else if (b < 512){
    int j = b - 256; float s = 0.f;
    for (int e = 0; e < 256; e++) s += wvwT[e * 256 + tid] * M1[e * 256 + j];
    WvT[j * 256 + tid] = __float2bfloat16(s);
  } else {
    float b2 = 0.f;
    for (int j = 0; j < 256; j++) b2 += bq[j] * B2[j * 256 + tid];
    float s = 0.f;
    for (int e = 0; e < 256; e++) s += wvb[e] * M1[e * 256 + tid];
    for (int f = 0; f < 256; f++) s += ipb[512 + f] * opwT[f * 256 + tid];
    bv[tid] = s + opb[tid];
    for (int i = tid; i < NBIG; i += 256)
      biasc[i] = (i - 4096 == tid) ? b2 : 0.f;
    for (int k = 0; k < 256; k++)
      bigBT[(size_t)(4096 + tid) * 384 + k] = __float2bfloat16(0.f);
  }
}

// ---------------- pre-phase ----------------
__global__ __launch_bounds__(384)
void k_pre(const float* __restrict__ cf, const float* __restrict__ cfw, const float* __restrict__ cfb,
           const float* __restrict__ htw, const float* __restrict__ htb,
           float* __restrict__ cfvec, float* __restrict__ duc)
{
  int c = blockIdx.x;
  int col = threadIdx.x;
  __shared__ float row[512];
  for (int i = col; i < 512; i += 384) row[i] = cf[c * 512 + i];
  __syncthreads();
  if (col < 128){
    float acc = cfb[col];
    for (int k = 0; k < 512; k++) acc += row[k] * cfw[k * 128 + col];
    cfvec[c * 128 + col] = acc;
  } else {
    int j = col - 128;
    float acc = htb[j];
    for (int k = 0; k < 512; k++) acc += row[k] * htw[k * 256 + j];
    duc[c * 256 + j] = acc;
  }
}
__global__ void k_mean(const float* cv, float* m){
  int o = threadIdx.x;
  float s = 0.f;
  for (int c = 0; c < 64; c++) s += cv[c * 128 + o];
  m[o] = s * (1.f / 64.f);
}
__global__ __launch_bounds__(384)
void k_infasm(const float* __restrict__ x, const float* __restrict__ duc,
              const float* __restrict__ cv, const float* __restrict__ cm,
              bf16* __restrict__ inf){
  int n = blockIdx.x, o = threadIdx.x;
  float v;
  if (o < 256){
    if (n < 8192)      v = x[(n & 127) * 256 + o];
    else if (n < 8256) v = duc[(n - 8192) * 256 + o];
    else               v = x[(n - 8256) * 256 + o];
  } else {
    int oo = o - 256;
    if (n < 8192)      v = cv[(n >> 7) * 128 + oo];
    else if (n < 8256) v = cv[(n - 8192) * 128 + oo];
    else               v = cm[oo];
  }
  inf[(size_t)n * 384 + o] = __float2bfloat16(v);
}
__global__ void k_zeroi(int* p, int n){
  int i = blockIdx.x * blockDim.x + threadIdx.x; if (i < n) p[i] = 0;
}
__global__ void k_copyi(const int* a, int* b, int n){
  int i = blockIdx.x * blockDim.x + threadIdx.x; if (i < n) b[i] = a[i];
}
__global__ void k_countB(const int* __restrict__ edges, int* __restrict__ cnt){
  int i = blockIdx.x * blockDim.x + threadIdx.x;
  if (i < 4 * KE){
    int t = i / KE, idx = i - t * KE;
    int d = edges[t * 2 * KE + KE + idx];
    atomicAdd(&cnt[t * KN + d], 1);
  }
}
__global__ void k_fillB(const int* __restrict__ edges, int* __restrict__ cur, int* __restrict__ csrc){
  int i = blockIdx.x * blockDim.x + threadIdx.x;
  if (i < 4 * KE){
    int t = i / KE, idx = i - t * KE;
    int s = edges[t * 2 * KE + idx];
    int d = edges[t * 2 * KE + KE + idx];
    int p = atomicAdd(&cur[t * KN + d], 1);
    csrc[p] = s;
  }
}
__global__ void k_scan(const int* __restrict__ cnt, int* __restrict__ ptr, int n){
  __shared__ int part[1024];
  int tid = threadIdx.x;
  const int CH = (n + 1023) >> 10;
  int base = tid * CH;
  int s = 0;
  for (int i = 0; i < CH; i++){ int idx = base + i; if (idx < n) s += cnt[idx]; }
  part[tid] = s; __syncthreads();
  for (int off = 1; off < 1024; off <<= 1){
    int v = (tid >= off) ? part[tid - off] : 0;
    __syncthreads();
    part[tid] += v;
    __syncthreads();
  }
  int run = part[tid] - s;
  for (int i = 0; i < CH; i++){
    int idx = base + i;
    if (idx < n){ ptr[idx] = run; run += cnt[idx]; }
  }
  if (tid == 1023) ptr[n] = part[1023];
}

// ------------- fused GAT agg + attention: wave w = relation w, barrier-free gather -------------
__global__ __launch_bounds__(256)
void k_aggattn(const int* __restrict__ ptr, const int* __restrict__ csrc,
               const bf16* __restrict__ big, const float* __restrict__ gb,
               bf16* __restrict__ rbar)
{
  const int n = blockIdx.x, tid = threadIdx.x;
  const int w = tid >> 6, lane = tid & 63;
  const int t = w;
  const int head = lane >> 4;
  __shared__ float s_rst[16][260];
  __shared__ float s_sc[16];
  __shared__ float sa4[4][64][4];
  __shared__ int ssrcW[4][64];
  const int beg = ptr[t * KN + n], deg = ptr[t * KN + n + 1] - beg;
  short4v e4 = *(const short4v*)&big[(size_t)n * NBIG + 4368 + t * 4];
  float ern[4] = {b2f(e4[0]), b2f(e4[1]), b2f(e4[2]), b2f(e4[3])};
  float sums[4] = {0.f, 0.f, 0.f, 0.f};
  for (int j = lane; j < deg; j += 64){
    int s = csrc[beg + j];
    short4v l4 = *(const short4v*)&big[(size_t)s * NBIG + 4352 + t * 4];
    #pragma unroll
    for (int h = 0; h < 4; h++){
      float e = b2f(l4[h]) + ern[h];
      e = e > 0.f ? e : 0.2f * e;
      sums[h] += __expf(e);
    }
  }
  #pragma unroll
  for (int off = 32; off; off >>= 1){
    #pragma unroll
    for (int h = 0; h < 4; h++) sums[h] += __shfl_xor(sums[h], off);
  }
  float sinv[4];
  #pragma unroll
  for (int h = 0; h < 4; h++) sinv[h] = 1.f / fmaxf(sums[h], 1e-9f);
  float acc[16];
  #pragma unroll
  for (int i = 0; i < 16; i++) acc[i] = 0.f;
  const size_t cbase = (size_t)t * 1024 + lane * 16;
  for (int c0 = 0; c0 < deg; c0 += 64){
    int cn = min(64, deg - c0);
    if (lane < cn){
      int s = csrc[beg + c0 + lane];
      ssrcW[t][lane] = s;
      short4v l4 = *(const short4v*)&big[(size_t)s * NBIG + 4352 + t * 4];
      #pragma unroll
      for (int h = 0; h < 4; h++){
        float e = b2f(l4[h]) + ern[h];
        e = e > 0.f ? e : 0.2f * e;
        sa4[t][lane][h] = __expf(e) * sinv[h];
      }
    }
    for (int j = 0; j < cn; j++){
      int s = ssrcW[t][j];
      float wj = sa4[t][j][head];
      const bf16* fp = &big[(size_t)s * NBIG + cbase];
      short8 v0 = *(const short8*)fp;
      short8 v1 = *(const short8*)(fp + 8);
      #pragma unroll
      for (int i = 0; i < 8; i++) acc[i] += wj * b2f(v0[i]);
      #pragma unroll
      for (int i = 0; i < 8; i++) acc[8 + i] += wj * b2f(v1[i]);
    }
  }
  {
    const float* gbp = gb + t * 1024 + lane * 16;
    float* rp = &s_rst[t * 4 + head][(lane & 15) * 16];
    #pragma unroll
    for (int i = 0; i < 16; i++) rp[i] = acc[i] + gbp[i];
  }
  __syncthreads();
  const bf16* q = big + (size_t)n * NBIG + 4096;
  #pragma unroll
  for (int si = 0; si < 4; si++){
    int s = w * 4 + si;
    float v = 0.f;
    #pragma unroll
    for (int i = 0; i < 4; i++){
      int o = lane + i * 64;
      v += s_rst[s][o] * toF(q[o]);
    }
    #pragma unroll
    for (int off = 32; off; off >>= 1) v += __shfl_down(v, off);
    if (lane == 0) s_sc[s] = v * 0.0625f;
  }
  __syncthreads();
  float sc[16]; float m = -1e30f;
  #pragma unroll
  for (int s = 0; s < 16; s++){ sc[s] = s_sc[s]; m = fmaxf(m, sc[s]); }
  float sum = 0.f;
  #pragma unroll
  for (int s = 0; s < 16; s++){ sc[s] = __expf(sc[s] - m); sum += sc[s]; }
  float inv = 1.f / sum;
  float r = 0.f;
  #pragma unroll
  for (int s = 0; s < 16; s++) r += sc[s] * s_rst[s][tid];
  rbar[(size_t)n * 256 + tid] = __float2bfloat16(r * inv);
}

struct LWT {
  const float *gw, *al, *ar, *gb, *wqw, *wqb, *wkw, *wkb, *wvw, *wvb, *ipw, *ipb, *opw, *opb;
};

extern "C" void kernel_launch(void* const* d_in, const int* in_sizes, int n_in,
                              void* d_out, int out_size, void* d_ws, size_t ws_size,
                              hipStream_t stream)
{
  const float* x   = (const float*)d_in[0];
  const float* cf  = (const float*)d_in[1];
  const float* cfw = (const float*)d_in[2];
  const float* cfb = (const float*)d_in[3];
  const float* htw = (const float*)d_in[4];
  const float* htb = (const float*)d_in[5];
  LWT L[2];
  for (int l = 0; l < 2; l++){
    int b = 6 + l * 14;
    L[l].gw  = (const float*)d_in[b + 0];
    L[l].al  = (const float*)d_in[b + 1];
    L[l].ar  = (const float*)d_in[b + 2];
    L[l].gb  = (const float*)d_in[b + 3];
    L[l].wqw = (const float*)d_in[b + 4];
    L[l].wqb = (const float*)d_in[b + 5];
    L[l].wkw = (const float*)d_in[b + 6];
    L[l].wkb = (const float*)d_in[b + 7];
    L[l].wvw = (const float*)d_in[b + 8];
    L[l].wvb = (const float*)d_in[b + 9];
    L[l].ipw = (const float*)d_in[b + 10];
    L[l].ipb = (const float*)d_in[b + 11];
    L[l].opw = (const float*)d_in[b + 12];
    L[l].opb = (const float*)d_in[b + 13];
  }
  const int* edges = (const int*)d_in[34];

  // -------- workspace layout --------
  char* w = (char*)d_ws;
  size_t off = 0;
  auto alc = [&](size_t bytes) -> void* {
    off = (off + 255) & ~(size_t)255;
    void* p = w + off; off += bytes; return p;
  };
  float* f_cfvec = (float*)alc(64 * 128 * 4);
  float* f_cfmean= (float*)alc(128 * 4);
  float* f_duc   = (float*)alc(64 * 256 * 4);
  bf16*  b_inf   = (bf16*) alc((size_t)KNPAD * 384 * 2);
  bf16*  b_big   = (bf16*) alc((size_t)KN * NBIG * 2);
  bf16*  b_bigBT = (bf16*) alc((size_t)NBIG * 384 * 2);
  float* f_biasc = (float*)alc((size_t)NBIG * 4);
  bf16*  b_rbar  = (bf16*) alc((size_t)KNPAD * 256 * 2);
  float* f_Wq    = (float*)alc(128 * 256 * 4);
  float* f_B2    = (float*)alc(256 * 256 * 4);
  float* f_M1    = (float*)alc(256 * 256 * 4);
  float* f_bq    = (float*)alc(256 * 4);
  float* f_bv    = (float*)alc(256 * 4);
  bf16*  b_WvT   = (bf16*) alc(256 * 256 * 2);
  float* f_ipwQT = (float*)alc(256 * 256 * 4);
  float* f_wkwT  = (float*)alc(256 * 256 * 4);
  float* f_opwT  = (float*)alc(256 * 256 * 4);
  float* f_wvwT  = (float*)alc(256 * 256 * 4);
  int*   i_ptr   = (int*)  alc((size_t)(4 * KN + 1) * 4);
  int*   i_src   = (int*)  alc((size_t)4 * KE * 4);
  int*   i_cnt   = (int*)  alc((size_t)4 * KN * 4);
  int*   i_cur   = (int*)  alc((size_t)4 * KN * 4);
  if (off > ws_size) return;

  // -------- pre-phase --------
  k_pre<<<64, 384, 0, stream>>>(cf, cfw, cfb, htw, htb, f_cfvec, f_duc);
  k_mean<<<1, 128, 0, stream>>>(f_cfvec, f_cfmean);
  k_infasm<<<KN, 384, 0, stream>>>(x, f_duc, f_cfvec, f_cfmean, b_inf);
  k_zpad<<<(96 * 384 + 255) / 256, 256, 0, stream>>>(b_bigBT);

  // -------- batched CSR --------
  k_zeroi<<<(4 * KN + 255) / 256, 256, 0, stream>>>(i_cnt, 4 * KN);
  k_countB<<<(4 * KE + 255) / 256, 256, 0, stream>>>(edges, i_cnt);
  k_scan<<<1, 1024, 0, stream>>>(i_cnt, i_ptr, 4 * KN);
  k_copyi<<<(4 * KN + 255) / 256, 256, 0, stream>>>(i_ptr, i_cur, 4 * KN);
  k_fillB<<<(4 * KE + 255) / 256, 256, 0, stream>>>(edges, i_cur, i_src);

  // -------- one layer --------
  auto run_layer = [&](const LWT& Wt, bool last){
    k_transGW<<<dim3(32, 12, 4), dim3(32, 8), 0, stream>>>(Wt.gw, b_bigBT);
    k_galr<<<dim3(96, 32), 256, 0, stream>>>(Wt.gw, Wt.al, Wt.ar, b_bigBT);
    k_wprep<<<dim3(8, 8, 4), dim3(32, 8), 0, stream>>>(Wt.ipw, Wt.wkw, Wt.opw, Wt.wvw,
                                                       f_ipwQT, f_wkwT, f_opwT, f_wvwT);
    k_fold1<<<641, 256, 0, stream>>>(Wt.wqw, Wt.wqb, Wt.ipw, Wt.ipb,
                                     f_ipwQT, f_wkwT, f_opwT,
                                     f_Wq, f_B2, f_M1, f_bq);
    k_fold2<<<513, 256, 0, stream>>>(f_Wq, f_B2, f_M1, f_bq, Wt.wvb, Wt.ipb, Wt.opb,
                                     f_wvwT, f_opwT,
                                     b_bigBT, b_WvT, f_bv, f_biasc);
    gemm_mfma_bt<bf16><<<(NBIG / 128) * 66, 256, 0, stream>>>(
        b_inf, b_bigBT, f_biasc, b_big, KN, NBIG, 384, NBIG, NBIG / 128);
    k_aggattn<<<KN, 256, 0, stream>>>(i_ptr, i_src, b_big, Wt.gb, b_rbar);
    if (last)
      gemm_mfma_bt<float><<<2 * 66, 256, 0, stream>>>(
          b_rbar, b_WvT, f_bv, (float*)d_out, KN, 256, 256, 256, 2);
    else
      gemm_mfma_bt<bf16><<<2 * 66, 256, 0, stream>>>(
          b_rbar, b_WvT, f_bv, b_inf, KN, 256, 256, 384, 2);
  };

  run_layer(L[0], false);
  run_layer(L[1], true);
}

// Round 16
// 520.973 us; speedup vs baseline: 5.9787x; 1.0469x over previous
//
#include <hip/hip_runtime.h>
#include <hip/hip_bf16.h>

typedef __hip_bfloat16 bf16;
typedef __attribute__((ext_vector_type(8))) short short8;
typedef __attribute__((ext_vector_type(4))) short short4v;
typedef __attribute__((ext_vector_type(4))) float f32x4;

#define KN 8384
#define KNPAD 8448
#define KE 50000
#define NBIG 4480    /* 4096 feat + 256 qk + 128 elr(pad) = 35*128 */

__device__ __forceinline__ float toF(float v){ return v; }
__device__ __forceinline__ float toF(bf16 v){ return __bfloat162float(v); }
__device__ __forceinline__ float b2f(short u){ return __uint_as_float(((unsigned int)(unsigned short)u) << 16); }
__device__ __forceinline__ void stor(float* p, float v){ *p = v; }
__device__ __forceinline__ void stor(bf16* p, float v){ *p = __float2bfloat16(v); }

__device__ __forceinline__ void glds16(const bf16* g, bf16* l){
  __builtin_amdgcn_global_load_lds(
      (const __attribute__((address_space(1))) unsigned int*)(g),
      (__attribute__((address_space(3))) unsigned int*)(l), 16, 0, 0);
}

// ---------------- MFMA GEMM: 3-deep glds pipeline, vmcnt(4), XCD-chunked swizzle ----------------
template<typename TC>
__global__ __launch_bounds__(256)
void gemm_mfma_bt(const bf16* __restrict__ A, const bf16* __restrict__ BT,
                  const float* __restrict__ bias, TC* __restrict__ C,
                  int M, int N, int K, int ldc, int nbx)
{
  __shared__ bf16 As[3][128 * 32];
  __shared__ bf16 Bs[3][128 * 32];
  const int nwg = gridDim.x;
  const int q = nwg >> 3, r = nwg & 7;
  const int xcd = blockIdx.x & 7, idx = blockIdx.x >> 3;
  const int sw = (xcd < r) ? xcd * (q + 1) + idx : r * (q + 1) + (xcd - r) * q + idx;
  const int bn = (sw % nbx) * 128, bm = (sw / nbx) * 128;
  const int tid = threadIdx.x;
  const int w = tid >> 6, l = tid & 63;
  const int wr = (w >> 1) * 64, wc = (w & 1) * 64;
  const int lr = l & 15;
  int rS[2], lqS[2];
  #pragma unroll
  for (int i = 0; i < 2; i++){
    rS[i] = w * 32 + i * 16 + (l >> 2);
    lqS[i] = (l & 3) ^ ((rS[i] >> 1) & 3);
  }
  const bf16* gA0 = A  + (size_t)(bm + rS[0]) * K + lqS[0] * 8;
  const bf16* gA1 = A  + (size_t)(bm + rS[1]) * K + lqS[1] * 8;
  const bf16* gB0 = BT + (size_t)(bn + rS[0]) * K + lqS[0] * 8;
  const bf16* gB1 = BT + (size_t)(bn + rS[1]) * K + lqS[1] * 8;
  const int nt = K >> 5;
  auto issue = [&](int t){
    int b = t - (t / 3) * 3;
    int k0 = t << 5;
    glds16(gA0 + k0, &As[b][w * 1024]);
    glds16(gA1 + k0, &As[b][w * 1024 + 512]);
    glds16(gB0 + k0, &Bs[b][w * 1024]);
    glds16(gB1 + k0, &Bs[b][w * 1024 + 512]);
  };
  f32x4 acc[4][4] = {};
  issue(0);
  issue(1);
  for (int t = 0; t < nt; t++){
    if (t < nt - 1) asm volatile("s_waitcnt vmcnt(4)\ns_barrier" ::: "memory");
    else            asm volatile("s_waitcnt vmcnt(0)\ns_barrier" ::: "memory");
    if (t + 2 < nt) issue(t + 2);   // buffer (t+2)%3 freed by this barrier
    int b = t - (t / 3) * 3;
    short8 a[4], bb[4];
    #pragma unroll
    for (int i = 0; i < 4; i++){
      int R = wr + i * 16 + lr;
      int pq = (l >> 4) ^ ((R >> 1) & 3);
      a[i] = *(short8*)&As[b][R * 32 + pq * 8];
    }
    #pragma unroll
    for (int j = 0; j < 4; j++){
      int R = wc + j * 16 + lr;
      int pq = (l >> 4) ^ ((R >> 1) & 3);
      bb[j] = *(short8*)&Bs[b][R * 32 + pq * 8];
    }
    #pragma unroll
    for (int i = 0; i < 4; i++)
      #pragma unroll
      for (int j = 0; j < 4; j++)
        acc[i][j] = __builtin_amdgcn_mfma_f32_16x16x32_bf16(a[i], bb[j], acc[i][j], 0, 0, 0);
  }
  const int orow = (l >> 4) * 4, ocol = l & 15;
  #pragma unroll
  for (int i = 0; i < 4; i++){
    #pragma unroll
    for (int j = 0; j < 4; j++){
      int gcol = bn + wc + j * 16 + ocol;
      float bv = bias ? bias[gcol] : 0.f;
      #pragma unroll
      for (int rg = 0; rg < 4; rg++){
        int grow = bm + wr + i * 16 + orow + rg;
        if (grow < M) stor(&C[(size_t)grow * ldc + gcol], acc[i][j][rg] + bv);
      }
    }
  }
}

// ---------------- pointer bundle for both layers ----------------
struct LPtrs {
  const float *gw[2], *al[2], *ar[2];
  const float *wqw[2], *wqb[2], *wkw[2], *wvw[2], *wvb[2];
  const float *ipw[2], *ipb[2], *opw[2], *opb[2];
  bf16* bigBT[2];
  float *ipwQT[2], *wkwT[2], *opwT[2], *wvwT[2];
  float *Wq[2], *B2[2], *M1[2], *bq[2];
  bf16* WvT[2];
  float *bv[2], *biasc[2];
};

// ---------------- fat prep kernel: transGW | galr | wprep | zeroQK | zeroPad, z = layer ----------------
#define PT0 1536   /* transGW: 4 rel * 384 (32 n-tiles x 12 k-tiles) */
#define PT1 4608   /* + galr: 96 kblk * 32 r */
#define PT2 4864   /* + wprep: 4 mats * 64 tiles */
#define PT3 5248   /* + zeroQK: 256*384/256 */
#define PT4 5392   /* + zeroPad: 96*384/256 */
__global__ __launch_bounds__(256)
void k_prep_all(LPtrs P){
  const int lay = blockIdx.z;
  const int b = blockIdx.x, tid = threadIdx.x;
  bf16* bigBT = P.bigBT[lay];
  if (b < PT0){
    __shared__ float t[32][33];
    int rel = b / 384, rem = b % 384;
    int n0 = (rem % 32) * 32, k0 = (rem / 32) * 32;
    const float* B = P.gw[lay] + (size_t)rel * 384 * 1024;
    bf16* BT = bigBT + (size_t)rel * 1024 * 384;
    int tx = tid & 31, ty = tid >> 5;
    for (int i = ty; i < 32; i += 8)
      t[i][tx] = B[(size_t)(k0 + i) * 1024 + n0 + tx];
    __syncthreads();
    for (int i = ty; i < 32; i += 8)
      BT[(size_t)(n0 + i) * 384 + k0 + tx] = __float2bfloat16(t[tx][i]);
  } else if (b < PT1){
    int bb = b - PT0;
    int kblk = bb % 96, r = bb / 96;
    int k = kblk * 4 + (tid >> 6), lane = tid & 63;
    int rr = r & 15, t = rr >> 2, h = rr & 3;
    const float* wsrc = ((r < 16) ? P.al[lay] : P.ar[lay]) + t * 1024 + h * 256;
    const float* gp = P.gw[lay] + (size_t)t * 384 * 1024 + (size_t)k * 1024 + h * 256;
    float v = 0.f;
    #pragma unroll
    for (int i = 0; i < 4; i++){
      int o = lane + i * 64;
      v += gp[o] * wsrc[o];
    }
    #pragma unroll
    for (int off = 32; off; off >>= 1) v += __shfl_down(v, off);
    if (lane == 0) bigBT[(size_t)(4352 + r) * 384 + k] = __float2bfloat16(v);
  } else if (b < PT2){
    __shared__ float t[32][33];
    int bb = b - PT1;
    int mat = bb >> 6, rem = bb & 63;
    int c0 = (rem & 7) * 32, r0 = (rem >> 3) * 32;
    const float* S; float* D;
    switch (mat){
      case 0: S = P.ipw[lay]; D = P.ipwQT[lay]; break;
      case 1: S = P.wkw[lay]; D = P.wkwT[lay]; break;
      case 2: S = P.opw[lay]; D = P.opwT[lay]; break;
      default: S = P.wvw[lay]; D = P.wvwT[lay]; break;
    }
    int tx = tid & 31, ty = tid >> 5;
    for (int i = ty; i < 32; i += 8)
      t[i][tx] = S[(size_t)(r0 + i) * 256 + c0 + tx];
    __syncthreads();
    for (int i = ty; i < 32; i += 8)
      D[(size_t)(c0 + i) * 256 + r0 + tx] = t[tx][i];
  } else if (b < PT3){
    int idx = (b - PT2) * 256 + tid;                 // qk rows, full width (fold2 overwrites cols 256+)
    bigBT[(size_t)(4096 + idx / 384) * 384 + idx % 384] = __float2bfloat16(0.f);
  } else {
    int idx = (b - PT3) * 256 + tid;                 // pad rows 4384..4479
    bigBT[(size_t)(4384 + idx / 384) * 384 + idx % 384] = __float2bfloat16(0.f);
  }
}

// ---------------- F1 (z = layer): Wq, B2, M1, bq ----------------
__global__ __launch_bounds__(256)
void k_fold1(LPtrs P){
  const int lay = blockIdx.z;
  int b = blockIdx.x, tid = threadIdx.x;
  if (b < 128){
    int c = b; float s = 0.f;
    for (int e = 0; e < 256; e++) s += P.wqw[lay][c * 256 + e] * P.ipwQT[lay][e * 256 + tid];
    P.Wq[lay][c * 256 + tid] = s;
  } else if (b < 384){
    int j = b - 128; float s = 0.f;
    for (int e = 0; e < 256; e++) s += P.wkwT[lay][e * 256 + tid] * P.ipw[lay][(256 + j) * 256 + e];
    P.B2[lay][j * 256 + tid] = s;
  } else if (b < 640){
    int e = b - 384; float s = 0.f;
    for (int f = 0; f < 256; f++) s += P.ipw[lay][(512 + f) * 256 + e] * P.opwT[lay][f * 256 + tid];
    P.M1[lay][e * 256 + tid] = s;
  } else {
    float s = 0.f;
    for (int e = 0; e < 256; e++) s += P.wqb[lay][e] * P.ipwQT[lay][e * 256 + tid];
    P.bq[lay][tid] = s + P.ipb[lay][tid];
  }
}

// ---------------- F2 (z = layer): W2 -> bigBT qk rows, WvT, bv, biasc ----------------
__global__ __launch_bounds__(256)
void k_fold2(LPtrs P){
  const int lay = blockIdx.z;
  int b = blockIdx.x, tid = threadIdx.x;
  if (b < 256){            // W2[d][c] = sum_j Wq[d][j]*B2[j][c]; d = b, c = tid
    __shared__ float wqr[256];
    wqr[tid] = P.Wq[lay][b * 256 + tid];
    __syncthreads();
    float s = 0.f;
    for (int j = 0; j < 256; j++) s += wqr[j] * P.B2[lay][j * 256 + tid];
    P.bigBT[lay][(size_t)(4096 + tid) * 384 + 256 + b] = __float2bfloat16(s);
  } else if (b < 512){     // WvT[j][c]
    int j = b - 256; float s = 0.f;
    for (int e = 0; e < 256; e++) s += P.wvwT[lay][e * 256 + tid] * P.M1[lay][e * 256 + j];
    P.WvT[lay][j * 256 + tid] = __float2bfloat16(s);
  } else {                 // biasc, bv
    float b2 = 0.f;
    for (int j = 0; j < 256; j++) b2 += P.bq[lay][j] * P.B2[lay][j * 256 + tid];
    float s = 0.f;
    for (int e = 0; e < 256; e++) s += P.wvb[lay][e] * P.M1[lay][e * 256 + tid];
    for (int f = 0; f < 256; f++) s += P.ipb[lay][512 + f] * P.opwT[lay][f * 256 + tid];
    P.bv[lay][tid] = s + P.opb[lay][tid];
    for (int i = tid; i < NBIG; i += 256)
      P.biasc[lay][i] = (i - 4096 == tid) ? b2 : 0.f;
  }
}

// ---------------- pre-phase ----------------
__global__ __launch_bounds__(384)
void k_pre(const float* __restrict__ cf, const float* __restrict__ cfw, const float* __restrict__ cfb,
           const float* __restrict__ htw, const float* __restrict__ htb,
           float* __restrict__ cfvec, float* __restrict__ duc)
{
  int c = blockIdx.x;
  int col = threadIdx.x;
  __shared__ float row[512];
  for (int i = col; i < 512; i += 384) row[i] = cf[c * 512 + i];
  __syncthreads();
  if (col < 128){
    float acc = cfb[col];
    for (int k = 0; k < 512; k++) acc += row[k] * cfw[k * 128 + col];
    cfvec[c * 128 + col] = acc;
  } else {
    int j = col - 128;
    float acc = htb[j];
    for (int k = 0; k < 512; k++) acc += row[k] * htw[k * 256 + j];
    duc[c * 256 + j] = acc;
  }
}
__global__ void k_mean(const float* cv, float* m){
  int o = threadIdx.x;
  float s = 0.f;
  for (int c = 0; c < 64; c++) s += cv[c * 128 + o];
  m[o] = s * (1.f / 64.f);
}
__global__ __launch_bounds__(384)
void k_infasm(const float* __restrict__ x, const float* __restrict__ duc,
              const float* __restrict__ cv, const float* __restrict__ cm,
              bf16* __restrict__ inf){
  int n = blockIdx.x, o = threadIdx.x;
  float v;
  if (o < 256){
    if (n < 8192)      v = x[(n & 127) * 256 + o];
    else if (n < 8256) v = duc[(n - 8192) * 256 + o];
    else               v = x[(n - 8256) * 256 + o];
  } else {
    int oo = o - 256;
    if (n < 8192)      v = cv[(n >> 7) * 128 + oo];
    else if (n < 8256) v = cv[(n - 8192) * 128 + oo];
    else               v = cm[oo];
  }
  inf[(size_t)n * 384 + o] = __float2bfloat16(v);
}
__global__ void k_zeroi(int* p, int n){
  int i = blockIdx.x * blockDim.x + threadIdx.x; if (i < n) p[i] = 0;
}
__global__ void k_countB(const int* __restrict__ edges, int* __restrict__ cnt){
  int i = blockIdx.x * blockDim.x + threadIdx.x;
  if (i < 4 * KE){
    int t = i / KE, idx = i - t * KE;
    int d = edges[t * 2 * KE + KE + idx];
    atomicAdd(&cnt[t * KN + d], 1);
  }
}
__global__ void k_fillB(const int* __restrict__ edges, int* __restrict__ cur, int* __restrict__ csrc){
  int i = blockIdx.x * blockDim.x + threadIdx.x;
  if (i < 4 * KE){
    int t = i / KE, idx = i - t * KE;
    int s = edges[t * 2 * KE + idx];
    int d = edges[t * 2 * KE + KE + idx];
    int p = atomicAdd(&cur[t * KN + d], 1);
    csrc[p] = s;
  }
}
// scan also seeds cur (replaces copyi)
__global__ void k_scan(const int* __restrict__ cnt, int* __restrict__ ptr,
                       int* __restrict__ cur, int n){
  __shared__ int part[1024];
  int tid = threadIdx.x;
  const int CH = (n + 1023) >> 10;
  int base = tid * CH;
  int s = 0;
  for (int i = 0; i < CH; i++){ int idx = base + i; if (idx < n) s += cnt[idx]; }
  part[tid] = s; __syncthreads();
  for (int off = 1; off < 1024; off <<= 1){
    int v = (tid >= off) ? part[tid - off] : 0;
    __syncthreads();
    part[tid] += v;
    __syncthreads();
  }
  int run = part[tid] - s;
  for (int i = 0; i < CH; i++){
    int idx = base + i;
    if (idx < n){ ptr[idx] = run; cur[idx] = run; run += cnt[idx]; }
  }
  if (tid == 1023) ptr[n] = part[1023];
}

// ------------- fused GAT agg + attention: wave = relation, 4-way unrolled gather -------------
__global__ __launch_bounds__(256)
void k_aggattn(const int* __restrict__ ptr, const int* __restrict__ csrc,
               const bf16* __restrict__ big, const float* __restrict__ gb,
               bf16* __restrict__ rbar)
{
  const int n = blockIdx.x, tid = threadIdx.x;
  const int w = tid >> 6, lane = tid & 63;
  const int t = w;
  const int head = lane >> 4;
  __shared__ float s_rst[16][260];
  __shared__ float s_sc[16];
  __shared__ float sa4[4][64][4];
  __shared__ int ssrcW[4][64];
  const int beg = ptr[t * KN + n], deg = ptr[t * KN + n + 1] - beg;
  short4v e4 = *(const short4v*)&big[(size_t)n * NBIG + 4368 + t * 4];
  float ern[4] = {b2f(e4[0]), b2f(e4[1]), b2f(e4[2]), b2f(e4[3])};
  float sums[4] = {0.f, 0.f, 0.f, 0.f};
  for (int j = lane; j < deg; j += 64){
    int s = csrc[beg + j];
    short4v l4 = *(const short4v*)&big[(size_t)s * NBIG + 4352 + t * 4];
    #pragma unroll
    for (int h = 0; h < 4; h++){
      float e = b2f(l4[h]) + ern[h];
      e = e > 0.f ? e : 0.2f * e;
      sums[h] += __expf(e);
    }
  }
  #pragma unroll
  for (int off = 32; off; off >>= 1){
    #pragma unroll
    for (int h = 0; h < 4; h++) sums[h] += __shfl_xor(sums[h], off);
  }
  float sinv[4];
  #pragma unroll
  for (int h = 0; h < 4; h++) sinv[h] = 1.f / fmaxf(sums[h], 1e-9f);
  float acc[16];
  #pragma unroll
  for (int i = 0; i < 16; i++) acc[i] = 0.f;
  const size_t cbase = (size_t)t * 1024 + lane * 16;
  for (int c0 = 0; c0 < deg; c0 += 64){
    int cn = min(64, deg - c0);
    if (lane < cn){
      int s = csrc[beg + c0 + lane];
      ssrcW[t][lane] = s;
      short4v l4 = *(const short4v*)&big[(size_t)s * NBIG + 4352 + t * 4];
      #pragma unroll
      for (int h = 0; h < 4; h++){
        float e = b2f(l4[h]) + ern[h];
        e = e > 0.f ? e : 0.2f * e;
        sa4[t][lane][h] = __expf(e) * sinv[h];
      }
    }
    int j = 0;
    for (; j + 3 < cn; j += 4){
      int s0 = ssrcW[t][j],     s1 = ssrcW[t][j + 1];
      int s2 = ssrcW[t][j + 2], s3 = ssrcW[t][j + 3];
      float w0 = sa4[t][j][head],     w1 = sa4[t][j + 1][head];
      float w2 = sa4[t][j + 2][head], w3 = sa4[t][j + 3][head];
      const bf16* f0 = &big[(size_t)s0 * NBIG + cbase];
      const bf16* f1 = &big[(size_t)s1 * NBIG + cbase];
      const bf16* f2 = &big[(size_t)s2 * NBIG + cbase];
      const bf16* f3 = &big[(size_t)s3 * NBIG + cbase];
      short8 a0 = *(const short8*)f0, b0 = *(const short8*)(f0 + 8);
      short8 a1 = *(const short8*)f1, b1 = *(const short8*)(f1 + 8);
      short8 a2 = *(const short8*)f2, b2 = *(const short8*)(f2 + 8);
      short8 a3 = *(const short8*)f3, b3 = *(const short8*)(f3 + 8);
      #pragma unroll
      for (int i = 0; i < 8; i++)
        acc[i] += w0 * b2f(a0[i]) + w1 * b2f(a1[i]) + w2 * b2f(a2[i]) + w3 * b2f(a3[i]);
      #pragma unroll
      for (int i = 0; i < 8; i++)
        acc[8 + i] += w0 * b2f(b0[i]) + w1 * b2f(b1[i]) + w2 * b2f(b2[i]) + w3 * b2f(b3[i]);
    }
    for (; j < cn; j++){
      int s = ssrcW[t][j];
      float wj = sa4[t][j][head];
      const bf16* fp = &big[(size_t)s * NBIG + cbase];
      short8 v0 = *(const short8*)fp;
      short8 v1 = *(const short8*)(fp + 8);
      #pragma unroll
      for (int i = 0; i < 8; i++) acc[i] += wj * b2f(v0[i]);
      #pragma unroll
      for (int i = 0; i < 8; i++) acc[8 + i] += wj * b2f(v1[i]);
    }
  }
  {
    const float* gbp = gb + t * 1024 + lane * 16;
    float* rp = &s_rst[t * 4 + head][(lane & 15) * 16];
    #pragma unroll
    for (int i = 0; i < 16; i++) rp[i] = acc[i] + gbp[i];
  }
  __syncthreads();
  const bf16* q = big + (size_t)n * NBIG + 4096;
  #pragma unroll
  for (int si = 0; si < 4; si++){
    int s = w * 4 + si;
    float v = 0.f;
    #pragma unroll
    for (int i = 0; i < 4; i++){
      int o = lane + i * 64;
      v += s_rst[s][o] * toF(q[o]);
    }
    #pragma unroll
    for (int off = 32; off; off >>= 1) v += __shfl_down(v, off);
    if (lane == 0) s_sc[s] = v * 0.0625f;
  }
  __syncthreads();
  float sc[16]; float m = -1e30f;
  #pragma unroll
  for (int s = 0; s < 16; s++){ sc[s] = s_sc[s]; m = fmaxf(m, sc[s]); }
  float sum = 0.f;
  #pragma unroll
  for (int s = 0; s < 16; s++){ sc[s] = __expf(sc[s] - m); sum += sc[s]; }
  float inv = 1.f / sum;
  float r = 0.f;
  #pragma unroll
  for (int s = 0; s < 16; s++) r += sc[s] * s_rst[s][tid];
  rbar[(size_t)n * 256 + tid] = __float2bfloat16(r * inv);
}

extern "C" void kernel_launch(void* const* d_in, const int* in_sizes, int n_in,
                              void* d_out, int out_size, void* d_ws, size_t ws_size,
                              hipStream_t stream)
{
  const float* x   = (const float*)d_in[0];
  const float* cf  = (const float*)d_in[1];
  const float* cfw = (const float*)d_in[2];
  const float* cfb = (const float*)d_in[3];
  const float* htw = (const float*)d_in[4];
  const float* htb = (const float*)d_in[5];
  LPtrs P;
  const float* gbp[2];
  for (int l = 0; l < 2; l++){
    int b = 6 + l * 14;
    P.gw[l]  = (const float*)d_in[b + 0];
    P.al[l]  = (const float*)d_in[b + 1];
    P.ar[l]  = (const float*)d_in[b + 2];
    gbp[l]   = (const float*)d_in[b + 3];
    P.wqw[l] = (const float*)d_in[b + 4];
    P.wqb[l] = (const float*)d_in[b + 5];
    P.wkw[l] = (const float*)d_in[b + 6];
    P.wvw[l] = (const float*)d_in[b + 8];
    P.wvb[l] = (const float*)d_in[b + 9];
    P.ipw[l] = (const float*)d_in[b + 10];
    P.ipb[l] = (const float*)d_in[b + 11];
    P.opw[l] = (const float*)d_in[b + 12];
    P.opb[l] = (const float*)d_in[b + 13];
  }
  const int* edges = (const int*)d_in[34];

  // -------- workspace layout --------
  char* w = (char*)d_ws;
  size_t off = 0;
  auto alc = [&](size_t bytes) -> void* {
    off = (off + 255) & ~(size_t)255;
    void* p = w + off; off += bytes; return p;
  };
  float* f_cfvec = (float*)alc(64 * 128 * 4);
  float* f_cfmean= (float*)alc(128 * 4);
  float* f_duc   = (float*)alc(64 * 256 * 4);
  bf16*  b_inf   = (bf16*) alc((size_t)KNPAD * 384 * 2);
  bf16*  b_big   = (bf16*) alc((size_t)KN * NBIG * 2);
  bf16*  b_rbar  = (bf16*) alc((size_t)KNPAD * 256 * 2);
  for (int l = 0; l < 2; l++){
    P.bigBT[l] = (bf16*) alc((size_t)NBIG * 384 * 2);
    P.biasc[l] = (float*)alc((size_t)NBIG * 4);
    P.ipwQT[l] = (float*)alc(256 * 256 * 4);
    P.wkwT[l]  = (float*)alc(256 * 256 * 4);
    P.opwT[l]  = (float*)alc(256 * 256 * 4);
    P.wvwT[l]  = (float*)alc(256 * 256 * 4);
    P.Wq[l]    = (float*)alc(128 * 256 * 4);
    P.B2[l]    = (float*)alc(256 * 256 * 4);
    P.M1[l]    = (float*)alc(256 * 256 * 4);
    P.bq[l]    = (float*)alc(256 * 4);
    P.bv[l]    = (float*)alc(256 * 4);
    P.WvT[l]   = (bf16*) alc(256 * 256 * 2);
  }
  int* i_ptr = (int*)alc((size_t)(4 * KN + 1) * 4);
  int* i_src = (int*)alc((size_t)4 * KE * 4);
  int* i_cnt = (int*)alc((size_t)4 * KN * 4);
  int* i_cur = (int*)alc((size_t)4 * KN * 4);
  if (off > ws_size) return;

  // -------- pre-phase + prep (both layers) --------
  k_pre<<<64, 384, 0, stream>>>(cf, cfw, cfb, htw, htb, f_cfvec, f_duc);
  k_mean<<<1, 128, 0, stream>>>(f_cfvec, f_cfmean);
  k_infasm<<<KN, 384, 0, stream>>>(x, f_duc, f_cfvec, f_cfmean, b_inf);
  k_prep_all<<<dim3(PT4, 1, 2), 256, 0, stream>>>(P);
  k_fold1<<<dim3(641, 1, 2), 256, 0, stream>>>(P);
  k_fold2<<<dim3(513, 1, 2), 256, 0, stream>>>(P);

  // -------- batched CSR --------
  k_zeroi<<<(4 * KN + 255) / 256, 256, 0, stream>>>(i_cnt, 4 * KN);
  k_countB<<<(4 * KE + 255) / 256, 256, 0, stream>>>(edges, i_cnt);
  k_scan<<<1, 1024, 0, stream>>>(i_cnt, i_ptr, i_cur, 4 * KN);
  k_fillB<<<(4 * KE + 255) / 256, 256, 0, stream>>>(edges, i_cur, i_src);

  // -------- layers --------
  for (int l = 0; l < 2; l++){
    gemm_mfma_bt<bf16><<<(NBIG / 128) * 66, 256, 0, stream>>>(
        b_inf, P.bigBT[l], P.biasc[l], b_big, KN, NBIG, 384, NBIG, NBIG / 128);
    k_aggattn<<<KN, 256, 0, stream>>>(i_ptr, i_src, b_big, gbp[l], b_rbar);
    if (l == 1)
      gemm_mfma_bt<float><<<2 * 66, 256, 0, stream>>>(
          b_rbar, P.WvT[l], P.bv[l], (float*)d_out, KN, 256, 256, 256, 2);
    else
      gemm_mfma_bt<bf16><<<2 * 66, 256, 0, stream>>>(
          b_rbar, P.WvT[l], P.bv[l], b_inf, KN, 256, 256, 384, 2);
  }
}